// Round 1
// baseline (2044.763 us; speedup 1.0000x reference)
//
#include <hip/hip_runtime.h>
#include <hip/hip_bf16.h>

// Problem constants: B=2, T=2048, W=1024, H=16, C=64
// scale^2 = 1/sqrt(64) = 1/8 applied to scores and to pos interaction.

#define LOG2E 1.4426950408889634f

// ---------------------------------------------------------------------------
// Generic fp32 tiled GEMM with bias and optional per-row scale on A:
//   C[M,N] = (rowscale ⊙ A)[M,K] @ B[K,N] + bias[N]
// Tile 128x128, K-step 16, 256 threads, each thread 2x2 quadrants of 4x4.
// ---------------------------------------------------------------------------
__global__ __launch_bounds__(256) void gemm_bias(
    const float* __restrict__ A, const float* __restrict__ B,
    const float* __restrict__ bias, float* __restrict__ C,
    int M, int N, int K, const float* __restrict__ rowscale) {
  __shared__ float As[16][132];  // [k][m], padded +4 to break bank conflicts
  __shared__ float Bs[16][128];  // [k][n]

  const int tid = threadIdx.x;
  const int m0 = blockIdx.y * 128;
  const int n0 = blockIdx.x * 128;
  const int tx = tid & 15;   // col group
  const int ty = tid >> 4;   // row group

  // staging indices
  const int ar = tid >> 2;          // A row within tile (0..63), +64 for 2nd
  const int af = tid & 3;           // A float4 index along K (0..3)
  const int bk = tid >> 5;          // B k-row (0..7), +8 for 2nd
  const int bf = tid & 31;          // B float4 col (0..31)

  float acc[2][2][4][4];
#pragma unroll
  for (int a = 0; a < 2; ++a)
#pragma unroll
    for (int b = 0; b < 2; ++b)
#pragma unroll
      for (int i = 0; i < 4; ++i)
#pragma unroll
        for (int j = 0; j < 4; ++j) acc[a][b][i][j] = 0.f;

  for (int kt = 0; kt < K; kt += 16) {
    __syncthreads();
#pragma unroll
    for (int rr = 0; rr < 2; ++rr) {
      int r = ar + rr * 64;
      float4 v = *(const float4*)&A[(size_t)(m0 + r) * K + kt + af * 4];
      if (rowscale) {
        float s = rowscale[m0 + r];
        v.x *= s; v.y *= s; v.z *= s; v.w *= s;
      }
      As[af * 4 + 0][r] = v.x;
      As[af * 4 + 1][r] = v.y;
      As[af * 4 + 2][r] = v.z;
      As[af * 4 + 3][r] = v.w;
    }
#pragma unroll
    for (int rr = 0; rr < 2; ++rr) {
      int kk = bk + rr * 8;
      *(float4*)&Bs[kk][bf * 4] =
          *(const float4*)&B[(size_t)(kt + kk) * N + n0 + bf * 4];
    }
    __syncthreads();

#pragma unroll
    for (int kk = 0; kk < 16; ++kk) {
      float4 a0 = *(const float4*)&As[kk][ty * 4];
      float4 a1 = *(const float4*)&As[kk][64 + ty * 4];
      float4 b0 = *(const float4*)&Bs[kk][tx * 4];
      float4 b1 = *(const float4*)&Bs[kk][64 + tx * 4];
      float af2[2][4] = {{a0.x, a0.y, a0.z, a0.w}, {a1.x, a1.y, a1.z, a1.w}};
      float bf2[2][4] = {{b0.x, b0.y, b0.z, b0.w}, {b1.x, b1.y, b1.z, b1.w}};
#pragma unroll
      for (int ri = 0; ri < 2; ++ri)
#pragma unroll
        for (int i = 0; i < 4; ++i)
#pragma unroll
          for (int cj = 0; cj < 2; ++cj)
#pragma unroll
            for (int j = 0; j < 4; ++j)
              acc[ri][cj][i][j] = fmaf(af2[ri][i], bf2[cj][j], acc[ri][cj][i][j]);
    }
  }

#pragma unroll
  for (int ri = 0; ri < 2; ++ri)
#pragma unroll
    for (int i = 0; i < 4; ++i) {
      int r = m0 + ri * 64 + ty * 4 + i;
#pragma unroll
      for (int cj = 0; cj < 2; ++cj) {
        int c = n0 + cj * 64 + tx * 4;
        float4 o;
        o.x = acc[ri][cj][i][0] + bias[c + 0];
        o.y = acc[ri][cj][i][1] + bias[c + 1];
        o.z = acc[ri][cj][i][2] + bias[c + 2];
        o.w = acc[ri][cj][i][3] + bias[c + 3];
        *(float4*)&C[(size_t)r * N + c] = o;
      }
    }
}

// ---------------------------------------------------------------------------
// k_mean[b,h,c] = mean over t of k = qkv[b,t,h*192+64+c]
// grid 32 (= b*16+h), block 256
// ---------------------------------------------------------------------------
__global__ __launch_bounds__(256) void kmean_kernel(const float* __restrict__ qkv,
                                                    float* __restrict__ km) {
  int bh = blockIdx.x;
  int b = bh >> 4, h = bh & 15;
  int c = threadIdx.x & 63, seg = threadIdx.x >> 6;
  const float* base = qkv + (size_t)b * 2048 * 3072 + h * 192 + 64 + c;
  float s = 0.f;
  for (int t = seg * 512; t < seg * 512 + 512; ++t) s += base[(size_t)t * 3072];
  __shared__ float red[4][64];
  red[seg][c] = s;
  __syncthreads();
  if (seg == 0) {
    float v = red[0][c] + red[1][c] + red[2][c] + red[3][c];
    km[(bh << 6) + c] = v * (1.0f / 2048.0f);
  }
}

// ---------------------------------------------------------------------------
// pos[row] = (1/8) * sum_{h,c} q[row, h*192+c] * km[b, h*64+c]
// grid 1024 blocks (4 rows each), block 256 = 4 waves, 1 wave per row
// ---------------------------------------------------------------------------
__global__ __launch_bounds__(256) void pos_kernel(const float* __restrict__ qkv,
                                                  const float* __restrict__ km,
                                                  float* __restrict__ pos) {
  __shared__ float kms[1024];
  int blk = blockIdx.x;
  int b = (blk * 4) >> 11;  // 4 rows per block never cross batch (2048%4==0)
  for (int i = threadIdx.x; i < 1024; i += 256) {
    int h = i >> 6, c = i & 63;
    kms[i] = km[(b * 16 + h) * 64 + c] * 0.125f;
  }
  __syncthreads();
  int w = threadIdx.x >> 6, lane = threadIdx.x & 63;
  int row = blk * 4 + w;
  const float* qrow = qkv + (size_t)row * 3072;
  float p = 0.f;
#pragma unroll
  for (int h = 0; h < 16; ++h) p = fmaf(qrow[h * 192 + lane], kms[h * 64 + lane], p);
#pragma unroll
  for (int off = 32; off; off >>= 1) p += __shfl_xor(p, off, 64);
  if (lane == 0) pos[row] = p;
}

// ---------------------------------------------------------------------------
// aw[b,t] = (pos - min) / (max - min + 1e-6), min/max over t per batch
// grid 2 (batch), block 1024 (each thread handles t and t+1024)
// ---------------------------------------------------------------------------
__global__ __launch_bounds__(1024) void aw_kernel(const float* __restrict__ pos,
                                                  float* __restrict__ aw) {
  int b = blockIdx.x, tid = threadIdx.x;
  float p0 = pos[b * 2048 + tid], p1 = pos[b * 2048 + 1024 + tid];
  float mn = fminf(p0, p1), mx = fmaxf(p0, p1);
#pragma unroll
  for (int off = 32; off; off >>= 1) {
    mn = fminf(mn, __shfl_xor(mn, off, 64));
    mx = fmaxf(mx, __shfl_xor(mx, off, 64));
  }
  __shared__ float smn[16], smx[16];
  int wave = tid >> 6, lane = tid & 63;
  if (lane == 0) { smn[wave] = mn; smx[wave] = mx; }
  __syncthreads();
  if (tid < 64) {
    mn = (lane < 16) ? smn[lane] : 3.0e38f;
    mx = (lane < 16) ? smx[lane] : -3.0e38f;
#pragma unroll
    for (int off = 8; off; off >>= 1) {
      mn = fminf(mn, __shfl_xor(mn, off, 64));
      mx = fmaxf(mx, __shfl_xor(mx, off, 64));
    }
    if (lane == 0) { smn[0] = mn; smx[0] = mx; }
  }
  __syncthreads();
  float MN = smn[0], inv = 1.0f / (smx[0] - MN + 1e-6f);
  aw[b * 2048 + tid] = (p0 - MN) * inv;
  aw[b * 2048 + 1024 + tid] = (p1 - MN) * inv;
}

// ---------------------------------------------------------------------------
// Flash attention, fp32, thread-per-q-row. Block = 128 threads (2 waves),
// grid = (32 bh, 16 q-tiles). K/V tiles 64x64 staged in padded LDS.
// Scores computed in exp2 domain: q pre-scaled by 0.125*log2(e).
// ---------------------------------------------------------------------------
__global__ __launch_bounds__(128) void attn_kernel(const float* __restrict__ qkv,
                                                   float* __restrict__ attn) {
  const int b = blockIdx.x >> 4, h = blockIdx.x & 15;
  const int tid = threadIdx.x;
  const int t = blockIdx.y * 128 + tid;
  const float* base = qkv + (size_t)b * 2048 * 3072 + h * 192;

  __shared__ float Ks[64][68];
  __shared__ float Vs[64][68];

  float q[64], o[64];
  const float* qrow = base + (size_t)t * 3072;
  const float QS = 0.125f * LOG2E;
#pragma unroll
  for (int c4 = 0; c4 < 16; ++c4) {
    float4 v = *(const float4*)&qrow[c4 * 4];
    q[4 * c4 + 0] = v.x * QS; q[4 * c4 + 1] = v.y * QS;
    q[4 * c4 + 2] = v.z * QS; q[4 * c4 + 3] = v.w * QS;
  }
#pragma unroll
  for (int c = 0; c < 64; ++c) o[c] = 0.f;
  float m = -1e30f, l = 0.f;

  for (int s0 = 0; s0 < 2048; s0 += 64) {
    __syncthreads();
#pragma unroll
    for (int i = 0; i < 8; ++i) {
      int L = i * 128 + tid;
      int r = L >> 4, c4 = L & 15;
      const float* src = base + (size_t)(s0 + r) * 3072 + 64;
      *(float4*)&Ks[r][c4 * 4] = *(const float4*)&src[c4 * 4];
      *(float4*)&Vs[r][c4 * 4] = *(const float4*)&src[64 + c4 * 4];
    }
    __syncthreads();

    for (int s = 0; s < 64; ++s) {
      float sa = 0.f, sb = 0.f, sc2 = 0.f, sd = 0.f;
#pragma unroll
      for (int c4 = 0; c4 < 16; ++c4) {
        float4 k4 = *(const float4*)&Ks[s][c4 * 4];
        sa = fmaf(q[4 * c4 + 0], k4.x, sa);
        sb = fmaf(q[4 * c4 + 1], k4.y, sb);
        sc2 = fmaf(q[4 * c4 + 2], k4.z, sc2);
        sd = fmaf(q[4 * c4 + 3], k4.w, sd);
      }
      float sc = (sa + sb) + (sc2 + sd);
      if (sc <= m) {
        float p = exp2f(sc - m);
        l += p;
#pragma unroll
        for (int c4 = 0; c4 < 16; ++c4) {
          float4 v4 = *(const float4*)&Vs[s][c4 * 4];
          o[4 * c4 + 0] = fmaf(p, v4.x, o[4 * c4 + 0]);
          o[4 * c4 + 1] = fmaf(p, v4.y, o[4 * c4 + 1]);
          o[4 * c4 + 2] = fmaf(p, v4.z, o[4 * c4 + 2]);
          o[4 * c4 + 3] = fmaf(p, v4.w, o[4 * c4 + 3]);
        }
      } else {
        float corr = exp2f(m - sc);
        l = fmaf(l, corr, 1.0f);
#pragma unroll
        for (int c4 = 0; c4 < 16; ++c4) {
          float4 v4 = *(const float4*)&Vs[s][c4 * 4];
          o[4 * c4 + 0] = fmaf(o[4 * c4 + 0], corr, v4.x);
          o[4 * c4 + 1] = fmaf(o[4 * c4 + 1], corr, v4.y);
          o[4 * c4 + 2] = fmaf(o[4 * c4 + 2], corr, v4.z);
          o[4 * c4 + 3] = fmaf(o[4 * c4 + 3], corr, v4.w);
        }
        m = sc;
      }
    }
  }

  float invl = 1.0f / l;
  float* orow = attn + (size_t)(b * 2048 + t) * 1024 + h * 64;
#pragma unroll
  for (int c4 = 0; c4 < 16; ++c4) {
    float4 v;
    v.x = o[4 * c4 + 0] * invl;
    v.y = o[4 * c4 + 1] * invl;
    v.z = o[4 * c4 + 2] * invl;
    v.w = o[4 * c4 + 3] * invl;
    *(float4*)&orow[c4 * 4] = v;
  }
}

// ---------------------------------------------------------------------------
extern "C" void kernel_launch(void* const* d_in, const int* in_sizes, int n_in,
                              void* d_out, int out_size, void* d_ws, size_t ws_size,
                              hipStream_t stream) {
  const float* x      = (const float*)d_in[0];  // [2,2048,1024]
  const float* W_qkv  = (const float*)d_in[1];  // [1024,3072]
  const float* b_qkv  = (const float*)d_in[2];  // [3072]
  const float* W_proj = (const float*)d_in[3];  // [1024,1024]
  const float* b_proj = (const float*)d_in[4];  // [1024]
  float* out = (float*)d_out;                   // [2,2048,1024]

  float* ws  = (float*)d_ws;
  float* qkv  = ws;                    // 4096*3072 = 12,582,912 floats (48 MB)
  float* attn = ws + 12582912;         // 4096*1024 =  4,194,304 floats (16 MB)
  float* km   = attn + 4194304;        // 2048 floats
  float* pos  = km + 2048;             // 4096 floats
  float* aw   = pos + 4096;            // 4096 floats

  // 1) qkv = x @ W_qkv + b_qkv
  gemm_bias<<<dim3(24, 32), 256, 0, stream>>>(x, W_qkv, b_qkv, qkv,
                                              4096, 3072, 1024, nullptr);
  // 2) k_mean
  kmean_kernel<<<32, 256, 0, stream>>>(qkv, km);
  // 3) flash attention
  attn_kernel<<<dim3(32, 16), 128, 0, stream>>>(qkv, attn);
  // 4) pos interaction
  pos_kernel<<<1024, 256, 0, stream>>>(qkv, km, pos);
  // 5) adaptive weight
  aw_kernel<<<2, 1024, 0, stream>>>(pos, aw);
  // 6) out = (aw ⊙ attn) @ W_proj + b_proj
  gemm_bias<<<dim3(8, 32), 256, 0, stream>>>(attn, W_proj, b_proj, out,
                                             4096, 1024, 1024, aw);
}

// Round 2
// 717.688 us; speedup vs baseline: 2.8491x; 2.8491x over previous
//
#include <hip/hip_runtime.h>
#include <hip/hip_bf16.h>

// Problem constants: B=2, T=2048, W=1024, H=16, C=64
// scale^2 = 1/8 folded into Q along with log2(e) (exp2-domain softmax).

#define LOG2E 1.4426950408889634f

typedef float f32x4 __attribute__((ext_vector_type(4)));
typedef short bf16x8 __attribute__((ext_vector_type(8)));

__device__ __forceinline__ unsigned short f2bf(float f) {
  union { float f; unsigned int u; } v; v.f = f;
  unsigned int r = v.u + 0x7fffu + ((v.u >> 16) & 1u);
  return (unsigned short)(r >> 16);
}
__device__ __forceinline__ float bf2f(unsigned short h) {
  union { unsigned int u; float f; } v; v.u = ((unsigned int)h) << 16;
  return v.f;
}

// ---------------------------------------------------------------------------
// Generic fp32 tiled GEMM with bias and optional per-row scale on A.
// (unchanged from round 1 — verified)
// ---------------------------------------------------------------------------
__global__ __launch_bounds__(256) void gemm_bias(
    const float* __restrict__ A, const float* __restrict__ B,
    const float* __restrict__ bias, float* __restrict__ C,
    int M, int N, int K, const float* __restrict__ rowscale) {
  __shared__ float As[16][132];
  __shared__ float Bs[16][128];

  const int tid = threadIdx.x;
  const int m0 = blockIdx.y * 128;
  const int n0 = blockIdx.x * 128;
  const int tx = tid & 15;
  const int ty = tid >> 4;

  const int ar = tid >> 2;
  const int af = tid & 3;
  const int bk = tid >> 5;
  const int bf = tid & 31;

  float acc[2][2][4][4];
#pragma unroll
  for (int a = 0; a < 2; ++a)
#pragma unroll
    for (int b = 0; b < 2; ++b)
#pragma unroll
      for (int i = 0; i < 4; ++i)
#pragma unroll
        for (int j = 0; j < 4; ++j) acc[a][b][i][j] = 0.f;

  for (int kt = 0; kt < K; kt += 16) {
    __syncthreads();
#pragma unroll
    for (int rr = 0; rr < 2; ++rr) {
      int r = ar + rr * 64;
      float4 v = *(const float4*)&A[(size_t)(m0 + r) * K + kt + af * 4];
      if (rowscale) {
        float s = rowscale[m0 + r];
        v.x *= s; v.y *= s; v.z *= s; v.w *= s;
      }
      As[af * 4 + 0][r] = v.x;
      As[af * 4 + 1][r] = v.y;
      As[af * 4 + 2][r] = v.z;
      As[af * 4 + 3][r] = v.w;
    }
#pragma unroll
    for (int rr = 0; rr < 2; ++rr) {
      int kk = bk + rr * 8;
      *(float4*)&Bs[kk][bf * 4] =
          *(const float4*)&B[(size_t)(kt + kk) * N + n0 + bf * 4];
    }
    __syncthreads();

#pragma unroll
    for (int kk = 0; kk < 16; ++kk) {
      float4 a0 = *(const float4*)&As[kk][ty * 4];
      float4 a1 = *(const float4*)&As[kk][64 + ty * 4];
      float4 b0 = *(const float4*)&Bs[kk][tx * 4];
      float4 b1 = *(const float4*)&Bs[kk][64 + tx * 4];
      float af2[2][4] = {{a0.x, a0.y, a0.z, a0.w}, {a1.x, a1.y, a1.z, a1.w}};
      float bf2[2][4] = {{b0.x, b0.y, b0.z, b0.w}, {b1.x, b1.y, b1.z, b1.w}};
#pragma unroll
      for (int ri = 0; ri < 2; ++ri)
#pragma unroll
        for (int i = 0; i < 4; ++i)
#pragma unroll
          for (int cj = 0; cj < 2; ++cj)
#pragma unroll
            for (int j = 0; j < 4; ++j)
              acc[ri][cj][i][j] = fmaf(af2[ri][i], bf2[cj][j], acc[ri][cj][i][j]);
    }
  }

#pragma unroll
  for (int ri = 0; ri < 2; ++ri)
#pragma unroll
    for (int i = 0; i < 4; ++i) {
      int r = m0 + ri * 64 + ty * 4 + i;
#pragma unroll
      for (int cj = 0; cj < 2; ++cj) {
        int c = n0 + cj * 64 + tx * 4;
        float4 o;
        o.x = acc[ri][cj][i][0] + bias[c + 0];
        o.y = acc[ri][cj][i][1] + bias[c + 1];
        o.z = acc[ri][cj][i][2] + bias[c + 2];
        o.w = acc[ri][cj][i][3] + bias[c + 3];
        *(float4*)&C[(size_t)r * N + c] = o;
      }
    }
}

// ---------------------------------------------------------------------------
// Pre-pass: qkv fp32 -> bf16 operands for MFMA attention.
//  Qh/Ql: scaled (0.125*log2e) hi/lo split, row-major [bh][2048][64]
//  Khg/Klg: hi/lo split K, 8KB swizzled tile images [bh*32+stile][64s][64c]
//  Vtg: V transposed, swizzled tile images [bh*32+stile][64c][64s]
// Swizzle: byte ^= (row&7)<<4 within each 128B row (2-way-free ds_read_b128).
// ---------------------------------------------------------------------------
__global__ __launch_bounds__(256) void convert_kernel(
    const float* __restrict__ qkv,
    unsigned short* __restrict__ Qh, unsigned short* __restrict__ Ql,
    unsigned short* __restrict__ Khg, unsigned short* __restrict__ Klg,
    unsigned short* __restrict__ Vtg) {
  const int stile = blockIdx.x, bh = blockIdx.y;
  const int b = bh >> 4, h = bh & 15;
  const int tid = threadIdx.x;
  const int s = tid >> 2;           // 0..63 (row within tile)
  const int cg = (tid & 3) << 4;    // col base (16 cols per thread)
  const int t = stile * 64 + s;
  const float* row = qkv + (size_t)(b * 2048 + t) * 3072 + h * 192;
  const float QS = 0.125f * LOG2E;

  __shared__ unsigned short vs[64][72];

  // Q: scaled hi/lo split, row-major
  {
    unsigned int* qh32 = (unsigned int*)(Qh + ((size_t)bh * 2048 + t) * 64 + cg);
    unsigned int* ql32 = (unsigned int*)(Ql + ((size_t)bh * 2048 + t) * 64 + cg);
#pragma unroll
    for (int j = 0; j < 4; ++j) {
      float4 v = *(const float4*)&row[cg + j * 4];
      float f[4] = {v.x * QS, v.y * QS, v.z * QS, v.w * QS};
      unsigned short hh[4], llo[4];
#pragma unroll
      for (int e = 0; e < 4; ++e) {
        hh[e] = f2bf(f[e]);
        llo[e] = f2bf(f[e] - bf2f(hh[e]));
      }
      qh32[j * 2 + 0] = (unsigned int)hh[0] | ((unsigned int)hh[1] << 16);
      qh32[j * 2 + 1] = (unsigned int)hh[2] | ((unsigned int)hh[3] << 16);
      ql32[j * 2 + 0] = (unsigned int)llo[0] | ((unsigned int)llo[1] << 16);
      ql32[j * 2 + 1] = (unsigned int)llo[2] | ((unsigned int)llo[3] << 16);
    }
  }
  // K: hi/lo split into swizzled tile images
  {
    unsigned int* kh32 = (unsigned int*)(Khg + (size_t)(bh * 32 + stile) * 4096);
    unsigned int* kl32 = (unsigned int*)(Klg + (size_t)(bh * 32 + stile) * 4096);
    const int sw = (s & 7) << 4;
#pragma unroll
    for (int j = 0; j < 4; ++j) {
      float4 v = *(const float4*)&row[64 + cg + j * 4];
      float f[4] = {v.x, v.y, v.z, v.w};
#pragma unroll
      for (int p = 0; p < 2; ++p) {
        int c0 = cg + j * 4 + p * 2;
        unsigned short h0 = f2bf(f[p * 2]), h1 = f2bf(f[p * 2 + 1]);
        unsigned short l0 = f2bf(f[p * 2] - bf2f(h0));
        unsigned short l1 = f2bf(f[p * 2 + 1] - bf2f(h1));
        int byte = (s * 128 + c0 * 2) ^ sw;
        kh32[byte >> 2] = (unsigned int)h0 | ((unsigned int)h1 << 16);
        kl32[byte >> 2] = (unsigned int)l0 | ((unsigned int)l1 << 16);
      }
    }
  }
  // V: bf16 to LDS, then transposed swizzled image
#pragma unroll
  for (int j = 0; j < 4; ++j) {
    float4 v = *(const float4*)&row[128 + cg + j * 4];
    vs[s][cg + j * 4 + 0] = f2bf(v.x);
    vs[s][cg + j * 4 + 1] = f2bf(v.y);
    vs[s][cg + j * 4 + 2] = f2bf(v.z);
    vs[s][cg + j * 4 + 3] = f2bf(v.w);
  }
  __syncthreads();
  {
    const int c = tid >> 2;          // V^T row (channel)
    const int sb = (tid & 3) << 4;   // s range base
    unsigned int* vt32 = (unsigned int*)(Vtg + (size_t)(bh * 32 + stile) * 4096);
    const int sw = (c & 7) << 4;
#pragma unroll
    for (int p = 0; p < 8; ++p) {
      int ss = sb + p * 2;
      unsigned int wv = (unsigned int)vs[ss][c] | ((unsigned int)vs[ss + 1][c] << 16);
      int byte = (c * 128 + ss * 2) ^ sw;
      vt32[byte >> 2] = wv;
    }
  }
}

// ---------------------------------------------------------------------------
// MFMA flash attention. Block 256 = 4 waves, each wave owns 16 q rows.
// Grid (32 q-tiles, 32 bh). KVBLK=64. QK^T in split-bf16 (3 products),
// PV in single bf16. LDS: Kh|Kl|Vt tile images (24KB, global_load_lds
// staged) + per-wave P buffer (pad 80 shorts/row).
// MFMA 16x16x32 layouts: A row=lane&15,k=(lane>>4)*8+j ; B col=lane&15,
// k=(lane>>4)*8+j ; D col=lane&15,row=(lane>>4)*4+reg (verified m89/m91).
// ---------------------------------------------------------------------------
__global__ __launch_bounds__(256, 4) void attn_mfma(
    const unsigned short* __restrict__ Qh, const unsigned short* __restrict__ Ql,
    const unsigned short* __restrict__ Khg, const unsigned short* __restrict__ Klg,
    const unsigned short* __restrict__ Vtg, float* __restrict__ attn) {
  const int qt = blockIdx.x, bh = blockIdx.y;
  const int b = bh >> 4, h = bh & 15;
  const int tid = threadIdx.x;
  const int w = tid >> 6, l = tid & 63;
  const int lc = l & 15, lr = l >> 4;

  __shared__ __align__(16) unsigned short lds[12288 + 4 * 1280];
  unsigned short* KhT = lds;            // 4096 shorts (8KB image)
  unsigned short* KlT = lds + 4096;
  unsigned short* VtT = lds + 8192;
  unsigned short* Pl  = lds + 12288 + w * 1280;  // 16 rows x 80 shorts

  const int q0 = qt * 64 + w * 16;
  bf16x8 qh0, qh1, ql0, ql1;
  {
    size_t base = ((size_t)bh * 2048 + q0 + lc) * 64 + lr * 8;
    qh0 = *(const bf16x8*)&Qh[base];
    qh1 = *(const bf16x8*)&Qh[base + 32];
    ql0 = *(const bf16x8*)&Ql[base];
    ql1 = *(const bf16x8*)&Ql[base + 32];
  }

  f32x4 o[4];
  float m[4], lsum[4];
#pragma unroll
  for (int r = 0; r < 4; ++r) { m[r] = -1e30f; lsum[r] = 0.f; }
#pragma unroll
  for (int ct = 0; ct < 4; ++ct) o[ct] = (f32x4){0.f, 0.f, 0.f, 0.f};

  const unsigned short* pKh = Khg + (size_t)bh * 32 * 4096;
  const unsigned short* pKl = Klg + (size_t)bh * 32 * 4096;
  const unsigned short* pVt = Vtg + (size_t)bh * 32 * 4096;

  for (int kvt = 0; kvt < 32; ++kvt) {
    // stage 24KB: 24 chunks of 1KB; wave w does chunks 6w..6w+5
    {
      size_t tb = (size_t)kvt * 4096;
#pragma unroll
      for (int i = 0; i < 6; ++i) {
        int c = w * 6 + i;
        int arr = c >> 3;
        const unsigned short* gb =
            (arr == 0) ? (pKh + tb) : (arr == 1) ? (pKl + tb) : (pVt + tb);
        const unsigned short* g = gb + (c & 7) * 512 + l * 8;
        unsigned short* dst = lds + c * 512;
        __builtin_amdgcn_global_load_lds(
            (const __attribute__((address_space(1))) unsigned int*)g,
            (__attribute__((address_space(3))) unsigned int*)dst, 16, 0, 0);
      }
    }
    __syncthreads();

    // QK^T: S[16q][64s] as 4 sub-tiles, split-bf16 3 products
    f32x4 sacc[4];
#pragma unroll
    for (int st = 0; st < 4; ++st) {
      int row = st * 16 + lc;
      int sw = (row & 7) << 4;
      int i0 = ((row * 128 + lr * 16) ^ sw) >> 1;
      int i1 = ((row * 128 + 64 + lr * 16) ^ sw) >> 1;
      bf16x8 kh0 = *(const bf16x8*)&KhT[i0];
      bf16x8 kh1 = *(const bf16x8*)&KhT[i1];
      bf16x8 kl0 = *(const bf16x8*)&KlT[i0];
      bf16x8 kl1 = *(const bf16x8*)&KlT[i1];
      f32x4 acc = (f32x4){0.f, 0.f, 0.f, 0.f};
      acc = __builtin_amdgcn_mfma_f32_16x16x32_bf16(qh0, kh0, acc, 0, 0, 0);
      acc = __builtin_amdgcn_mfma_f32_16x16x32_bf16(qh1, kh1, acc, 0, 0, 0);
      acc = __builtin_amdgcn_mfma_f32_16x16x32_bf16(ql0, kh0, acc, 0, 0, 0);
      acc = __builtin_amdgcn_mfma_f32_16x16x32_bf16(ql1, kh1, acc, 0, 0, 0);
      acc = __builtin_amdgcn_mfma_f32_16x16x32_bf16(qh0, kl0, acc, 0, 0, 0);
      acc = __builtin_amdgcn_mfma_f32_16x16x32_bf16(qh1, kl1, acc, 0, 0, 0);
      sacc[st] = acc;
    }

    // online softmax (rows live at lane-groups sharing l>>4; reduce over lc)
    float corr[4];
#pragma unroll
    for (int r = 0; r < 4; ++r) {
      float pm = fmaxf(fmaxf(sacc[0][r], sacc[1][r]), fmaxf(sacc[2][r], sacc[3][r]));
      pm = fmaxf(pm, __shfl_xor(pm, 1));
      pm = fmaxf(pm, __shfl_xor(pm, 2));
      pm = fmaxf(pm, __shfl_xor(pm, 4));
      pm = fmaxf(pm, __shfl_xor(pm, 8));
      float mn = fmaxf(m[r], pm);
      corr[r] = exp2f(m[r] - mn);
      m[r] = mn;
    }
#pragma unroll
    for (int st = 0; st < 4; ++st)
#pragma unroll
      for (int r = 0; r < 4; ++r)
        sacc[st][r] = exp2f(sacc[st][r] - m[r]);
#pragma unroll
    for (int r = 0; r < 4; ++r) {
      float ps = (sacc[0][r] + sacc[1][r]) + (sacc[2][r] + sacc[3][r]);
      ps += __shfl_xor(ps, 1);
      ps += __shfl_xor(ps, 2);
      ps += __shfl_xor(ps, 4);
      ps += __shfl_xor(ps, 8);
      lsum[r] = lsum[r] * corr[r] + ps;
    }
#pragma unroll
    for (int ct = 0; ct < 4; ++ct)
#pragma unroll
      for (int r = 0; r < 4; ++r) o[ct][r] *= corr[r];

    // P -> LDS (D layout) -> A-frag readback
#pragma unroll
    for (int st = 0; st < 4; ++st)
#pragma unroll
      for (int r = 0; r < 4; ++r)
        Pl[(lr * 4 + r) * 80 + st * 16 + lc] = f2bf(sacc[st][r]);
    bf16x8 pa0 = *(const bf16x8*)&Pl[lc * 80 + lr * 8];
    bf16x8 pa1 = *(const bf16x8*)&Pl[lc * 80 + 32 + lr * 8];

    // PV: O += P @ V  (V^T tile image, B-frag reads)
#pragma unroll
    for (int ct = 0; ct < 4; ++ct) {
      int row = ct * 16 + lc;
      int sw = (row & 7) << 4;
      bf16x8 v0 = *(const bf16x8*)&VtT[((row * 128 + lr * 16) ^ sw) >> 1];
      bf16x8 v1 = *(const bf16x8*)&VtT[((row * 128 + 64 + lr * 16) ^ sw) >> 1];
      o[ct] = __builtin_amdgcn_mfma_f32_16x16x32_bf16(pa0, v0, o[ct], 0, 0, 0);
      o[ct] = __builtin_amdgcn_mfma_f32_16x16x32_bf16(pa1, v1, o[ct], 0, 0, 0);
    }
    __syncthreads();
  }

  float invl[4];
#pragma unroll
  for (int r = 0; r < 4; ++r) invl[r] = 1.0f / lsum[r];
#pragma unroll
  for (int r = 0; r < 4; ++r) {
    float* orow = attn + (size_t)(b * 2048 + q0 + lr * 4 + r) * 1024 + h * 64 + lc;
#pragma unroll
    for (int ct = 0; ct < 4; ++ct) orow[ct * 16] = o[ct][r] * invl[r];
  }
}

// ---------------------------------------------------------------------------
// k_mean / pos / aw (unchanged from round 1 — verified)
// ---------------------------------------------------------------------------
__global__ __launch_bounds__(256) void kmean_kernel(const float* __restrict__ qkv,
                                                    float* __restrict__ km) {
  int bh = blockIdx.x;
  int b = bh >> 4, h = bh & 15;
  int c = threadIdx.x & 63, seg = threadIdx.x >> 6;
  const float* base = qkv + (size_t)b * 2048 * 3072 + h * 192 + 64 + c;
  float s = 0.f;
  for (int t = seg * 512; t < seg * 512 + 512; ++t) s += base[(size_t)t * 3072];
  __shared__ float red[4][64];
  red[seg][c] = s;
  __syncthreads();
  if (seg == 0) {
    float v = red[0][c] + red[1][c] + red[2][c] + red[3][c];
    km[(bh << 6) + c] = v * (1.0f / 2048.0f);
  }
}

__global__ __launch_bounds__(256) void pos_kernel(const float* __restrict__ qkv,
                                                  const float* __restrict__ km,
                                                  float* __restrict__ pos) {
  __shared__ float kms[1024];
  int blk = blockIdx.x;
  int b = (blk * 4) >> 11;
  for (int i = threadIdx.x; i < 1024; i += 256) {
    int h = i >> 6, c = i & 63;
    kms[i] = km[(b * 16 + h) * 64 + c] * 0.125f;
  }
  __syncthreads();
  int w = threadIdx.x >> 6, lane = threadIdx.x & 63;
  int row = blk * 4 + w;
  const float* qrow = qkv + (size_t)row * 3072;
  float p = 0.f;
#pragma unroll
  for (int h = 0; h < 16; ++h) p = fmaf(qrow[h * 192 + lane], kms[h * 64 + lane], p);
#pragma unroll
  for (int off = 32; off; off >>= 1) p += __shfl_xor(p, off, 64);
  if (lane == 0) pos[row] = p;
}

__global__ __launch_bounds__(1024) void aw_kernel(const float* __restrict__ pos,
                                                  float* __restrict__ aw) {
  int b = blockIdx.x, tid = threadIdx.x;
  float p0 = pos[b * 2048 + tid], p1 = pos[b * 2048 + 1024 + tid];
  float mn = fminf(p0, p1), mx = fmaxf(p0, p1);
#pragma unroll
  for (int off = 32; off; off >>= 1) {
    mn = fminf(mn, __shfl_xor(mn, off, 64));
    mx = fmaxf(mx, __shfl_xor(mx, off, 64));
  }
  __shared__ float smn[16], smx[16];
  int wave = tid >> 6, lane = tid & 63;
  if (lane == 0) { smn[wave] = mn; smx[wave] = mx; }
  __syncthreads();
  if (tid < 64) {
    mn = (lane < 16) ? smn[lane] : 3.0e38f;
    mx = (lane < 16) ? smx[lane] : -3.0e38f;
#pragma unroll
    for (int off = 8; off; off >>= 1) {
      mn = fminf(mn, __shfl_xor(mn, off, 64));
      mx = fmaxf(mx, __shfl_xor(mx, off, 64));
    }
    if (lane == 0) { smn[0] = mn; smx[0] = mx; }
  }
  __syncthreads();
  float MN = smn[0], inv = 1.0f / (smx[0] - MN + 1e-6f);
  aw[b * 2048 + tid] = (p0 - MN) * inv;
  aw[b * 2048 + 1024 + tid] = (p1 - MN) * inv;
}

// ---------------------------------------------------------------------------
extern "C" void kernel_launch(void* const* d_in, const int* in_sizes, int n_in,
                              void* d_out, int out_size, void* d_ws, size_t ws_size,
                              hipStream_t stream) {
  const float* x      = (const float*)d_in[0];
  const float* W_qkv  = (const float*)d_in[1];
  const float* b_qkv  = (const float*)d_in[2];
  const float* W_proj = (const float*)d_in[3];
  const float* b_proj = (const float*)d_in[4];
  float* out = (float*)d_out;

  float* ws   = (float*)d_ws;
  float* qkv  = ws;                    // 12,582,912 floats (48 MB)
  float* attn = ws + 12582912;         // 4,194,304 floats (16 MB)
  float* km   = attn + 4194304;        // 2048
  float* pos  = km + 2048;             // 4096
  float* aw   = pos + 4096;            // 4096
  unsigned short* bfb = (unsigned short*)(aw + 4096);  // 16B-aligned
  unsigned short* Qh  = bfb;                 // 4,194,304 shorts (8 MB) each
  unsigned short* Ql  = Qh + 4194304;
  unsigned short* Khg = Ql + 4194304;
  unsigned short* Klg = Khg + 4194304;
  unsigned short* Vtg = Klg + 4194304;

  // 1) qkv = x @ W_qkv + b_qkv
  gemm_bias<<<dim3(24, 32), 256, 0, stream>>>(x, W_qkv, b_qkv, qkv,
                                              4096, 3072, 1024, nullptr);
  // 2) bf16 operand pre-pass
  convert_kernel<<<dim3(32, 32), 256, 0, stream>>>(qkv, Qh, Ql, Khg, Klg, Vtg);
  // 3) MFMA flash attention
  attn_mfma<<<dim3(32, 32), 256, 0, stream>>>(Qh, Ql, Khg, Klg, Vtg, attn);
  // 4) k_mean, pos, aw
  kmean_kernel<<<32, 256, 0, stream>>>(qkv, km);
  pos_kernel<<<1024, 256, 0, stream>>>(qkv, km, pos);
  aw_kernel<<<2, 1024, 0, stream>>>(pos, aw);
  // 5) out = (aw ⊙ attn) @ W_proj + b_proj
  gemm_bias<<<dim3(8, 32), 256, 0, stream>>>(attn, W_proj, b_proj, out,
                                             4096, 1024, 1024, aw);
}

// Round 3
// 388.498 us; speedup vs baseline: 5.2633x; 1.8473x over previous
//
#include <hip/hip_runtime.h>
#include <hip/hip_bf16.h>

// Problem constants: B=2, T=2048, W=1024, H=16, C=64
// scale^2 = 1/8 folded into Q along with log2(e) (exp2-domain softmax).

#define LOG2E 1.4426950408889634f

typedef float f32x4 __attribute__((ext_vector_type(4)));
typedef short bf16x8 __attribute__((ext_vector_type(8)));

__device__ __forceinline__ unsigned short f2bf(float f) {
  union { float f; unsigned int u; } v; v.f = f;
  unsigned int r = v.u + 0x7fffu + ((v.u >> 16) & 1u);
  return (unsigned short)(r >> 16);
}
__device__ __forceinline__ float bf2f(unsigned short h) {
  union { unsigned int u; float f; } v; v.u = ((unsigned int)h) << 16;
  return v.f;
}

// ---------------------------------------------------------------------------
// conv_split: fp32 -> bf16 hi/lo (a ~= hi + lo, err ~2^-17), optional rowscale.
// Thread handles 8 consecutive floats. grid = nelem/(256*8).
// ---------------------------------------------------------------------------
__global__ __launch_bounds__(256) void conv_split(
    const float* __restrict__ in, unsigned short* __restrict__ hi,
    unsigned short* __restrict__ lo, const float* __restrict__ rowscale,
    int ncols) {
  size_t base = ((size_t)blockIdx.x * 256 + threadIdx.x) * 8;
  float rs = rowscale ? rowscale[base / (size_t)ncols] : 1.0f;
  float4 v0 = *(const float4*)&in[base];
  float4 v1 = *(const float4*)&in[base + 4];
  float f[8] = {v0.x, v0.y, v0.z, v0.w, v1.x, v1.y, v1.z, v1.w};
  unsigned int hw[4], lw[4];
#pragma unroll
  for (int p = 0; p < 4; ++p) {
    float a = f[2 * p] * rs, b = f[2 * p + 1] * rs;
    unsigned short ha = f2bf(a), hb = f2bf(b);
    unsigned short la = f2bf(a - bf2f(ha)), lb = f2bf(b - bf2f(hb));
    hw[p] = (unsigned int)ha | ((unsigned int)hb << 16);
    lw[p] = (unsigned int)la | ((unsigned int)lb << 16);
  }
  uint4 H = {hw[0], hw[1], hw[2], hw[3]};
  uint4 L = {lw[0], lw[1], lw[2], lw[3]};
  *(uint4*)&hi[base] = H;
  *(uint4*)&lo[base] = L;
}

// ---------------------------------------------------------------------------
// conv_split_T: in [K][N] fp32 -> out [N][K] bf16 hi/lo (LDS 32x32 transpose).
// grid (N/32, K/32), block 256.
// ---------------------------------------------------------------------------
__global__ __launch_bounds__(256) void conv_split_T(
    const float* __restrict__ in, unsigned short* __restrict__ hi,
    unsigned short* __restrict__ lo, int K, int N) {
  __shared__ float t[32][33];
  const int n0 = blockIdx.x * 32, k0 = blockIdx.y * 32;
  const int r = threadIdx.x >> 3, c4 = (threadIdx.x & 7) * 4;
  float4 v = *(const float4*)&in[(size_t)(k0 + r) * N + n0 + c4];
  t[r][c4 + 0] = v.x; t[r][c4 + 1] = v.y; t[r][c4 + 2] = v.z; t[r][c4 + 3] = v.w;
  __syncthreads();
  unsigned int hw[2], lw[2];
#pragma unroll
  for (int p = 0; p < 2; ++p) {
    float a = t[c4 + 2 * p][r], b = t[c4 + 2 * p + 1][r];
    unsigned short ha = f2bf(a), hb = f2bf(b);
    unsigned short la = f2bf(a - bf2f(ha)), lb = f2bf(b - bf2f(hb));
    hw[p] = (unsigned int)ha | ((unsigned int)hb << 16);
    lw[p] = (unsigned int)la | ((unsigned int)lb << 16);
  }
  size_t o = (size_t)(n0 + r) * K + k0 + c4;
  *(uint2*)&hi[o] = make_uint2(hw[0], hw[1]);
  *(uint2*)&lo[o] = make_uint2(lw[0], lw[1]);
}

// ---------------------------------------------------------------------------
// Split-bf16 MFMA GEMM: C[M,N] = (Ah+Al)[M,K] @ (Bh+Bl)^T?[N,K] + bias
// A hi/lo row-major [M][K]; B hi/lo row-major [N][K] (i.e. B-transposed).
// 3-product emulation: AhBh + AhBl + AlBh. Tile 128x128, BK=32, 4 waves 2x2,
// double-buffered LDS (2x32KB), global_load_lds width-16, linear layout
// (BK=32 rows = 64B -> each frag ds_read_b128 covers a contiguous 1KB:
// conflict-free without swizzle).
// ---------------------------------------------------------------------------
__global__ __launch_bounds__(256, 2) void gemm_mfma_split(
    const unsigned short* __restrict__ Ah, const unsigned short* __restrict__ Al,
    const unsigned short* __restrict__ Bh, const unsigned short* __restrict__ Bl,
    const float* __restrict__ bias, float* __restrict__ C,
    int M, int N, int K) {
  __shared__ __align__(16) unsigned short lds[2][16384];  // per buf: Ah|Al|Bh|Bl 4096 shorts each

  const int tid = threadIdx.x;
  const int w = tid >> 6, l = tid & 63;
  const int lc = l & 15, lr = l >> 4;
  const int wr = w >> 1, wc = w & 1;
  const int m0 = blockIdx.y * 128, n0 = blockIdx.x * 128;

  f32x4 acc[4][4];
#pragma unroll
  for (int mi = 0; mi < 4; ++mi)
#pragma unroll
    for (int ni = 0; ni < 4; ++ni) acc[mi][ni] = (f32x4){0.f, 0.f, 0.f, 0.f};

  // wave w stages array w: 0=Ah,1=Al,2=Bh,3=Bl (8KB = 8 chunks of 1KB each)
  const unsigned short* src = (w == 0) ? Ah : (w == 1) ? Al : (w == 2) ? Bh : Bl;
  const int rowbase = (w < 2) ? m0 : n0;
  const int lrow = l >> 2, lkk = (l & 3) * 8;

  const int NT = K / 32;
  int buf = 0;

#define STAGE(B_, KT_)                                                         \
  {                                                                            \
    unsigned short* dst = lds[B_] + w * 4096;                                  \
    _Pragma("unroll") for (int c = 0; c < 8; ++c) {                            \
      const unsigned short* g =                                                \
          src + (size_t)(rowbase + c * 16 + lrow) * K + (KT_) + lkk;           \
      __builtin_amdgcn_global_load_lds(                                        \
          (const __attribute__((address_space(1))) unsigned int*)g,            \
          (__attribute__((address_space(3))) unsigned int*)(dst + c * 512),    \
          16, 0, 0);                                                           \
    }                                                                          \
  }

  STAGE(0, 0);
  asm volatile("s_waitcnt vmcnt(0)");
  __syncthreads();

  for (int t = 0; t < NT; ++t) {
    if (t + 1 < NT) STAGE(buf ^ 1, (t + 1) * 32);

    const unsigned short* bp = lds[buf];
    bf16x8 ah[4], al[4], bh[4], bl[4];
#pragma unroll
    for (int mi = 0; mi < 4; ++mi) {
      int ro = (wr * 64 + mi * 16 + lc) * 32 + lr * 8;
      ah[mi] = *(const bf16x8*)&bp[ro];
      al[mi] = *(const bf16x8*)&bp[4096 + ro];
    }
#pragma unroll
    for (int ni = 0; ni < 4; ++ni) {
      int co = (wc * 64 + ni * 16 + lc) * 32 + lr * 8;
      bh[ni] = *(const bf16x8*)&bp[8192 + co];
      bl[ni] = *(const bf16x8*)&bp[12288 + co];
    }

    __builtin_amdgcn_s_setprio(1);
#pragma unroll
    for (int mi = 0; mi < 4; ++mi)
#pragma unroll
      for (int ni = 0; ni < 4; ++ni) {
        acc[mi][ni] = __builtin_amdgcn_mfma_f32_16x16x32_bf16(ah[mi], bh[ni], acc[mi][ni], 0, 0, 0);
        acc[mi][ni] = __builtin_amdgcn_mfma_f32_16x16x32_bf16(ah[mi], bl[ni], acc[mi][ni], 0, 0, 0);
        acc[mi][ni] = __builtin_amdgcn_mfma_f32_16x16x32_bf16(al[mi], bh[ni], acc[mi][ni], 0, 0, 0);
      }
    __builtin_amdgcn_s_setprio(0);

    __syncthreads();
    buf ^= 1;
  }
#undef STAGE

#pragma unroll
  for (int mi = 0; mi < 4; ++mi)
#pragma unroll
    for (int r = 0; r < 4; ++r) {
      int row = m0 + wr * 64 + mi * 16 + lr * 4 + r;
#pragma unroll
      for (int ni = 0; ni < 4; ++ni) {
        int col = n0 + wc * 64 + ni * 16 + lc;
        C[(size_t)row * N + col] = acc[mi][ni][r] + bias[col];
      }
    }
}

// ---------------------------------------------------------------------------
// Pre-pass: qkv fp32 -> bf16 operands for MFMA attention (round-2, verified).
// ---------------------------------------------------------------------------
__global__ __launch_bounds__(256) void convert_kernel(
    const float* __restrict__ qkv,
    unsigned short* __restrict__ Qh, unsigned short* __restrict__ Ql,
    unsigned short* __restrict__ Khg, unsigned short* __restrict__ Klg,
    unsigned short* __restrict__ Vtg) {
  const int stile = blockIdx.x, bh = blockIdx.y;
  const int b = bh >> 4, h = bh & 15;
  const int tid = threadIdx.x;
  const int s = tid >> 2;
  const int cg = (tid & 3) << 4;
  const int t = stile * 64 + s;
  const float* row = qkv + (size_t)(b * 2048 + t) * 3072 + h * 192;
  const float QS = 0.125f * LOG2E;

  __shared__ unsigned short vs[64][72];

  {
    unsigned int* qh32 = (unsigned int*)(Qh + ((size_t)bh * 2048 + t) * 64 + cg);
    unsigned int* ql32 = (unsigned int*)(Ql + ((size_t)bh * 2048 + t) * 64 + cg);
#pragma unroll
    for (int j = 0; j < 4; ++j) {
      float4 v = *(const float4*)&row[cg + j * 4];
      float f[4] = {v.x * QS, v.y * QS, v.z * QS, v.w * QS};
      unsigned short hh[4], llo[4];
#pragma unroll
      for (int e = 0; e < 4; ++e) {
        hh[e] = f2bf(f[e]);
        llo[e] = f2bf(f[e] - bf2f(hh[e]));
      }
      qh32[j * 2 + 0] = (unsigned int)hh[0] | ((unsigned int)hh[1] << 16);
      qh32[j * 2 + 1] = (unsigned int)hh[2] | ((unsigned int)hh[3] << 16);
      ql32[j * 2 + 0] = (unsigned int)llo[0] | ((unsigned int)llo[1] << 16);
      ql32[j * 2 + 1] = (unsigned int)llo[2] | ((unsigned int)llo[3] << 16);
    }
  }
  {
    unsigned int* kh32 = (unsigned int*)(Khg + (size_t)(bh * 32 + stile) * 4096);
    unsigned int* kl32 = (unsigned int*)(Klg + (size_t)(bh * 32 + stile) * 4096);
    const int sw = (s & 7) << 4;
#pragma unroll
    for (int j = 0; j < 4; ++j) {
      float4 v = *(const float4*)&row[64 + cg + j * 4];
      float f[4] = {v.x, v.y, v.z, v.w};
#pragma unroll
      for (int p = 0; p < 2; ++p) {
        int c0 = cg + j * 4 + p * 2;
        unsigned short h0 = f2bf(f[p * 2]), h1 = f2bf(f[p * 2 + 1]);
        unsigned short l0 = f2bf(f[p * 2] - bf2f(h0));
        unsigned short l1 = f2bf(f[p * 2 + 1] - bf2f(h1));
        int byte = (s * 128 + c0 * 2) ^ sw;
        kh32[byte >> 2] = (unsigned int)h0 | ((unsigned int)h1 << 16);
        kl32[byte >> 2] = (unsigned int)l0 | ((unsigned int)l1 << 16);
      }
    }
  }
#pragma unroll
  for (int j = 0; j < 4; ++j) {
    float4 v = *(const float4*)&row[128 + cg + j * 4];
    vs[s][cg + j * 4 + 0] = f2bf(v.x);
    vs[s][cg + j * 4 + 1] = f2bf(v.y);
    vs[s][cg + j * 4 + 2] = f2bf(v.z);
    vs[s][cg + j * 4 + 3] = f2bf(v.w);
  }
  __syncthreads();
  {
    const int c = tid >> 2;
    const int sb = (tid & 3) << 4;
    unsigned int* vt32 = (unsigned int*)(Vtg + (size_t)(bh * 32 + stile) * 4096);
    const int sw = (c & 7) << 4;
#pragma unroll
    for (int p = 0; p < 8; ++p) {
      int ss = sb + p * 2;
      unsigned int wv = (unsigned int)vs[ss][c] | ((unsigned int)vs[ss + 1][c] << 16);
      int byte = (c * 128 + ss * 2) ^ sw;
      vt32[byte >> 2] = wv;
    }
  }
}

// ---------------------------------------------------------------------------
// MFMA flash attention (round-2, verified).
// ---------------------------------------------------------------------------
__global__ __launch_bounds__(256, 4) void attn_mfma(
    const unsigned short* __restrict__ Qh, const unsigned short* __restrict__ Ql,
    const unsigned short* __restrict__ Khg, const unsigned short* __restrict__ Klg,
    const unsigned short* __restrict__ Vtg, float* __restrict__ attn) {
  const int qt = blockIdx.x, bh = blockIdx.y;
  const int b = bh >> 4, h = bh & 15;
  const int tid = threadIdx.x;
  const int w = tid >> 6, l = tid & 63;
  const int lc = l & 15, lr = l >> 4;

  __shared__ __align__(16) unsigned short lds[12288 + 4 * 1280];
  unsigned short* KhT = lds;
  unsigned short* KlT = lds + 4096;
  unsigned short* VtT = lds + 8192;
  unsigned short* Pl  = lds + 12288 + w * 1280;

  const int q0 = qt * 64 + w * 16;
  bf16x8 qh0, qh1, ql0, ql1;
  {
    size_t base = ((size_t)bh * 2048 + q0 + lc) * 64 + lr * 8;
    qh0 = *(const bf16x8*)&Qh[base];
    qh1 = *(const bf16x8*)&Qh[base + 32];
    ql0 = *(const bf16x8*)&Ql[base];
    ql1 = *(const bf16x8*)&Ql[base + 32];
  }

  f32x4 o[4];
  float m[4], lsum[4];
#pragma unroll
  for (int r = 0; r < 4; ++r) { m[r] = -1e30f; lsum[r] = 0.f; }
#pragma unroll
  for (int ct = 0; ct < 4; ++ct) o[ct] = (f32x4){0.f, 0.f, 0.f, 0.f};

  const unsigned short* pKh = Khg + (size_t)bh * 32 * 4096;
  const unsigned short* pKl = Klg + (size_t)bh * 32 * 4096;
  const unsigned short* pVt = Vtg + (size_t)bh * 32 * 4096;

  for (int kvt = 0; kvt < 32; ++kvt) {
    {
      size_t tb = (size_t)kvt * 4096;
#pragma unroll
      for (int i = 0; i < 6; ++i) {
        int c = w * 6 + i;
        int arr = c >> 3;
        const unsigned short* gb =
            (arr == 0) ? (pKh + tb) : (arr == 1) ? (pKl + tb) : (pVt + tb);
        const unsigned short* g = gb + (c & 7) * 512 + l * 8;
        unsigned short* dst = lds + c * 512;
        __builtin_amdgcn_global_load_lds(
            (const __attribute__((address_space(1))) unsigned int*)g,
            (__attribute__((address_space(3))) unsigned int*)dst, 16, 0, 0);
      }
    }
    __syncthreads();

    f32x4 sacc[4];
#pragma unroll
    for (int st = 0; st < 4; ++st) {
      int row = st * 16 + lc;
      int sw = (row & 7) << 4;
      int i0 = ((row * 128 + lr * 16) ^ sw) >> 1;
      int i1 = ((row * 128 + 64 + lr * 16) ^ sw) >> 1;
      bf16x8 kh0 = *(const bf16x8*)&KhT[i0];
      bf16x8 kh1 = *(const bf16x8*)&KhT[i1];
      bf16x8 kl0 = *(const bf16x8*)&KlT[i0];
      bf16x8 kl1 = *(const bf16x8*)&KlT[i1];
      f32x4 acc = (f32x4){0.f, 0.f, 0.f, 0.f};
      acc = __builtin_amdgcn_mfma_f32_16x16x32_bf16(qh0, kh0, acc, 0, 0, 0);
      acc = __builtin_amdgcn_mfma_f32_16x16x32_bf16(qh1, kh1, acc, 0, 0, 0);
      acc = __builtin_amdgcn_mfma_f32_16x16x32_bf16(ql0, kh0, acc, 0, 0, 0);
      acc = __builtin_amdgcn_mfma_f32_16x16x32_bf16(ql1, kh1, acc, 0, 0, 0);
      acc = __builtin_amdgcn_mfma_f32_16x16x32_bf16(qh0, kl0, acc, 0, 0, 0);
      acc = __builtin_amdgcn_mfma_f32_16x16x32_bf16(qh1, kl1, acc, 0, 0, 0);
      sacc[st] = acc;
    }

    float corr[4];
#pragma unroll
    for (int r = 0; r < 4; ++r) {
      float pm = fmaxf(fmaxf(sacc[0][r], sacc[1][r]), fmaxf(sacc[2][r], sacc[3][r]));
      pm = fmaxf(pm, __shfl_xor(pm, 1));
      pm = fmaxf(pm, __shfl_xor(pm, 2));
      pm = fmaxf(pm, __shfl_xor(pm, 4));
      pm = fmaxf(pm, __shfl_xor(pm, 8));
      float mn = fmaxf(m[r], pm);
      corr[r] = exp2f(m[r] - mn);
      m[r] = mn;
    }
#pragma unroll
    for (int st = 0; st < 4; ++st)
#pragma unroll
      for (int r = 0; r < 4; ++r)
        sacc[st][r] = exp2f(sacc[st][r] - m[r]);
#pragma unroll
    for (int r = 0; r < 4; ++r) {
      float ps = (sacc[0][r] + sacc[1][r]) + (sacc[2][r] + sacc[3][r]);
      ps += __shfl_xor(ps, 1);
      ps += __shfl_xor(ps, 2);
      ps += __shfl_xor(ps, 4);
      ps += __shfl_xor(ps, 8);
      lsum[r] = lsum[r] * corr[r] + ps;
    }
#pragma unroll
    for (int ct = 0; ct < 4; ++ct)
#pragma unroll
      for (int r = 0; r < 4; ++r) o[ct][r] *= corr[r];

#pragma unroll
    for (int st = 0; st < 4; ++st)
#pragma unroll
      for (int r = 0; r < 4; ++r)
        Pl[(lr * 4 + r) * 80 + st * 16 + lc] = f2bf(sacc[st][r]);
    bf16x8 pa0 = *(const bf16x8*)&Pl[lc * 80 + lr * 8];
    bf16x8 pa1 = *(const bf16x8*)&Pl[lc * 80 + 32 + lr * 8];

#pragma unroll
    for (int ct = 0; ct < 4; ++ct) {
      int row = ct * 16 + lc;
      int sw = (row & 7) << 4;
      bf16x8 v0 = *(const bf16x8*)&VtT[((row * 128 + lr * 16) ^ sw) >> 1];
      bf16x8 v1 = *(const bf16x8*)&VtT[((row * 128 + 64 + lr * 16) ^ sw) >> 1];
      o[ct] = __builtin_amdgcn_mfma_f32_16x16x32_bf16(pa0, v0, o[ct], 0, 0, 0);
      o[ct] = __builtin_amdgcn_mfma_f32_16x16x32_bf16(pa1, v1, o[ct], 0, 0, 0);
    }
    __syncthreads();
  }

  float invl[4];
#pragma unroll
  for (int r = 0; r < 4; ++r) invl[r] = 1.0f / lsum[r];
#pragma unroll
  for (int r = 0; r < 4; ++r) {
    float* orow = attn + (size_t)(b * 2048 + q0 + lr * 4 + r) * 1024 + h * 64 + lc;
#pragma unroll
    for (int ct = 0; ct < 4; ++ct) orow[ct * 16] = o[ct][r] * invl[r];
  }
}

// ---------------------------------------------------------------------------
// k_mean partials from swizzled K images: kmp[bh][seg][c] = sum of 256 t's.
// grid (32 bh, 8 seg), block 256 (4 tiles of 64 rows each).
// ---------------------------------------------------------------------------
__global__ __launch_bounds__(256) void kmean_part(
    const unsigned short* __restrict__ Khg, const unsigned short* __restrict__ Klg,
    float* __restrict__ kmp) {
  const int bh = blockIdx.x, seg = blockIdx.y;
  const int c = threadIdx.x & 63, sub = threadIdx.x >> 6;
  const int tile = seg * 4 + sub;
  const unsigned short* kh = Khg + (size_t)(bh * 32 + tile) * 4096;
  const unsigned short* kl = Klg + (size_t)(bh * 32 + tile) * 4096;
  float sum = 0.f;
#pragma unroll 8
  for (int s = 0; s < 64; ++s) {
    int sidx = ((s * 128 + c * 2) ^ ((s & 7) << 4)) >> 1;
    sum += bf2f(kh[sidx]) + bf2f(kl[sidx]);
  }
  __shared__ float red[4][64];
  red[sub][c] = sum;
  __syncthreads();
  if (sub == 0)
    kmp[(size_t)(bh * 8 + seg) * 64 + c] =
        red[0][c] + red[1][c] + red[2][c] + red[3][c];
}

// ---------------------------------------------------------------------------
// pos[row] = (1/8) * sum_{h,c} q*km ; q read from scaled Qh/Ql (q' = q*QS),
// so kms = km/(2048*LOG2E) gives q'*kms summed = (1/8) q*km_mean.
// grid 1024 blocks (4 rows each), block 256.
// ---------------------------------------------------------------------------
__global__ __launch_bounds__(256) void pos_kernel(
    const unsigned short* __restrict__ Qh, const unsigned short* __restrict__ Ql,
    const float* __restrict__ kmp, float* __restrict__ pos) {
  __shared__ float kms[1024];
  int blk = blockIdx.x;
  int b = (blk * 4) >> 11;
  for (int i = threadIdx.x; i < 1024; i += 256) {
    int h = i >> 6, cc = i & 63;
    float s = 0.f;
#pragma unroll
    for (int seg = 0; seg < 8; ++seg)
      s += kmp[(size_t)((b * 16 + h) * 8 + seg) * 64 + cc];
    kms[i] = s * (1.0f / 2048.0f) * (1.0f / LOG2E);
  }
  __syncthreads();
  int w = threadIdx.x >> 6, lane = threadIdx.x & 63;
  int row = blk * 4 + w;
  int t = row & 2047;
  float p = 0.f;
#pragma unroll
  for (int h = 0; h < 16; ++h) {
    size_t idx = ((size_t)(b * 16 + h) * 2048 + t) * 64 + lane;
    p = fmaf(bf2f(Qh[idx]) + bf2f(Ql[idx]), kms[h * 64 + lane], p);
  }
#pragma unroll
  for (int off = 32; off; off >>= 1) p += __shfl_xor(p, off, 64);
  if (lane == 0) pos[row] = p;
}

// ---------------------------------------------------------------------------
// aw[b,t] = (pos - min) / (max - min + 1e-6) (round-1, verified)
// ---------------------------------------------------------------------------
__global__ __launch_bounds__(1024) void aw_kernel(const float* __restrict__ pos,
                                                  float* __restrict__ aw) {
  int b = blockIdx.x, tid = threadIdx.x;
  float p0 = pos[b * 2048 + tid], p1 = pos[b * 2048 + 1024 + tid];
  float mn = fminf(p0, p1), mx = fmaxf(p0, p1);
#pragma unroll
  for (int off = 32; off; off >>= 1) {
    mn = fminf(mn, __shfl_xor(mn, off, 64));
    mx = fmaxf(mx, __shfl_xor(mx, off, 64));
  }
  __shared__ float smn[16], smx[16];
  int wave = tid >> 6, lane = tid & 63;
  if (lane == 0) { smn[wave] = mn; smx[wave] = mx; }
  __syncthreads();
  if (tid < 64) {
    mn = (lane < 16) ? smn[lane] : 3.0e38f;
    mx = (lane < 16) ? smx[lane] : -3.0e38f;
#pragma unroll
    for (int off = 8; off; off >>= 1) {
      mn = fminf(mn, __shfl_xor(mn, off, 64));
      mx = fmaxf(mx, __shfl_xor(mx, off, 64));
    }
    if (lane == 0) { smn[0] = mn; smx[0] = mx; }
  }
  __syncthreads();
  float MN = smn[0], inv = 1.0f / (smx[0] - MN + 1e-6f);
  aw[b * 2048 + tid] = (p0 - MN) * inv;
  aw[b * 2048 + 1024 + tid] = (p1 - MN) * inv;
}

// ---------------------------------------------------------------------------
// Workspace layout (byte offsets; peak 109,051,904 B — within round-2-proven
// footprint). qkv fp32 dies after convert_kernel (kmean/pos read bf16 images),
// freeing its region for A2/Wp/kmp/pos/aw. xh/xl die after gemm_qkv, freeing
// their region for attn fp32. Wq dies after gemm_qkv, overlaid by images.
// ---------------------------------------------------------------------------
extern "C" void kernel_launch(void* const* d_in, const int* in_sizes, int n_in,
                              void* d_out, int out_size, void* d_ws, size_t ws_size,
                              hipStream_t stream) {
  const float* x      = (const float*)d_in[0];
  const float* W_qkv  = (const float*)d_in[1];
  const float* b_qkv  = (const float*)d_in[2];
  const float* W_proj = (const float*)d_in[3];
  const float* b_proj = (const float*)d_in[4];
  float* out = (float*)d_out;

  char* wsb = (char*)d_ws;
  float* qkv_f = (float*)wsb;                               // [0, 50.33M) live: gemm_qkv..convert
  unsigned short* A2h = (unsigned short*)wsb;               // [0, 8.39M)   live: conv_attn..gemm_proj
  unsigned short* A2l = A2h + 4194304;                      // [8.39M, 16.78M)
  unsigned short* Wph = (unsigned short*)(wsb + 16777216);  // [16.78M, 18.87M)
  unsigned short* Wpl = Wph + 1048576;                      // [18.87M, 20.97M)
  float* kmp = (float*)(wsb + 20971520);                    // 16384 f
  float* pos = kmp + 16384;                                 // 4096 f
  float* aw  = pos + 4096;                                  // 4096 f (ends 21.07M)
  unsigned short* xh = (unsigned short*)(wsb + 50331648);   // [50.33M, 58.72M) live: ..gemm_qkv
  unsigned short* xl = xh + 4194304;                        // [58.72M, 67.11M)
  float* attn_f = (float*)(wsb + 50331648);                 // same region, live: attn..conv_attn
  unsigned short* Wqh = (unsigned short*)(wsb + 67108864);  // [67.11M, 73.4M) live: ..gemm_qkv
  unsigned short* Wql = Wqh + 3145728;                      // [73.4M, 79.69M)
  unsigned short* Qh  = (unsigned short*)(wsb + 67108864);  // images overlay Wq after gemm_qkv
  unsigned short* Ql  = Qh + 4194304;
  unsigned short* Khg = Ql + 4194304;
  unsigned short* Klg = Khg + 4194304;
  unsigned short* Vtg = Klg + 4194304;                      // ends 109.05M

  // 1) split x and W_qkv^T to bf16 hi/lo
  conv_split<<<2048, 256, 0, stream>>>(x, xh, xl, nullptr, 1024);
  conv_split_T<<<dim3(96, 32), 256, 0, stream>>>(W_qkv, Wqh, Wql, 1024, 3072);
  // 2) qkv = x @ W_qkv + b (split-bf16 MFMA)
  gemm_mfma_split<<<dim3(24, 32), 256, 0, stream>>>(xh, xl, Wqh, Wql, b_qkv,
                                                    qkv_f, 4096, 3072, 1024);
  // 3) attention operand images (overwrites Wq region)
  convert_kernel<<<dim3(32, 32), 256, 0, stream>>>(qkv_f, Qh, Ql, Khg, Klg, Vtg);
  // 4) k_mean partials / pos / aw (from bf16 images; qkv_f now dead)
  kmean_part<<<dim3(32, 8), 256, 0, stream>>>(Khg, Klg, kmp);
  pos_kernel<<<1024, 256, 0, stream>>>(Qh, Ql, kmp, pos);
  aw_kernel<<<2, 1024, 0, stream>>>(pos, aw);
  // 5) MFMA flash attention (overwrites x region)
  attn_mfma<<<dim3(32, 32), 256, 0, stream>>>(Qh, Ql, Khg, Klg, Vtg, attn_f);
  // 6) A2 = aw ⊙ attn, split bf16 (overwrites qkv region); W_proj^T split
  conv_split<<<2048, 256, 0, stream>>>(attn_f, A2h, A2l, aw, 1024);
  conv_split_T<<<dim3(32, 32), 256, 0, stream>>>(W_proj, Wph, Wpl, 1024, 1024);
  // 7) out = A2 @ W_proj + b (split-bf16 MFMA)
  gemm_mfma_split<<<dim3(8, 32), 256, 0, stream>>>(A2h, A2l, Wph, Wpl, b_proj,
                                                   out, 4096, 1024, 1024);
}

// Round 4
// 349.841 us; speedup vs baseline: 5.8448x; 1.1105x over previous
//
#include <hip/hip_runtime.h>
#include <hip/hip_bf16.h>

// Problem constants: B=2, T=2048, W=1024, H=16, C=64
// scale^2 = 1/8 folded into Q along with log2(e) (exp2-domain softmax).

#define LOG2E 1.4426950408889634f

typedef float f32x4 __attribute__((ext_vector_type(4)));
typedef short bf16x8 __attribute__((ext_vector_type(8)));

__device__ __forceinline__ unsigned short f2bf(float f) {
  union { float f; unsigned int u; } v; v.f = f;
  unsigned int r = v.u + 0x7fffu + ((v.u >> 16) & 1u);
  return (unsigned short)(r >> 16);
}
__device__ __forceinline__ float bf2f(unsigned short h) {
  union { unsigned int u; float f; } v; v.u = ((unsigned int)h) << 16;
  return v.f;
}
// fast round (no tie-to-even fix): error <= 0.5 ulp, fine for P in [0,1]
__device__ __forceinline__ unsigned short f2bf_fast(float f) {
  union { float f; unsigned int u; } v; v.f = f;
  return (unsigned short)((v.u + 0x8000u) >> 16);
}

// ---------------------------------------------------------------------------
// conv_split: fp32 -> bf16 hi/lo (a ~= hi + lo, err ~2^-17), optional rowscale.
// ---------------------------------------------------------------------------
__global__ __launch_bounds__(256) void conv_split(
    const float* __restrict__ in, unsigned short* __restrict__ hi,
    unsigned short* __restrict__ lo, const float* __restrict__ rowscale,
    int ncols) {
  size_t base = ((size_t)blockIdx.x * 256 + threadIdx.x) * 8;
  float rs = rowscale ? rowscale[base / (size_t)ncols] : 1.0f;
  float4 v0 = *(const float4*)&in[base];
  float4 v1 = *(const float4*)&in[base + 4];
  float f[8] = {v0.x, v0.y, v0.z, v0.w, v1.x, v1.y, v1.z, v1.w};
  unsigned int hw[4], lw[4];
#pragma unroll
  for (int p = 0; p < 4; ++p) {
    float a = f[2 * p] * rs, b = f[2 * p + 1] * rs;
    unsigned short ha = f2bf(a), hb = f2bf(b);
    unsigned short la = f2bf(a - bf2f(ha)), lb = f2bf(b - bf2f(hb));
    hw[p] = (unsigned int)ha | ((unsigned int)hb << 16);
    lw[p] = (unsigned int)la | ((unsigned int)lb << 16);
  }
  uint4 H = {hw[0], hw[1], hw[2], hw[3]};
  uint4 L = {lw[0], lw[1], lw[2], lw[3]};
  *(uint4*)&hi[base] = H;
  *(uint4*)&lo[base] = L;
}

// ---------------------------------------------------------------------------
// conv_split_T: in [K][N] fp32 -> out [N][K] bf16 hi/lo (LDS 32x32 transpose).
// ---------------------------------------------------------------------------
__global__ __launch_bounds__(256) void conv_split_T(
    const float* __restrict__ in, unsigned short* __restrict__ hi,
    unsigned short* __restrict__ lo, int K, int N) {
  __shared__ float t[32][33];
  const int n0 = blockIdx.x * 32, k0 = blockIdx.y * 32;
  const int r = threadIdx.x >> 3, c4 = (threadIdx.x & 7) * 4;
  float4 v = *(const float4*)&in[(size_t)(k0 + r) * N + n0 + c4];
  t[r][c4 + 0] = v.x; t[r][c4 + 1] = v.y; t[r][c4 + 2] = v.z; t[r][c4 + 3] = v.w;
  __syncthreads();
  unsigned int hw[2], lw[2];
#pragma unroll
  for (int p = 0; p < 2; ++p) {
    float a = t[c4 + 2 * p][r], b = t[c4 + 2 * p + 1][r];
    unsigned short ha = f2bf(a), hb = f2bf(b);
    unsigned short la = f2bf(a - bf2f(ha)), lb = f2bf(b - bf2f(hb));
    hw[p] = (unsigned int)ha | ((unsigned int)hb << 16);
    lw[p] = (unsigned int)la | ((unsigned int)lb << 16);
  }
  size_t o = (size_t)(n0 + r) * K + k0 + c4;
  *(uint2*)&hi[o] = make_uint2(hw[0], hw[1]);
  *(uint2*)&lo[o] = make_uint2(lw[0], lw[1]);
}

// ---------------------------------------------------------------------------
// Split-bf16 MFMA GEMM (round-3, verified): C = (Ah+Al)@(Bh+Bl)^T + bias.
// ---------------------------------------------------------------------------
__global__ __launch_bounds__(256, 2) void gemm_mfma_split(
    const unsigned short* __restrict__ Ah, const unsigned short* __restrict__ Al,
    const unsigned short* __restrict__ Bh, const unsigned short* __restrict__ Bl,
    const float* __restrict__ bias, float* __restrict__ C,
    int M, int N, int K) {
  __shared__ __align__(16) unsigned short lds[2][16384];

  const int tid = threadIdx.x;
  const int w = tid >> 6, l = tid & 63;
  const int lc = l & 15, lr = l >> 4;
  const int wr = w >> 1, wc = w & 1;
  const int m0 = blockIdx.y * 128, n0 = blockIdx.x * 128;

  f32x4 acc[4][4];
#pragma unroll
  for (int mi = 0; mi < 4; ++mi)
#pragma unroll
    for (int ni = 0; ni < 4; ++ni) acc[mi][ni] = (f32x4){0.f, 0.f, 0.f, 0.f};

  const unsigned short* src = (w == 0) ? Ah : (w == 1) ? Al : (w == 2) ? Bh : Bl;
  const int rowbase = (w < 2) ? m0 : n0;
  const int lrow = l >> 2, lkk = (l & 3) * 8;

  const int NT = K / 32;
  int buf = 0;

#define STAGE(B_, KT_)                                                         \
  {                                                                            \
    unsigned short* dst = lds[B_] + w * 4096;                                  \
    _Pragma("unroll") for (int c = 0; c < 8; ++c) {                            \
      const unsigned short* g =                                                \
          src + (size_t)(rowbase + c * 16 + lrow) * K + (KT_) + lkk;           \
      __builtin_amdgcn_global_load_lds(                                        \
          (const __attribute__((address_space(1))) unsigned int*)g,            \
          (__attribute__((address_space(3))) unsigned int*)(dst + c * 512),    \
          16, 0, 0);                                                           \
    }                                                                          \
  }

  STAGE(0, 0);
  asm volatile("s_waitcnt vmcnt(0)");
  __syncthreads();

  for (int t = 0; t < NT; ++t) {
    if (t + 1 < NT) STAGE(buf ^ 1, (t + 1) * 32);

    const unsigned short* bp = lds[buf];
    bf16x8 ah[4], al[4], bh[4], bl[4];
#pragma unroll
    for (int mi = 0; mi < 4; ++mi) {
      int ro = (wr * 64 + mi * 16 + lc) * 32 + lr * 8;
      ah[mi] = *(const bf16x8*)&bp[ro];
      al[mi] = *(const bf16x8*)&bp[4096 + ro];
    }
#pragma unroll
    for (int ni = 0; ni < 4; ++ni) {
      int co = (wc * 64 + ni * 16 + lc) * 32 + lr * 8;
      bh[ni] = *(const bf16x8*)&bp[8192 + co];
      bl[ni] = *(const bf16x8*)&bp[12288 + co];
    }

    __builtin_amdgcn_s_setprio(1);
#pragma unroll
    for (int mi = 0; mi < 4; ++mi)
#pragma unroll
      for (int ni = 0; ni < 4; ++ni) {
        acc[mi][ni] = __builtin_amdgcn_mfma_f32_16x16x32_bf16(ah[mi], bh[ni], acc[mi][ni], 0, 0, 0);
        acc[mi][ni] = __builtin_amdgcn_mfma_f32_16x16x32_bf16(ah[mi], bl[ni], acc[mi][ni], 0, 0, 0);
        acc[mi][ni] = __builtin_amdgcn_mfma_f32_16x16x32_bf16(al[mi], bh[ni], acc[mi][ni], 0, 0, 0);
      }
    __builtin_amdgcn_s_setprio(0);

    __syncthreads();
    buf ^= 1;
  }
#undef STAGE

#pragma unroll
  for (int mi = 0; mi < 4; ++mi)
#pragma unroll
    for (int r = 0; r < 4; ++r) {
      int row = m0 + wr * 64 + mi * 16 + lr * 4 + r;
#pragma unroll
      for (int ni = 0; ni < 4; ++ni) {
        int col = n0 + wc * 64 + ni * 16 + lc;
        C[(size_t)row * N + col] = acc[mi][ni][r] + bias[col];
      }
    }
}

// ---------------------------------------------------------------------------
// Pre-pass: qkv fp32 -> bf16 operands for MFMA attention (round-2, verified).
// ---------------------------------------------------------------------------
__global__ __launch_bounds__(256) void convert_kernel(
    const float* __restrict__ qkv,
    unsigned short* __restrict__ Qh, unsigned short* __restrict__ Ql,
    unsigned short* __restrict__ Khg, unsigned short* __restrict__ Klg,
    unsigned short* __restrict__ Vtg) {
  const int stile = blockIdx.x, bh = blockIdx.y;
  const int b = bh >> 4, h = bh & 15;
  const int tid = threadIdx.x;
  const int s = tid >> 2;
  const int cg = (tid & 3) << 4;
  const int t = stile * 64 + s;
  const float* row = qkv + (size_t)(b * 2048 + t) * 3072 + h * 192;
  const float QS = 0.125f * LOG2E;

  __shared__ unsigned short vs[64][72];

  {
    unsigned int* qh32 = (unsigned int*)(Qh + ((size_t)bh * 2048 + t) * 64 + cg);
    unsigned int* ql32 = (unsigned int*)(Ql + ((size_t)bh * 2048 + t) * 64 + cg);
#pragma unroll
    for (int j = 0; j < 4; ++j) {
      float4 v = *(const float4*)&row[cg + j * 4];
      float f[4] = {v.x * QS, v.y * QS, v.z * QS, v.w * QS};
      unsigned short hh[4], llo[4];
#pragma unroll
      for (int e = 0; e < 4; ++e) {
        hh[e] = f2bf(f[e]);
        llo[e] = f2bf(f[e] - bf2f(hh[e]));
      }
      qh32[j * 2 + 0] = (unsigned int)hh[0] | ((unsigned int)hh[1] << 16);
      qh32[j * 2 + 1] = (unsigned int)hh[2] | ((unsigned int)hh[3] << 16);
      ql32[j * 2 + 0] = (unsigned int)llo[0] | ((unsigned int)llo[1] << 16);
      ql32[j * 2 + 1] = (unsigned int)llo[2] | ((unsigned int)llo[3] << 16);
    }
  }
  {
    unsigned int* kh32 = (unsigned int*)(Khg + (size_t)(bh * 32 + stile) * 4096);
    unsigned int* kl32 = (unsigned int*)(Klg + (size_t)(bh * 32 + stile) * 4096);
    const int sw = (s & 7) << 4;
#pragma unroll
    for (int j = 0; j < 4; ++j) {
      float4 v = *(const float4*)&row[64 + cg + j * 4];
      float f[4] = {v.x, v.y, v.z, v.w};
#pragma unroll
      for (int p = 0; p < 2; ++p) {
        int c0 = cg + j * 4 + p * 2;
        unsigned short h0 = f2bf(f[p * 2]), h1 = f2bf(f[p * 2 + 1]);
        unsigned short l0 = f2bf(f[p * 2] - bf2f(h0));
        unsigned short l1 = f2bf(f[p * 2 + 1] - bf2f(h1));
        int byte = (s * 128 + c0 * 2) ^ sw;
        kh32[byte >> 2] = (unsigned int)h0 | ((unsigned int)h1 << 16);
        kl32[byte >> 2] = (unsigned int)l0 | ((unsigned int)l1 << 16);
      }
    }
  }
#pragma unroll
  for (int j = 0; j < 4; ++j) {
    float4 v = *(const float4*)&row[128 + cg + j * 4];
    vs[s][cg + j * 4 + 0] = f2bf(v.x);
    vs[s][cg + j * 4 + 1] = f2bf(v.y);
    vs[s][cg + j * 4 + 2] = f2bf(v.z);
    vs[s][cg + j * 4 + 3] = f2bf(v.w);
  }
  __syncthreads();
  {
    const int c = tid >> 2;
    const int sb = (tid & 3) << 4;
    unsigned int* vt32 = (unsigned int*)(Vtg + (size_t)(bh * 32 + stile) * 4096);
    const int sw = (c & 7) << 4;
#pragma unroll
    for (int p = 0; p < 8; ++p) {
      int ss = sb + p * 2;
      unsigned int wv = (unsigned int)vs[ss][c] | ((unsigned int)vs[ss + 1][c] << 16);
      int byte = (c * 128 + ss * 2) ^ sw;
      vt32[byte >> 2] = wv;
    }
  }
}

// ---------------------------------------------------------------------------
// MFMA flash attention, round-4: VALU diet.
//  - per-lane partial lsum (reduced once at end)
//  - defer-max: __any-gated rescale path (THR=0, exact)
//  - fast P rounding (2 ops/val)
//  - XOR-swizzled P tile [16][64] (2-way = free); P read idx == K idx[st=0]
//  LDS: 24KB images + 4 waves * 2KB P = 32768 B.
// ---------------------------------------------------------------------------
__global__ __launch_bounds__(256, 4) void attn_mfma(
    const unsigned short* __restrict__ Qh, const unsigned short* __restrict__ Ql,
    const unsigned short* __restrict__ Khg, const unsigned short* __restrict__ Klg,
    const unsigned short* __restrict__ Vtg, float* __restrict__ attn) {
  const int qt = blockIdx.x, bh = blockIdx.y;
  const int b = bh >> 4, h = bh & 15;
  const int tid = threadIdx.x;
  const int w = tid >> 6, l = tid & 63;
  const int lc = l & 15, lr = l >> 4;

  __shared__ __align__(16) unsigned short lds[16384];
  unsigned short* KhT = lds;
  unsigned short* KlT = lds + 4096;
  unsigned short* VtT = lds + 8192;
  unsigned short* Pl  = lds + 12288 + w * 1024;  // [16 q][64 k], XOR-swizzled

  const int q0 = qt * 64 + w * 16;
  bf16x8 qh0, qh1, ql0, ql1;
  {
    size_t base = ((size_t)bh * 2048 + q0 + lc) * 64 + lr * 8;
    qh0 = *(const bf16x8*)&Qh[base];
    qh1 = *(const bf16x8*)&Qh[base + 32];
    ql0 = *(const bf16x8*)&Ql[base];
    ql1 = *(const bf16x8*)&Ql[base + 32];
  }

  // hoisted swizzled LDS indices (shorts): same formula for K, V, and P(st=0)
  int kidx0[4], kidx1[4];
#pragma unroll
  for (int st = 0; st < 4; ++st) {
    int row = st * 16 + lc;
    int sw = (row & 7) << 4;
    kidx0[st] = ((row * 128 + lr * 16) ^ sw) >> 1;
    kidx1[st] = ((row * 128 + 64 + lr * 16) ^ sw) >> 1;
  }
  // P write indices: row = lr*4+r, col = st*16+lc
  int pw[4][4];
#pragma unroll
  for (int r = 0; r < 4; ++r) {
    int row = lr * 4 + r;
    int sw = (row & 7) << 4;
#pragma unroll
    for (int st = 0; st < 4; ++st)
      pw[r][st] = ((row * 128 + st * 32 + lc * 2) ^ sw) >> 1;
  }

  f32x4 o[4];
  float m[4], lsum[4];
#pragma unroll
  for (int r = 0; r < 4; ++r) { m[r] = -1e30f; lsum[r] = 0.f; }
#pragma unroll
  for (int ct = 0; ct < 4; ++ct) o[ct] = (f32x4){0.f, 0.f, 0.f, 0.f};

  const unsigned short* pKh = Khg + (size_t)bh * 32 * 4096;
  const unsigned short* pKl = Klg + (size_t)bh * 32 * 4096;
  const unsigned short* pVt = Vtg + (size_t)bh * 32 * 4096;

  for (int kvt = 0; kvt < 32; ++kvt) {
    {
      size_t tb = (size_t)kvt * 4096;
#pragma unroll
      for (int i = 0; i < 6; ++i) {
        int c = w * 6 + i;
        int arr = c >> 3;
        const unsigned short* gb =
            (arr == 0) ? (pKh + tb) : (arr == 1) ? (pKl + tb) : (pVt + tb);
        const unsigned short* g = gb + (c & 7) * 512 + l * 8;
        unsigned short* dst = lds + c * 512;
        __builtin_amdgcn_global_load_lds(
            (const __attribute__((address_space(1))) unsigned int*)g,
            (__attribute__((address_space(3))) unsigned int*)dst, 16, 0, 0);
      }
    }
    __syncthreads();

    // QK^T: S[16q][64k], split-bf16 3 products
    f32x4 sacc[4];
#pragma unroll
    for (int st = 0; st < 4; ++st) {
      bf16x8 kh0 = *(const bf16x8*)&KhT[kidx0[st]];
      bf16x8 kh1 = *(const bf16x8*)&KhT[kidx1[st]];
      bf16x8 kl0 = *(const bf16x8*)&KlT[kidx0[st]];
      bf16x8 kl1 = *(const bf16x8*)&KlT[kidx1[st]];
      f32x4 acc = (f32x4){0.f, 0.f, 0.f, 0.f};
      acc = __builtin_amdgcn_mfma_f32_16x16x32_bf16(qh0, kh0, acc, 0, 0, 0);
      acc = __builtin_amdgcn_mfma_f32_16x16x32_bf16(qh1, kh1, acc, 0, 0, 0);
      acc = __builtin_amdgcn_mfma_f32_16x16x32_bf16(ql0, kh0, acc, 0, 0, 0);
      acc = __builtin_amdgcn_mfma_f32_16x16x32_bf16(ql1, kh1, acc, 0, 0, 0);
      acc = __builtin_amdgcn_mfma_f32_16x16x32_bf16(qh0, kl0, acc, 0, 0, 0);
      acc = __builtin_amdgcn_mfma_f32_16x16x32_bf16(qh1, kl1, acc, 0, 0, 0);
      sacc[st] = acc;
    }

    // local per-lane max; wave-uniform gate on rescale
    float pml[4];
#pragma unroll
    for (int r = 0; r < 4; ++r)
      pml[r] = fmaxf(fmaxf(sacc[0][r], sacc[1][r]), fmaxf(sacc[2][r], sacc[3][r]));
    bool need = (pml[0] > m[0]) | (pml[1] > m[1]) | (pml[2] > m[2]) | (pml[3] > m[3]);
    if (__any(need)) {
#pragma unroll
      for (int r = 0; r < 4; ++r) {
        float pm = pml[r];
        pm = fmaxf(pm, __shfl_xor(pm, 1));
        pm = fmaxf(pm, __shfl_xor(pm, 2));
        pm = fmaxf(pm, __shfl_xor(pm, 4));
        pm = fmaxf(pm, __shfl_xor(pm, 8));
        float mn = fmaxf(m[r], pm);
        float corr = exp2f(m[r] - mn);
        m[r] = mn;
        lsum[r] *= corr;
        o[0][r] *= corr; o[1][r] *= corr; o[2][r] *= corr; o[3][r] *= corr;
      }
    }

    // exp2 + partial sum + pack/store P
#pragma unroll
    for (int st = 0; st < 4; ++st)
#pragma unroll
      for (int r = 0; r < 4; ++r)
        sacc[st][r] = exp2f(sacc[st][r] - m[r]);
#pragma unroll
    for (int r = 0; r < 4; ++r)
      lsum[r] += (sacc[0][r] + sacc[1][r]) + (sacc[2][r] + sacc[3][r]);
#pragma unroll
    for (int r = 0; r < 4; ++r)
#pragma unroll
      for (int st = 0; st < 4; ++st)
        Pl[pw[r][st]] = f2bf_fast(sacc[st][r]);

    bf16x8 pa0 = *(const bf16x8*)&Pl[kidx0[0]];
    bf16x8 pa1 = *(const bf16x8*)&Pl[kidx1[0]];

    // PV: O += P @ V
#pragma unroll
    for (int ct = 0; ct < 4; ++ct) {
      bf16x8 v0 = *(const bf16x8*)&VtT[kidx0[ct]];
      bf16x8 v1 = *(const bf16x8*)&VtT[kidx1[ct]];
      o[ct] = __builtin_amdgcn_mfma_f32_16x16x32_bf16(pa0, v0, o[ct], 0, 0, 0);
      o[ct] = __builtin_amdgcn_mfma_f32_16x16x32_bf16(pa1, v1, o[ct], 0, 0, 0);
    }
    __syncthreads();
  }

  // final cross-lane lsum reduction (once)
  float invl[4];
#pragma unroll
  for (int r = 0; r < 4; ++r) {
    float s = lsum[r];
    s += __shfl_xor(s, 1);
    s += __shfl_xor(s, 2);
    s += __shfl_xor(s, 4);
    s += __shfl_xor(s, 8);
    invl[r] = 1.0f / s;
  }
#pragma unroll
  for (int r = 0; r < 4; ++r) {
    float* orow = attn + (size_t)(b * 2048 + q0 + lr * 4 + r) * 1024 + h * 64 + lc;
#pragma unroll
    for (int ct = 0; ct < 4; ++ct) orow[ct * 16] = o[ct][r] * invl[r];
  }
}

// ---------------------------------------------------------------------------
// k_mean partials / pos / aw (round-3, verified)
// ---------------------------------------------------------------------------
__global__ __launch_bounds__(256) void kmean_part(
    const unsigned short* __restrict__ Khg, const unsigned short* __restrict__ Klg,
    float* __restrict__ kmp) {
  const int bh = blockIdx.x, seg = blockIdx.y;
  const int c = threadIdx.x & 63, sub = threadIdx.x >> 6;
  const int tile = seg * 4 + sub;
  const unsigned short* kh = Khg + (size_t)(bh * 32 + tile) * 4096;
  const unsigned short* kl = Klg + (size_t)(bh * 32 + tile) * 4096;
  float sum = 0.f;
#pragma unroll 8
  for (int s = 0; s < 64; ++s) {
    int sidx = ((s * 128 + c * 2) ^ ((s & 7) << 4)) >> 1;
    sum += bf2f(kh[sidx]) + bf2f(kl[sidx]);
  }
  __shared__ float red[4][64];
  red[sub][c] = sum;
  __syncthreads();
  if (sub == 0)
    kmp[(size_t)(bh * 8 + seg) * 64 + c] =
        red[0][c] + red[1][c] + red[2][c] + red[3][c];
}

__global__ __launch_bounds__(256) void pos_kernel(
    const unsigned short* __restrict__ Qh, const unsigned short* __restrict__ Ql,
    const float* __restrict__ kmp, float* __restrict__ pos) {
  __shared__ float kms[1024];
  int blk = blockIdx.x;
  int b = (blk * 4) >> 11;
  for (int i = threadIdx.x; i < 1024; i += 256) {
    int h = i >> 6, cc = i & 63;
    float s = 0.f;
#pragma unroll
    for (int seg = 0; seg < 8; ++seg)
      s += kmp[(size_t)((b * 16 + h) * 8 + seg) * 64 + cc];
    kms[i] = s * (1.0f / 2048.0f) * (1.0f / LOG2E);
  }
  __syncthreads();
  int w = threadIdx.x >> 6, lane = threadIdx.x & 63;
  int row = blk * 4 + w;
  int t = row & 2047;
  float p = 0.f;
#pragma unroll
  for (int h = 0; h < 16; ++h) {
    size_t idx = ((size_t)(b * 16 + h) * 2048 + t) * 64 + lane;
    p = fmaf(bf2f(Qh[idx]) + bf2f(Ql[idx]), kms[h * 64 + lane], p);
  }
#pragma unroll
  for (int off = 32; off; off >>= 1) p += __shfl_xor(p, off, 64);
  if (lane == 0) pos[row] = p;
}

__global__ __launch_bounds__(1024) void aw_kernel(const float* __restrict__ pos,
                                                  float* __restrict__ aw) {
  int b = blockIdx.x, tid = threadIdx.x;
  float p0 = pos[b * 2048 + tid], p1 = pos[b * 2048 + 1024 + tid];
  float mn = fminf(p0, p1), mx = fmaxf(p0, p1);
#pragma unroll
  for (int off = 32; off; off >>= 1) {
    mn = fminf(mn, __shfl_xor(mn, off, 64));
    mx = fmaxf(mx, __shfl_xor(mx, off, 64));
  }
  __shared__ float smn[16], smx[16];
  int wave = tid >> 6, lane = tid & 63;
  if (lane == 0) { smn[wave] = mn; smx[wave] = mx; }
  __syncthreads();
  if (tid < 64) {
    mn = (lane < 16) ? smn[lane] : 3.0e38f;
    mx = (lane < 16) ? smx[lane] : -3.0e38f;
#pragma unroll
    for (int off = 8; off; off >>= 1) {
      mn = fminf(mn, __shfl_xor(mn, off, 64));
      mx = fmaxf(mx, __shfl_xor(mx, off, 64));
    }
    if (lane == 0) { smn[0] = mn; smx[0] = mx; }
  }
  __syncthreads();
  float MN = smn[0], inv = 1.0f / (smx[0] - MN + 1e-6f);
  aw[b * 2048 + tid] = (p0 - MN) * inv;
  aw[b * 2048 + 1024 + tid] = (p1 - MN) * inv;
}

// ---------------------------------------------------------------------------
// Workspace layout (unchanged from round 3, peak 109 MB).
// ---------------------------------------------------------------------------
extern "C" void kernel_launch(void* const* d_in, const int* in_sizes, int n_in,
                              void* d_out, int out_size, void* d_ws, size_t ws_size,
                              hipStream_t stream) {
  const float* x      = (const float*)d_in[0];
  const float* W_qkv  = (const float*)d_in[1];
  const float* b_qkv  = (const float*)d_in[2];
  const float* W_proj = (const float*)d_in[3];
  const float* b_proj = (const float*)d_in[4];
  float* out = (float*)d_out;

  char* wsb = (char*)d_ws;
  float* qkv_f = (float*)wsb;
  unsigned short* A2h = (unsigned short*)wsb;
  unsigned short* A2l = A2h + 4194304;
  unsigned short* Wph = (unsigned short*)(wsb + 16777216);
  unsigned short* Wpl = Wph + 1048576;
  float* kmp = (float*)(wsb + 20971520);
  float* pos = kmp + 16384;
  float* aw  = pos + 4096;
  unsigned short* xh = (unsigned short*)(wsb + 50331648);
  unsigned short* xl = xh + 4194304;
  float* attn_f = (float*)(wsb + 50331648);
  unsigned short* Wqh = (unsigned short*)(wsb + 67108864);
  unsigned short* Wql = Wqh + 3145728;
  unsigned short* Qh  = (unsigned short*)(wsb + 67108864);
  unsigned short* Ql  = Qh + 4194304;
  unsigned short* Khg = Ql + 4194304;
  unsigned short* Klg = Khg + 4194304;
  unsigned short* Vtg = Klg + 4194304;

  conv_split<<<2048, 256, 0, stream>>>(x, xh, xl, nullptr, 1024);
  conv_split_T<<<dim3(96, 32), 256, 0, stream>>>(W_qkv, Wqh, Wql, 1024, 3072);
  gemm_mfma_split<<<dim3(24, 32), 256, 0, stream>>>(xh, xl, Wqh, Wql, b_qkv,
                                                    qkv_f, 4096, 3072, 1024);
  convert_kernel<<<dim3(32, 32), 256, 0, stream>>>(qkv_f, Qh, Ql, Khg, Klg, Vtg);
  kmean_part<<<dim3(32, 8), 256, 0, stream>>>(Khg, Klg, kmp);
  pos_kernel<<<1024, 256, 0, stream>>>(Qh, Ql, kmp, pos);
  aw_kernel<<<2, 1024, 0, stream>>>(pos, aw);
  attn_mfma<<<dim3(32, 32), 256, 0, stream>>>(Qh, Ql, Khg, Klg, Vtg, attn_f);
  conv_split<<<2048, 256, 0, stream>>>(attn_f, A2h, A2l, aw, 1024);
  conv_split_T<<<dim3(32, 32), 256, 0, stream>>>(W_proj, Wph, Wpl, 1024, 1024);
  gemm_mfma_split<<<dim3(8, 32), 256, 0, stream>>>(A2h, A2l, Wph, Wpl, b_proj,
                                                   out, 4096, 1024, 1024);
}

// Round 5
// 349.145 us; speedup vs baseline: 5.8565x; 1.0020x over previous
//
#include <hip/hip_runtime.h>
#include <hip/hip_bf16.h>

// Problem constants: B=2, T=2048, W=1024, H=16, C=64
// scale^2 = 1/8 folded into Q along with log2(e) (exp2-domain softmax).

#define LOG2E 1.4426950408889634f

typedef float f32x4 __attribute__((ext_vector_type(4)));
typedef short bf16x8 __attribute__((ext_vector_type(8)));

__device__ __forceinline__ unsigned short f2bf(float f) {
  union { float f; unsigned int u; } v; v.f = f;
  unsigned int r = v.u + 0x7fffu + ((v.u >> 16) & 1u);
  return (unsigned short)(r >> 16);
}
__device__ __forceinline__ float bf2f(unsigned short h) {
  union { unsigned int u; float f; } v; v.u = ((unsigned int)h) << 16;
  return v.f;
}
// fast round (no tie-to-even fix): error <= 0.5 ulp, fine for P in [0,1]
__device__ __forceinline__ unsigned short f2bf_fast(float f) {
  union { float f; unsigned int u; } v; v.f = f;
  return (unsigned short)((v.u + 0x8000u) >> 16);
}

// ---------------------------------------------------------------------------
// conv_split: fp32 -> bf16 hi/lo (a ~= hi + lo, err ~2^-17).
// ---------------------------------------------------------------------------
__global__ __launch_bounds__(256) void conv_split(
    const float* __restrict__ in, unsigned short* __restrict__ hi,
    unsigned short* __restrict__ lo) {
  size_t base = ((size_t)blockIdx.x * 256 + threadIdx.x) * 8;
  float4 v0 = *(const float4*)&in[base];
  float4 v1 = *(const float4*)&in[base + 4];
  float f[8] = {v0.x, v0.y, v0.z, v0.w, v1.x, v1.y, v1.z, v1.w};
  unsigned int hw[4], lw[4];
#pragma unroll
  for (int p = 0; p < 4; ++p) {
    float a = f[2 * p], b = f[2 * p + 1];
    unsigned short ha = f2bf(a), hb = f2bf(b);
    unsigned short la = f2bf(a - bf2f(ha)), lb = f2bf(b - bf2f(hb));
    hw[p] = (unsigned int)ha | ((unsigned int)hb << 16);
    lw[p] = (unsigned int)la | ((unsigned int)lb << 16);
  }
  uint4 H = {hw[0], hw[1], hw[2], hw[3]};
  uint4 L = {lw[0], lw[1], lw[2], lw[3]};
  *(uint4*)&hi[base] = H;
  *(uint4*)&lo[base] = L;
}

// ---------------------------------------------------------------------------
// conv_split_T: in [K][N] fp32 -> out [N][K] bf16 hi/lo (LDS 32x32 transpose).
// ---------------------------------------------------------------------------
__global__ __launch_bounds__(256) void conv_split_T(
    const float* __restrict__ in, unsigned short* __restrict__ hi,
    unsigned short* __restrict__ lo, int K, int N) {
  __shared__ float t[32][33];
  const int n0 = blockIdx.x * 32, k0 = blockIdx.y * 32;
  const int r = threadIdx.x >> 3, c4 = (threadIdx.x & 7) * 4;
  float4 v = *(const float4*)&in[(size_t)(k0 + r) * N + n0 + c4];
  t[r][c4 + 0] = v.x; t[r][c4 + 1] = v.y; t[r][c4 + 2] = v.z; t[r][c4 + 3] = v.w;
  __syncthreads();
  unsigned int hw[2], lw[2];
#pragma unroll
  for (int p = 0; p < 2; ++p) {
    float a = t[c4 + 2 * p][r], b = t[c4 + 2 * p + 1][r];
    unsigned short ha = f2bf(a), hb = f2bf(b);
    unsigned short la = f2bf(a - bf2f(ha)), lb = f2bf(b - bf2f(hb));
    hw[p] = (unsigned int)ha | ((unsigned int)hb << 16);
    lw[p] = (unsigned int)la | ((unsigned int)lb << 16);
  }
  size_t o = (size_t)(n0 + r) * K + k0 + c4;
  *(uint2*)&hi[o] = make_uint2(hw[0], hw[1]);
  *(uint2*)&lo[o] = make_uint2(lw[0], lw[1]);
}

// ---------------------------------------------------------------------------
// Split-bf16 MFMA GEMM (round-3, verified): C = (Ah+Al)@(Bh+Bl)^T + bias.
// ---------------------------------------------------------------------------
__global__ __launch_bounds__(256, 2) void gemm_mfma_split(
    const unsigned short* __restrict__ Ah, const unsigned short* __restrict__ Al,
    const unsigned short* __restrict__ Bh, const unsigned short* __restrict__ Bl,
    const float* __restrict__ bias, float* __restrict__ C,
    int M, int N, int K) {
  __shared__ __align__(16) unsigned short lds[2][16384];

  const int tid = threadIdx.x;
  const int w = tid >> 6, l = tid & 63;
  const int lc = l & 15, lr = l >> 4;
  const int wr = w >> 1, wc = w & 1;
  const int m0 = blockIdx.y * 128, n0 = blockIdx.x * 128;

  f32x4 acc[4][4];
#pragma unroll
  for (int mi = 0; mi < 4; ++mi)
#pragma unroll
    for (int ni = 0; ni < 4; ++ni) acc[mi][ni] = (f32x4){0.f, 0.f, 0.f, 0.f};

  const unsigned short* src = (w == 0) ? Ah : (w == 1) ? Al : (w == 2) ? Bh : Bl;
  const int rowbase = (w < 2) ? m0 : n0;
  const int lrow = l >> 2, lkk = (l & 3) * 8;

  const int NT = K / 32;
  int buf = 0;

#define STAGE(B_, KT_)                                                         \
  {                                                                            \
    unsigned short* dst = lds[B_] + w * 4096;                                  \
    _Pragma("unroll") for (int c = 0; c < 8; ++c) {                            \
      const unsigned short* g =                                                \
          src + (size_t)(rowbase + c * 16 + lrow) * K + (KT_) + lkk;           \
      __builtin_amdgcn_global_load_lds(                                        \
          (const __attribute__((address_space(1))) unsigned int*)g,            \
          (__attribute__((address_space(3))) unsigned int*)(dst + c * 512),    \
          16, 0, 0);                                                           \
    }                                                                          \
  }

  STAGE(0, 0);
  asm volatile("s_waitcnt vmcnt(0)");
  __syncthreads();

  for (int t = 0; t < NT; ++t) {
    if (t + 1 < NT) STAGE(buf ^ 1, (t + 1) * 32);

    const unsigned short* bp = lds[buf];
    bf16x8 ah[4], al[4], bh[4], bl[4];
#pragma unroll
    for (int mi = 0; mi < 4; ++mi) {
      int ro = (wr * 64 + mi * 16 + lc) * 32 + lr * 8;
      ah[mi] = *(const bf16x8*)&bp[ro];
      al[mi] = *(const bf16x8*)&bp[4096 + ro];
    }
#pragma unroll
    for (int ni = 0; ni < 4; ++ni) {
      int co = (wc * 64 + ni * 16 + lc) * 32 + lr * 8;
      bh[ni] = *(const bf16x8*)&bp[8192 + co];
      bl[ni] = *(const bf16x8*)&bp[12288 + co];
    }

    __builtin_amdgcn_s_setprio(1);
#pragma unroll
    for (int mi = 0; mi < 4; ++mi)
#pragma unroll
      for (int ni = 0; ni < 4; ++ni) {
        acc[mi][ni] = __builtin_amdgcn_mfma_f32_16x16x32_bf16(ah[mi], bh[ni], acc[mi][ni], 0, 0, 0);
        acc[mi][ni] = __builtin_amdgcn_mfma_f32_16x16x32_bf16(ah[mi], bl[ni], acc[mi][ni], 0, 0, 0);
        acc[mi][ni] = __builtin_amdgcn_mfma_f32_16x16x32_bf16(al[mi], bh[ni], acc[mi][ni], 0, 0, 0);
      }
    __builtin_amdgcn_s_setprio(0);

    __syncthreads();
    buf ^= 1;
  }
#undef STAGE

#pragma unroll
  for (int mi = 0; mi < 4; ++mi)
#pragma unroll
    for (int r = 0; r < 4; ++r) {
      int row = m0 + wr * 64 + mi * 16 + lr * 4 + r;
#pragma unroll
      for (int ni = 0; ni < 4; ++ni) {
        int col = n0 + wc * 64 + ni * 16 + lc;
        C[(size_t)row * N + col] = acc[mi][ni][r] + bias[col];
      }
    }
}

// ---------------------------------------------------------------------------
// Pre-pass: qkv fp32 -> bf16 operands for MFMA attention.
//  Qh/Ql: scaled (0.125*log2e) hi/lo split, row-major [bh][2048][64]
//  Ktg: single-bf16 K, swizzled tile images [bh*32+stile][64s][64c]
//  Vtg: V transposed, swizzled tile images [bh*32+stile][64c][64s]
// Swizzle: byte ^= (row&7)<<4 within each 128B row.
// ---------------------------------------------------------------------------
__global__ __launch_bounds__(256) void convert_kernel(
    const float* __restrict__ qkv,
    unsigned short* __restrict__ Qh, unsigned short* __restrict__ Ql,
    unsigned short* __restrict__ Ktg, unsigned short* __restrict__ Vtg) {
  const int stile = blockIdx.x, bh = blockIdx.y;
  const int b = bh >> 4, h = bh & 15;
  const int tid = threadIdx.x;
  const int s = tid >> 2;
  const int cg = (tid & 3) << 4;
  const int t = stile * 64 + s;
  const float* row = qkv + (size_t)(b * 2048 + t) * 3072 + h * 192;
  const float QS = 0.125f * LOG2E;

  __shared__ unsigned short vs[64][72];

  {
    unsigned int* qh32 = (unsigned int*)(Qh + ((size_t)bh * 2048 + t) * 64 + cg);
    unsigned int* ql32 = (unsigned int*)(Ql + ((size_t)bh * 2048 + t) * 64 + cg);
#pragma unroll
    for (int j = 0; j < 4; ++j) {
      float4 v = *(const float4*)&row[cg + j * 4];
      float f[4] = {v.x * QS, v.y * QS, v.z * QS, v.w * QS};
      unsigned short hh[4], llo[4];
#pragma unroll
      for (int e = 0; e < 4; ++e) {
        hh[e] = f2bf(f[e]);
        llo[e] = f2bf(f[e] - bf2f(hh[e]));
      }
      qh32[j * 2 + 0] = (unsigned int)hh[0] | ((unsigned int)hh[1] << 16);
      qh32[j * 2 + 1] = (unsigned int)hh[2] | ((unsigned int)hh[3] << 16);
      ql32[j * 2 + 0] = (unsigned int)llo[0] | ((unsigned int)llo[1] << 16);
      ql32[j * 2 + 1] = (unsigned int)llo[2] | ((unsigned int)llo[3] << 16);
    }
  }
  {
    unsigned int* kt32 = (unsigned int*)(Ktg + (size_t)(bh * 32 + stile) * 4096);
    const int sw = (s & 7) << 4;
#pragma unroll
    for (int j = 0; j < 4; ++j) {
      float4 v = *(const float4*)&row[64 + cg + j * 4];
      float f[4] = {v.x, v.y, v.z, v.w};
#pragma unroll
      for (int p = 0; p < 2; ++p) {
        int c0 = cg + j * 4 + p * 2;
        int byte = (s * 128 + c0 * 2) ^ sw;
        kt32[byte >> 2] = (unsigned int)f2bf(f[p * 2]) |
                          ((unsigned int)f2bf(f[p * 2 + 1]) << 16);
      }
    }
  }
#pragma unroll
  for (int j = 0; j < 4; ++j) {
    float4 v = *(const float4*)&row[128 + cg + j * 4];
    vs[s][cg + j * 4 + 0] = f2bf(v.x);
    vs[s][cg + j * 4 + 1] = f2bf(v.y);
    vs[s][cg + j * 4 + 2] = f2bf(v.z);
    vs[s][cg + j * 4 + 3] = f2bf(v.w);
  }
  __syncthreads();
  {
    const int c = tid >> 2;
    const int sb = (tid & 3) << 4;
    unsigned int* vt32 = (unsigned int*)(Vtg + (size_t)(bh * 32 + stile) * 4096);
    const int sw = (c & 7) << 4;
#pragma unroll
    for (int p = 0; p < 8; ++p) {
      int ss = sb + p * 2;
      unsigned int wv = (unsigned int)vs[ss][c] | ((unsigned int)vs[ss + 1][c] << 16);
      int byte = (c * 128 + ss * 2) ^ sw;
      vt32[byte >> 2] = wv;
    }
  }
}

// ---------------------------------------------------------------------------
// MFMA flash attention, round-5:
//  - K single-bf16 (split-Q only): 4 QK MFMA per S-tile (was 6)
//  - double-buffered K/V staging: next tile's global_load_lds issued at loop
//    top, full compute phase to land before the barrier drain
//  - fused epilogue: writes A2 = aw * attn/l directly as bf16 hi/lo split
//  LDS: 2 x (8KB K + 8KB V) + 4 waves x 2KB P = 40KB -> 4 blocks/CU.
// ---------------------------------------------------------------------------
__global__ __launch_bounds__(256, 4) void attn_mfma(
    const unsigned short* __restrict__ Qh, const unsigned short* __restrict__ Ql,
    const unsigned short* __restrict__ Ktg, const unsigned short* __restrict__ Vtg,
    const float* __restrict__ aw,
    unsigned short* __restrict__ A2h, unsigned short* __restrict__ A2l) {
  const int qt = blockIdx.x, bh = blockIdx.y;
  const int b = bh >> 4, h = bh & 15;
  const int tid = threadIdx.x;
  const int w = tid >> 6, l = tid & 63;
  const int lc = l & 15, lr = l >> 4;

  __shared__ __align__(16) unsigned short ldsKV[2][8192];  // [K 4096 | V 4096]
  __shared__ __align__(16) unsigned short ldsP[4096];
  unsigned short* Pl = ldsP + w * 1024;  // [16 q][64 k], XOR-swizzled

  const int q0 = qt * 64 + w * 16;
  bf16x8 qh0, qh1, ql0, ql1;
  {
    size_t base = ((size_t)bh * 2048 + q0 + lc) * 64 + lr * 8;
    qh0 = *(const bf16x8*)&Qh[base];
    qh1 = *(const bf16x8*)&Qh[base + 32];
    ql0 = *(const bf16x8*)&Ql[base];
    ql1 = *(const bf16x8*)&Ql[base + 32];
  }

  // hoisted swizzled LDS indices (shorts): same formula for K, V, and P(st=0)
  int kidx0[4], kidx1[4];
#pragma unroll
  for (int st = 0; st < 4; ++st) {
    int row = st * 16 + lc;
    int sw = (row & 7) << 4;
    kidx0[st] = ((row * 128 + lr * 16) ^ sw) >> 1;
    kidx1[st] = ((row * 128 + 64 + lr * 16) ^ sw) >> 1;
  }
  int pw[4][4];
#pragma unroll
  for (int r = 0; r < 4; ++r) {
    int row = lr * 4 + r;
    int sw = (row & 7) << 4;
#pragma unroll
    for (int st = 0; st < 4; ++st)
      pw[r][st] = ((row * 128 + st * 32 + lc * 2) ^ sw) >> 1;
  }

  f32x4 o[4];
  float m[4], lsum[4];
#pragma unroll
  for (int r = 0; r < 4; ++r) { m[r] = -1e30f; lsum[r] = 0.f; }
#pragma unroll
  for (int ct = 0; ct < 4; ++ct) o[ct] = (f32x4){0.f, 0.f, 0.f, 0.f};

  // staging: 16 chunks of 1KB; wave w handles chunks 4w..4w+3.
  // waves 0,1 -> K image; waves 2,3 -> V image. Wave-uniform source base.
  const unsigned short* gsrc =
      ((w < 2) ? Ktg : Vtg) + (size_t)bh * 32 * 4096 + (w & 1) * 2048 + l * 8;
  unsigned short* ldst0 = &ldsKV[0][(w >> 1) * 4096 + (w & 1) * 2048];
  unsigned short* ldst1 = &ldsKV[1][(w >> 1) * 4096 + (w & 1) * 2048];

#define STAGE_KV(DST_, T_)                                                     \
  {                                                                            \
    const unsigned short* g = gsrc + (size_t)(T_) * 4096;                      \
    _Pragma("unroll") for (int i = 0; i < 4; ++i) {                            \
      __builtin_amdgcn_global_load_lds(                                        \
          (const __attribute__((address_space(1))) unsigned int*)(g + i * 512),\
          (__attribute__((address_space(3))) unsigned int*)((DST_) + i * 512), \
          16, 0, 0);                                                           \
    }                                                                          \
  }

  STAGE_KV(ldst0, 0);
  asm volatile("s_waitcnt vmcnt(0)");
  __syncthreads();

  int buf = 0;
  for (int kvt = 0; kvt < 32; ++kvt) {
    if (kvt + 1 < 32) STAGE_KV(buf ? ldst0 : ldst1, kvt + 1);

    const unsigned short* KT = &ldsKV[buf][0];
    const unsigned short* VT = &ldsKV[buf][4096];

    // QK^T: S[16q][64k] = (qh+ql) @ k
    f32x4 sacc[4];
#pragma unroll
    for (int st = 0; st < 4; ++st) {
      bf16x8 k0 = *(const bf16x8*)&KT[kidx0[st]];
      bf16x8 k1 = *(const bf16x8*)&KT[kidx1[st]];
      f32x4 acc = (f32x4){0.f, 0.f, 0.f, 0.f};
      acc = __builtin_amdgcn_mfma_f32_16x16x32_bf16(qh0, k0, acc, 0, 0, 0);
      acc = __builtin_amdgcn_mfma_f32_16x16x32_bf16(qh1, k1, acc, 0, 0, 0);
      acc = __builtin_amdgcn_mfma_f32_16x16x32_bf16(ql0, k0, acc, 0, 0, 0);
      acc = __builtin_amdgcn_mfma_f32_16x16x32_bf16(ql1, k1, acc, 0, 0, 0);
      sacc[st] = acc;
    }

    // online softmax: local max, wave-uniform gated rescale
    float pml[4];
#pragma unroll
    for (int r = 0; r < 4; ++r)
      pml[r] = fmaxf(fmaxf(sacc[0][r], sacc[1][r]), fmaxf(sacc[2][r], sacc[3][r]));
    bool need = (pml[0] > m[0]) | (pml[1] > m[1]) | (pml[2] > m[2]) | (pml[3] > m[3]);
    if (__any(need)) {
#pragma unroll
      for (int r = 0; r < 4; ++r) {
        float pm = pml[r];
        pm = fmaxf(pm, __shfl_xor(pm, 1));
        pm = fmaxf(pm, __shfl_xor(pm, 2));
        pm = fmaxf(pm, __shfl_xor(pm, 4));
        pm = fmaxf(pm, __shfl_xor(pm, 8));
        float mn = fmaxf(m[r], pm);
        float corr = exp2f(m[r] - mn);
        m[r] = mn;
        lsum[r] *= corr;
        o[0][r] *= corr; o[1][r] *= corr; o[2][r] *= corr; o[3][r] *= corr;
      }
    }

    // exp2 + per-lane partial sum + pack/store P
#pragma unroll
    for (int st = 0; st < 4; ++st)
#pragma unroll
      for (int r = 0; r < 4; ++r)
        sacc[st][r] = exp2f(sacc[st][r] - m[r]);
#pragma unroll
    for (int r = 0; r < 4; ++r)
      lsum[r] += (sacc[0][r] + sacc[1][r]) + (sacc[2][r] + sacc[3][r]);
#pragma unroll
    for (int r = 0; r < 4; ++r)
#pragma unroll
      for (int st = 0; st < 4; ++st)
        Pl[pw[r][st]] = f2bf_fast(sacc[st][r]);

    bf16x8 pa0 = *(const bf16x8*)&Pl[kidx0[0]];
    bf16x8 pa1 = *(const bf16x8*)&Pl[kidx1[0]];

    // PV: O += P @ V
#pragma unroll
    for (int ct = 0; ct < 4; ++ct) {
      bf16x8 v0 = *(const bf16x8*)&VT[kidx0[ct]];
      bf16x8 v1 = *(const bf16x8*)&VT[kidx1[ct]];
      o[ct] = __builtin_amdgcn_mfma_f32_16x16x32_bf16(pa0, v0, o[ct], 0, 0, 0);
      o[ct] = __builtin_amdgcn_mfma_f32_16x16x32_bf16(pa1, v1, o[ct], 0, 0, 0);
    }
    __syncthreads();
    buf ^= 1;
  }
#undef STAGE_KV

  // epilogue: scale by aw/l, write bf16 hi/lo split of A2 directly
#pragma unroll
  for (int r = 0; r < 4; ++r) {
    float s = lsum[r];
    s += __shfl_xor(s, 1);
    s += __shfl_xor(s, 2);
    s += __shfl_xor(s, 4);
    s += __shfl_xor(s, 8);
    int t = q0 + lr * 4 + r;
    float sc = aw[b * 2048 + t] / s;
    size_t off = (size_t)(b * 2048 + t) * 1024 + h * 64 + lc;
#pragma unroll
    for (int ct = 0; ct < 4; ++ct) {
      float v = o[ct][r] * sc;
      unsigned short hh = f2bf(v);
      A2h[off + ct * 16] = hh;
      A2l[off + ct * 16] = f2bf(v - bf2f(hh));
    }
  }
}

// ---------------------------------------------------------------------------
// k_mean partials from swizzled K images (single bf16 now).
// ---------------------------------------------------------------------------
__global__ __launch_bounds__(256) void kmean_part(
    const unsigned short* __restrict__ Ktg, float* __restrict__ kmp) {
  const int bh = blockIdx.x, seg = blockIdx.y;
  const int c = threadIdx.x & 63, sub = threadIdx.x >> 6;
  const int tile = seg * 4 + sub;
  const unsigned short* kt = Ktg + (size_t)(bh * 32 + tile) * 4096;
  float sum = 0.f;
#pragma unroll 8
  for (int s = 0; s < 64; ++s) {
    int sidx = ((s * 128 + c * 2) ^ ((s & 7) << 4)) >> 1;
    sum += bf2f(kt[sidx]);
  }
  __shared__ float red[4][64];
  red[sub][c] = sum;
  __syncthreads();
  if (sub == 0)
    kmp[(size_t)(bh * 8 + seg) * 64 + c] =
        red[0][c] + red[1][c] + red[2][c] + red[3][c];
}

__global__ __launch_bounds__(256) void pos_kernel(
    const unsigned short* __restrict__ Qh, const unsigned short* __restrict__ Ql,
    const float* __restrict__ kmp, float* __restrict__ pos) {
  __shared__ float kms[1024];
  int blk = blockIdx.x;
  int b = (blk * 4) >> 11;
  for (int i = threadIdx.x; i < 1024; i += 256) {
    int h = i >> 6, cc = i & 63;
    float s = 0.f;
#pragma unroll
    for (int seg = 0; seg < 8; ++seg)
      s += kmp[(size_t)((b * 16 + h) * 8 + seg) * 64 + cc];
    kms[i] = s * (1.0f / 2048.0f) * (1.0f / LOG2E);
  }
  __syncthreads();
  int w = threadIdx.x >> 6, lane = threadIdx.x & 63;
  int row = blk * 4 + w;
  int t = row & 2047;
  float p = 0.f;
#pragma unroll
  for (int h = 0; h < 16; ++h) {
    size_t idx = ((size_t)(b * 16 + h) * 2048 + t) * 64 + lane;
    p = fmaf(bf2f(Qh[idx]) + bf2f(Ql[idx]), kms[h * 64 + lane], p);
  }
#pragma unroll
  for (int off = 32; off; off >>= 1) p += __shfl_xor(p, off, 64);
  if (lane == 0) pos[row] = p;
}

__global__ __launch_bounds__(1024) void aw_kernel(const float* __restrict__ pos,
                                                  float* __restrict__ aw) {
  int b = blockIdx.x, tid = threadIdx.x;
  float p0 = pos[b * 2048 + tid], p1 = pos[b * 2048 + 1024 + tid];
  float mn = fminf(p0, p1), mx = fmaxf(p0, p1);
#pragma unroll
  for (int off = 32; off; off >>= 1) {
    mn = fminf(mn, __shfl_xor(mn, off, 64));
    mx = fmaxf(mx, __shfl_xor(mx, off, 64));
  }
  __shared__ float smn[16], smx[16];
  int wave = tid >> 6, lane = tid & 63;
  if (lane == 0) { smn[wave] = mn; smx[wave] = mx; }
  __syncthreads();
  if (tid < 64) {
    mn = (lane < 16) ? smn[lane] : 3.0e38f;
    mx = (lane < 16) ? smx[lane] : -3.0e38f;
#pragma unroll
    for (int off = 8; off; off >>= 1) {
      mn = fminf(mn, __shfl_xor(mn, off, 64));
      mx = fmaxf(mx, __shfl_xor(mx, off, 64));
    }
    if (lane == 0) { smn[0] = mn; smx[0] = mx; }
  }
  __syncthreads();
  float MN = smn[0], inv = 1.0f / (smx[0] - MN + 1e-6f);
  aw[b * 2048 + tid] = (p0 - MN) * inv;
  aw[b * 2048 + 1024 + tid] = (p1 - MN) * inv;
}

// ---------------------------------------------------------------------------
// Workspace layout (peak ~100.1 MB):
//  [0,16M)      xh/xl        live conv..gemm_qkv;  then A2h/A2l (attn..gemm_proj)
//  [16M,64M)    qkv_f        live gemm_qkv..convert
//  [64M,76.6M)  Wqh/Wql      live conv..gemm_qkv;  then overlaid by images
//  [64M,96M)    Qh|Ql|Kt|Vt  live convert..attn
//  [96M,100M)   Wph/Wpl      live conv..gemm_proj
//  [100M,...)   kmp/pos/aw
// ---------------------------------------------------------------------------
extern "C" void kernel_launch(void* const* d_in, const int* in_sizes, int n_in,
                              void* d_out, int out_size, void* d_ws, size_t ws_size,
                              hipStream_t stream) {
  const float* x      = (const float*)d_in[0];
  const float* W_qkv  = (const float*)d_in[1];
  const float* b_qkv  = (const float*)d_in[2];
  const float* W_proj = (const float*)d_in[3];
  const float* b_proj = (const float*)d_in[4];
  float* out = (float*)d_out;

  char* wsb = (char*)d_ws;
  unsigned short* xh  = (unsigned short*)wsb;                // [0,16M)
  unsigned short* xl  = xh + 4194304;
  unsigned short* A2h = (unsigned short*)wsb;                // reuse after gemm_qkv
  unsigned short* A2l = A2h + 4194304;
  float* qkv_f = (float*)(wsb + 16777216);                   // [16M,64M)
  unsigned short* Wqh = (unsigned short*)(wsb + 67108864);   // [64M,76.6M)
  unsigned short* Wql = Wqh + 3145728;
  unsigned short* Qh  = (unsigned short*)(wsb + 67108864);   // images overlay Wq
  unsigned short* Ql  = Qh + 4194304;
  unsigned short* Ktg = Ql + 4194304;
  unsigned short* Vtg = Ktg + 4194304;                       // ends 96M
  unsigned short* Wph = (unsigned short*)(wsb + 100663296);  // [96M,100M)
  unsigned short* Wpl = Wph + 1048576;
  float* kmp = (float*)(wsb + 104857600);                    // [100M,...)
  float* pos = kmp + 16384;
  float* aw  = pos + 4096;

  // 1) operand prep
  conv_split<<<2048, 256, 0, stream>>>(x, xh, xl);
  conv_split_T<<<dim3(96, 32), 256, 0, stream>>>(W_qkv, Wqh, Wql, 1024, 3072);
  conv_split_T<<<dim3(32, 32), 256, 0, stream>>>(W_proj, Wph, Wpl, 1024, 1024);
  // 2) qkv = x @ W_qkv + b (split-bf16 MFMA)
  gemm_mfma_split<<<dim3(24, 32), 256, 0, stream>>>(xh, xl, Wqh, Wql, b_qkv,
                                                    qkv_f, 4096, 3072, 1024);
  // 3) attention operand images (overwrites Wq region)
  convert_kernel<<<dim3(32, 32), 256, 0, stream>>>(qkv_f, Qh, Ql, Ktg, Vtg);
  // 4) k_mean partials / pos / aw
  kmean_part<<<dim3(32, 8), 256, 0, stream>>>(Ktg, kmp);
  pos_kernel<<<1024, 256, 0, stream>>>(Qh, Ql, kmp, pos);
  aw_kernel<<<2, 1024, 0, stream>>>(pos, aw);
  // 5) MFMA flash attention, fused aw-scale + bf16-split epilogue
  attn_mfma<<<dim3(32, 32), 256, 0, stream>>>(Qh, Ql, Ktg, Vtg, aw, A2h, A2l);
  // 6) out = A2 @ W_proj + b (split-bf16 MFMA)
  gemm_mfma_split<<<dim3(8, 32), 256, 0, stream>>>(A2h, A2l, Wph, Wpl, b_proj,
                                                   out, 4096, 1024, 1024);
}

// Round 6
// 330.034 us; speedup vs baseline: 6.1956x; 1.0579x over previous
//
#include <hip/hip_runtime.h>
#include <hip/hip_bf16.h>

// Problem constants: B=2, T=2048, W=1024, H=16, C=64
// scale^2 = 1/8 folded into Q along with log2(e) (exp2-domain softmax).

#define LOG2E 1.4426950408889634f

typedef float f32x4 __attribute__((ext_vector_type(4)));
typedef short bf16x8 __attribute__((ext_vector_type(8)));

__device__ __forceinline__ unsigned short f2bf(float f) {
  union { float f; unsigned int u; } v; v.f = f;
  unsigned int r = v.u + 0x7fffu + ((v.u >> 16) & 1u);
  return (unsigned short)(r >> 16);
}
__device__ __forceinline__ float bf2f(unsigned short h) {
  union { unsigned int u; float f; } v; v.u = ((unsigned int)h) << 16;
  return v.f;
}
// packed f32x2 -> bf16x2 (v_cvt_pk_bf16_f32 via HIP intrinsic); a in low short
__device__ __forceinline__ unsigned int pk_bf16(float a, float b) {
  union { __hip_bfloat162 h; unsigned int u; } v;
  v.h = __float22bfloat162_rn(make_float2(a, b));
  return v.u;
}

// ---------------------------------------------------------------------------
// conv_split: fp32 -> bf16 hi/lo (a ~= hi + lo, err ~2^-17).
// ---------------------------------------------------------------------------
__global__ __launch_bounds__(256) void conv_split(
    const float* __restrict__ in, unsigned short* __restrict__ hi,
    unsigned short* __restrict__ lo) {
  size_t base = ((size_t)blockIdx.x * 256 + threadIdx.x) * 8;
  float4 v0 = *(const float4*)&in[base];
  float4 v1 = *(const float4*)&in[base + 4];
  float f[8] = {v0.x, v0.y, v0.z, v0.w, v1.x, v1.y, v1.z, v1.w};
  unsigned int hw[4], lw[4];
#pragma unroll
  for (int p = 0; p < 4; ++p) {
    float a = f[2 * p], b = f[2 * p + 1];
    unsigned short ha = f2bf(a), hb = f2bf(b);
    unsigned short la = f2bf(a - bf2f(ha)), lb = f2bf(b - bf2f(hb));
    hw[p] = (unsigned int)ha | ((unsigned int)hb << 16);
    lw[p] = (unsigned int)la | ((unsigned int)lb << 16);
  }
  uint4 H = {hw[0], hw[1], hw[2], hw[3]};
  uint4 L = {lw[0], lw[1], lw[2], lw[3]};
  *(uint4*)&hi[base] = H;
  *(uint4*)&lo[base] = L;
}

// ---------------------------------------------------------------------------
// conv_split_T: in [K][N] fp32 -> out [N][K] bf16 hi/lo (LDS 32x32 transpose).
// ---------------------------------------------------------------------------
__global__ __launch_bounds__(256) void conv_split_T(
    const float* __restrict__ in, unsigned short* __restrict__ hi,
    unsigned short* __restrict__ lo, int K, int N) {
  __shared__ float t[32][33];
  const int n0 = blockIdx.x * 32, k0 = blockIdx.y * 32;
  const int r = threadIdx.x >> 3, c4 = (threadIdx.x & 7) * 4;
  float4 v = *(const float4*)&in[(size_t)(k0 + r) * N + n0 + c4];
  t[r][c4 + 0] = v.x; t[r][c4 + 1] = v.y; t[r][c4 + 2] = v.z; t[r][c4 + 3] = v.w;
  __syncthreads();
  unsigned int hw[2], lw[2];
#pragma unroll
  for (int p = 0; p < 2; ++p) {
    float a = t[c4 + 2 * p][r], b = t[c4 + 2 * p + 1][r];
    unsigned short ha = f2bf(a), hb = f2bf(b);
    unsigned short la = f2bf(a - bf2f(ha)), lb = f2bf(b - bf2f(hb));
    hw[p] = (unsigned int)ha | ((unsigned int)hb << 16);
    lw[p] = (unsigned int)la | ((unsigned int)lb << 16);
  }
  size_t o = (size_t)(n0 + r) * K + k0 + c4;
  *(uint2*)&hi[o] = make_uint2(hw[0], hw[1]);
  *(uint2*)&lo[o] = make_uint2(lw[0], lw[1]);
}

// ---------------------------------------------------------------------------
// Split-bf16 MFMA GEMM (round-3, verified): C = (Ah+Al)@(Bh+Bl)^T + bias.
// ---------------------------------------------------------------------------
__global__ __launch_bounds__(256, 2) void gemm_mfma_split(
    const unsigned short* __restrict__ Ah, const unsigned short* __restrict__ Al,
    const unsigned short* __restrict__ Bh, const unsigned short* __restrict__ Bl,
    const float* __restrict__ bias, float* __restrict__ C,
    int M, int N, int K) {
  __shared__ __align__(16) unsigned short lds[2][16384];

  const int tid = threadIdx.x;
  const int w = tid >> 6, l = tid & 63;
  const int lc = l & 15, lr = l >> 4;
  const int wr = w >> 1, wc = w & 1;
  const int m0 = blockIdx.y * 128, n0 = blockIdx.x * 128;

  f32x4 acc[4][4];
#pragma unroll
  for (int mi = 0; mi < 4; ++mi)
#pragma unroll
    for (int ni = 0; ni < 4; ++ni) acc[mi][ni] = (f32x4){0.f, 0.f, 0.f, 0.f};

  const unsigned short* src = (w == 0) ? Ah : (w == 1) ? Al : (w == 2) ? Bh : Bl;
  const int rowbase = (w < 2) ? m0 : n0;
  const int lrow = l >> 2, lkk = (l & 3) * 8;

  const int NT = K / 32;
  int buf = 0;

#define STAGE(B_, KT_)                                                         \
  {                                                                            \
    unsigned short* dst = lds[B_] + w * 4096;                                  \
    _Pragma("unroll") for (int c = 0; c < 8; ++c) {                            \
      const unsigned short* g =                                                \
          src + (size_t)(rowbase + c * 16 + lrow) * K + (KT_) + lkk;           \
      __builtin_amdgcn_global_load_lds(                                        \
          (const __attribute__((address_space(1))) unsigned int*)g,            \
          (__attribute__((address_space(3))) unsigned int*)(dst + c * 512),    \
          16, 0, 0);                                                           \
    }                                                                          \
  }

  STAGE(0, 0);
  asm volatile("s_waitcnt vmcnt(0)");
  __syncthreads();

  for (int t = 0; t < NT; ++t) {
    if (t + 1 < NT) STAGE(buf ^ 1, (t + 1) * 32);

    const unsigned short* bp = lds[buf];
    bf16x8 ah[4], al[4], bh[4], bl[4];
#pragma unroll
    for (int mi = 0; mi < 4; ++mi) {
      int ro = (wr * 64 + mi * 16 + lc) * 32 + lr * 8;
      ah[mi] = *(const bf16x8*)&bp[ro];
      al[mi] = *(const bf16x8*)&bp[4096 + ro];
    }
#pragma unroll
    for (int ni = 0; ni < 4; ++ni) {
      int co = (wc * 64 + ni * 16 + lc) * 32 + lr * 8;
      bh[ni] = *(const bf16x8*)&bp[8192 + co];
      bl[ni] = *(const bf16x8*)&bp[12288 + co];
    }

    __builtin_amdgcn_s_setprio(1);
#pragma unroll
    for (int mi = 0; mi < 4; ++mi)
#pragma unroll
      for (int ni = 0; ni < 4; ++ni) {
        acc[mi][ni] = __builtin_amdgcn_mfma_f32_16x16x32_bf16(ah[mi], bh[ni], acc[mi][ni], 0, 0, 0);
        acc[mi][ni] = __builtin_amdgcn_mfma_f32_16x16x32_bf16(ah[mi], bl[ni], acc[mi][ni], 0, 0, 0);
        acc[mi][ni] = __builtin_amdgcn_mfma_f32_16x16x32_bf16(al[mi], bh[ni], acc[mi][ni], 0, 0, 0);
      }
    __builtin_amdgcn_s_setprio(0);

    __syncthreads();
    buf ^= 1;
  }
#undef STAGE

#pragma unroll
  for (int mi = 0; mi < 4; ++mi)
#pragma unroll
    for (int r = 0; r < 4; ++r) {
      int row = m0 + wr * 64 + mi * 16 + lr * 4 + r;
#pragma unroll
      for (int ni = 0; ni < 4; ++ni) {
        int col = n0 + wc * 64 + ni * 16 + lc;
        C[(size_t)row * N + col] = acc[mi][ni][r] + bias[col];
      }
    }
}

// ---------------------------------------------------------------------------
// Pre-pass: qkv fp32 -> bf16 operands for MFMA attention (round-5, verified).
// ---------------------------------------------------------------------------
__global__ __launch_bounds__(256) void convert_kernel(
    const float* __restrict__ qkv,
    unsigned short* __restrict__ Qh, unsigned short* __restrict__ Ql,
    unsigned short* __restrict__ Ktg, unsigned short* __restrict__ Vtg) {
  const int stile = blockIdx.x, bh = blockIdx.y;
  const int b = bh >> 4, h = bh & 15;
  const int tid = threadIdx.x;
  const int s = tid >> 2;
  const int cg = (tid & 3) << 4;
  const int t = stile * 64 + s;
  const float* row = qkv + (size_t)(b * 2048 + t) * 3072 + h * 192;
  const float QS = 0.125f * LOG2E;

  __shared__ unsigned short vs[64][72];

  {
    unsigned int* qh32 = (unsigned int*)(Qh + ((size_t)bh * 2048 + t) * 64 + cg);
    unsigned int* ql32 = (unsigned int*)(Ql + ((size_t)bh * 2048 + t) * 64 + cg);
#pragma unroll
    for (int j = 0; j < 4; ++j) {
      float4 v = *(const float4*)&row[cg + j * 4];
      float f[4] = {v.x * QS, v.y * QS, v.z * QS, v.w * QS};
      unsigned short hh[4], llo[4];
#pragma unroll
      for (int e = 0; e < 4; ++e) {
        hh[e] = f2bf(f[e]);
        llo[e] = f2bf(f[e] - bf2f(hh[e]));
      }
      qh32[j * 2 + 0] = (unsigned int)hh[0] | ((unsigned int)hh[1] << 16);
      qh32[j * 2 + 1] = (unsigned int)hh[2] | ((unsigned int)hh[3] << 16);
      ql32[j * 2 + 0] = (unsigned int)llo[0] | ((unsigned int)llo[1] << 16);
      ql32[j * 2 + 1] = (unsigned int)llo[2] | ((unsigned int)llo[3] << 16);
    }
  }
  {
    unsigned int* kt32 = (unsigned int*)(Ktg + (size_t)(bh * 32 + stile) * 4096);
    const int sw = (s & 7) << 4;
#pragma unroll
    for (int j = 0; j < 4; ++j) {
      float4 v = *(const float4*)&row[64 + cg + j * 4];
      float f[4] = {v.x, v.y, v.z, v.w};
#pragma unroll
      for (int p = 0; p < 2; ++p) {
        int c0 = cg + j * 4 + p * 2;
        int byte = (s * 128 + c0 * 2) ^ sw;
        kt32[byte >> 2] = (unsigned int)f2bf(f[p * 2]) |
                          ((unsigned int)f2bf(f[p * 2 + 1]) << 16);
      }
    }
  }
#pragma unroll
  for (int j = 0; j < 4; ++j) {
    float4 v = *(const float4*)&row[128 + cg + j * 4];
    vs[s][cg + j * 4 + 0] = f2bf(v.x);
    vs[s][cg + j * 4 + 1] = f2bf(v.y);
    vs[s][cg + j * 4 + 2] = f2bf(v.z);
    vs[s][cg + j * 4 + 3] = f2bf(v.w);
  }
  __syncthreads();
  {
    const int c = tid >> 2;
    const int sb = (tid & 3) << 4;
    unsigned int* vt32 = (unsigned int*)(Vtg + (size_t)(bh * 32 + stile) * 4096);
    const int sw = (c & 7) << 4;
#pragma unroll
    for (int p = 0; p < 8; ++p) {
      int ss = sb + p * 2;
      unsigned int wv = (unsigned int)vs[ss][c] | ((unsigned int)vs[ss + 1][c] << 16);
      int byte = (c * 128 + ss * 2) ^ sw;
      vt32[byte >> 2] = wv;
    }
  }
}

// ---------------------------------------------------------------------------
// MFMA flash attention, round-6: swapped QK^T (instruction diet).
//  S^T = mfma(K, Q): lane holds one q-row (q=lc), k = st*16+lr*4+r.
//  -> scalar m/lsum, 1-cmp gate, packed b32 P-stores (8 vs 16),
//     cvt_pk packing (8 vs 32 VALU). PV + epilogue layouts unchanged.
//  Rescale/invl move q=lc -> q=lr*4+r via __shfl (gated path / epilogue only).
// ---------------------------------------------------------------------------
__global__ __launch_bounds__(256, 4) void attn_mfma(
    const unsigned short* __restrict__ Qh, const unsigned short* __restrict__ Ql,
    const unsigned short* __restrict__ Ktg, const unsigned short* __restrict__ Vtg,
    const float* __restrict__ aw,
    unsigned short* __restrict__ A2h, unsigned short* __restrict__ A2l) {
  const int qt = blockIdx.x, bh = blockIdx.y;
  const int b = bh >> 4, h = bh & 15;
  const int tid = threadIdx.x;
  const int w = tid >> 6, l = tid & 63;
  const int lc = l & 15, lr = l >> 4;

  __shared__ __align__(16) unsigned short ldsKV[2][8192];  // [K 4096 | V 4096]
  __shared__ __align__(16) unsigned short ldsP[4096];
  unsigned short* Pl = ldsP + w * 1024;        // [16 q][64 k], XOR-swizzled
  unsigned int* Plw = (unsigned int*)Pl;

  const int q0 = qt * 64 + w * 16;
  bf16x8 qh0, qh1, ql0, ql1;
  {
    size_t base = ((size_t)bh * 2048 + q0 + lc) * 64 + lr * 8;
    qh0 = *(const bf16x8*)&Qh[base];
    qh1 = *(const bf16x8*)&Qh[base + 32];
    ql0 = *(const bf16x8*)&Ql[base];
    ql1 = *(const bf16x8*)&Ql[base + 32];
  }

  // swizzled K/V fragment read indices (shorts); P reads reuse st=0 entries
  int kidx0[4], kidx1[4];
#pragma unroll
  for (int st = 0; st < 4; ++st) {
    int row = st * 16 + lc;
    int sw = (row & 7) << 4;
    kidx0[st] = ((row * 128 + lr * 16) ^ sw) >> 1;
    kidx1[st] = ((row * 128 + 64 + lr * 16) ^ sw) >> 1;
  }
  // P b32 write word-indices: row q=lc, k-pair (st*16+lr*4+rp*2, +1)
  int pww[4][2];
  {
    int sw = (lc & 7) << 4;
#pragma unroll
    for (int st = 0; st < 4; ++st)
#pragma unroll
      for (int rp = 0; rp < 2; ++rp)
        pww[st][rp] = ((lc * 128 + st * 32 + lr * 8 + rp * 4) ^ sw) >> 2;
  }

  f32x4 o[4];
  float m = -1e30f, lsum = 0.f;
#pragma unroll
  for (int ct = 0; ct < 4; ++ct) o[ct] = (f32x4){0.f, 0.f, 0.f, 0.f};

  // staging (round-5, verified): 16 chunks of 1KB; wave w handles 4.
  const unsigned short* gsrc =
      ((w < 2) ? Ktg : Vtg) + (size_t)bh * 32 * 4096 + (w & 1) * 2048 + l * 8;
  unsigned short* ldst0 = &ldsKV[0][(w >> 1) * 4096 + (w & 1) * 2048];
  unsigned short* ldst1 = &ldsKV[1][(w >> 1) * 4096 + (w & 1) * 2048];

#define STAGE_KV(DST_, T_)                                                     \
  {                                                                            \
    const unsigned short* g = gsrc + (size_t)(T_) * 4096;                      \
    _Pragma("unroll") for (int i = 0; i < 4; ++i) {                            \
      __builtin_amdgcn_global_load_lds(                                        \
          (const __attribute__((address_space(1))) unsigned int*)(g + i * 512),\
          (__attribute__((address_space(3))) unsigned int*)((DST_) + i * 512), \
          16, 0, 0);                                                           \
    }                                                                          \
  }

  STAGE_KV(ldst0, 0);
  asm volatile("s_waitcnt vmcnt(0)");
  __syncthreads();

  int buf = 0;
  for (int kvt = 0; kvt < 32; ++kvt) {
    if (kvt + 1 < 32) STAGE_KV(buf ? ldst0 : ldst1, kvt + 1);

    const unsigned short* KT = &ldsKV[buf][0];
    const unsigned short* VT = &ldsKV[buf][4096];

    // swapped QK^T: sacc[st] = S^T[k=st*16+lr*4+r][q=lc]
    f32x4 sacc[4];
    __builtin_amdgcn_s_setprio(1);
#pragma unroll
    for (int st = 0; st < 4; ++st) {
      bf16x8 k0 = *(const bf16x8*)&KT[kidx0[st]];
      bf16x8 k1 = *(const bf16x8*)&KT[kidx1[st]];
      f32x4 acc = (f32x4){0.f, 0.f, 0.f, 0.f};
      acc = __builtin_amdgcn_mfma_f32_16x16x32_bf16(k0, qh0, acc, 0, 0, 0);
      acc = __builtin_amdgcn_mfma_f32_16x16x32_bf16(k1, qh1, acc, 0, 0, 0);
      acc = __builtin_amdgcn_mfma_f32_16x16x32_bf16(k0, ql0, acc, 0, 0, 0);
      acc = __builtin_amdgcn_mfma_f32_16x16x32_bf16(k1, ql1, acc, 0, 0, 0);
      sacc[st] = acc;
    }
    __builtin_amdgcn_s_setprio(0);

    // scalar online softmax for row q=lc
    float pmax = fmaxf(fmaxf(fmaxf(sacc[0][0], sacc[0][1]), fmaxf(sacc[0][2], sacc[0][3])),
                       fmaxf(fmaxf(sacc[1][0], sacc[1][1]), fmaxf(sacc[1][2], sacc[1][3])));
    pmax = fmaxf(pmax,
           fmaxf(fmaxf(fmaxf(sacc[2][0], sacc[2][1]), fmaxf(sacc[2][2], sacc[2][3])),
                 fmaxf(fmaxf(sacc[3][0], sacc[3][1]), fmaxf(sacc[3][2], sacc[3][3]))));
    if (__any(pmax > m)) {
      float pm = fmaxf(pmax, __shfl_xor(pmax, 16));
      pm = fmaxf(pm, __shfl_xor(pm, 32));
      float mn = fmaxf(m, pm);
      float corr = exp2f(m - mn);
      m = mn;
      lsum *= corr;
#pragma unroll
      for (int r = 0; r < 4; ++r) {
        float cq = __shfl(corr, lr * 4 + r);
        o[0][r] *= cq; o[1][r] *= cq; o[2][r] *= cq; o[3][r] *= cq;
      }
    }

    // exp2 + per-lane row partial sum
#pragma unroll
    for (int st = 0; st < 4; ++st)
#pragma unroll
      for (int r = 0; r < 4; ++r)
        sacc[st][r] = exp2f(sacc[st][r] - m);
#pragma unroll
    for (int st = 0; st < 4; ++st)
      lsum += (sacc[st][0] + sacc[st][1]) + (sacc[st][2] + sacc[st][3]);

    // pack pairs (adjacent k) + 8 b32 stores
#pragma unroll
    for (int st = 0; st < 4; ++st) {
      Plw[pww[st][0]] = pk_bf16(sacc[st][0], sacc[st][1]);
      Plw[pww[st][1]] = pk_bf16(sacc[st][2], sacc[st][3]);
    }

    bf16x8 pa0 = *(const bf16x8*)&Pl[kidx0[0]];
    bf16x8 pa1 = *(const bf16x8*)&Pl[kidx1[0]];

    // PV: O += P @ V (unchanged)
    __builtin_amdgcn_s_setprio(1);
#pragma unroll
    for (int ct = 0; ct < 4; ++ct) {
      bf16x8 v0 = *(const bf16x8*)&VT[kidx0[ct]];
      bf16x8 v1 = *(const bf16x8*)&VT[kidx1[ct]];
      o[ct] = __builtin_amdgcn_mfma_f32_16x16x32_bf16(pa0, v0, o[ct], 0, 0, 0);
      o[ct] = __builtin_amdgcn_mfma_f32_16x16x32_bf16(pa1, v1, o[ct], 0, 0, 0);
    }
    __builtin_amdgcn_s_setprio(0);
    __syncthreads();
    buf ^= 1;
  }
#undef STAGE_KV

  // row sum for q=lc, then move to q=lr*4+r for the epilogue
  lsum += __shfl_xor(lsum, 16);
  lsum += __shfl_xor(lsum, 32);
  float inv = 1.0f / lsum;
#pragma unroll
  for (int r = 0; r < 4; ++r) {
    int t = q0 + lr * 4 + r;
    float sc = aw[b * 2048 + t] * __shfl(inv, lr * 4 + r);
    size_t off = (size_t)(b * 2048 + t) * 1024 + h * 64 + lc;
#pragma unroll
    for (int ct = 0; ct < 4; ++ct) {
      float v = o[ct][r] * sc;
      unsigned short hh = f2bf(v);
      A2h[off + ct * 16] = hh;
      A2l[off + ct * 16] = f2bf(v - bf2f(hh));
    }
  }
}

// ---------------------------------------------------------------------------
// k_mean partials / pos / aw (round-5, verified)
// ---------------------------------------------------------------------------
__global__ __launch_bounds__(256) void kmean_part(
    const unsigned short* __restrict__ Ktg, float* __restrict__ kmp) {
  const int bh = blockIdx.x, seg = blockIdx.y;
  const int c = threadIdx.x & 63, sub = threadIdx.x >> 6;
  const int tile = seg * 4 + sub;
  const unsigned short* kt = Ktg + (size_t)(bh * 32 + tile) * 4096;
  float sum = 0.f;
#pragma unroll 8
  for (int s = 0; s < 64; ++s) {
    int sidx = ((s * 128 + c * 2) ^ ((s & 7) << 4)) >> 1;
    sum += bf2f(kt[sidx]);
  }
  __shared__ float red[4][64];
  red[sub][c] = sum;
  __syncthreads();
  if (sub == 0)
    kmp[(size_t)(bh * 8 + seg) * 64 + c] =
        red[0][c] + red[1][c] + red[2][c] + red[3][c];
}

__global__ __launch_bounds__(256) void pos_kernel(
    const unsigned short* __restrict__ Qh, const unsigned short* __restrict__ Ql,
    const float* __restrict__ kmp, float* __restrict__ pos) {
  __shared__ float kms[1024];
  int blk = blockIdx.x;
  int b = (blk * 4) >> 11;
  for (int i = threadIdx.x; i < 1024; i += 256) {
    int h = i >> 6, cc = i & 63;
    float s = 0.f;
#pragma unroll
    for (int seg = 0; seg < 8; ++seg)
      s += kmp[(size_t)((b * 16 + h) * 8 + seg) * 64 + cc];
    kms[i] = s * (1.0f / 2048.0f) * (1.0f / LOG2E);
  }
  __syncthreads();
  int w = threadIdx.x >> 6, lane = threadIdx.x & 63;
  int row = blk * 4 + w;
  int t = row & 2047;
  float p = 0.f;
#pragma unroll
  for (int h = 0; h < 16; ++h) {
    size_t idx = ((size_t)(b * 16 + h) * 2048 + t) * 64 + lane;
    p = fmaf(bf2f(Qh[idx]) + bf2f(Ql[idx]), kms[h * 64 + lane], p);
  }
#pragma unroll
  for (int off = 32; off; off >>= 1) p += __shfl_xor(p, off, 64);
  if (lane == 0) pos[row] = p;
}

__global__ __launch_bounds__(1024) void aw_kernel(const float* __restrict__ pos,
                                                  float* __restrict__ aw) {
  int b = blockIdx.x, tid = threadIdx.x;
  float p0 = pos[b * 2048 + tid], p1 = pos[b * 2048 + 1024 + tid];
  float mn = fminf(p0, p1), mx = fmaxf(p0, p1);
#pragma unroll
  for (int off = 32; off; off >>= 1) {
    mn = fminf(mn, __shfl_xor(mn, off, 64));
    mx = fmaxf(mx, __shfl_xor(mx, off, 64));
  }
  __shared__ float smn[16], smx[16];
  int wave = tid >> 6, lane = tid & 63;
  if (lane == 0) { smn[wave] = mn; smx[wave] = mx; }
  __syncthreads();
  if (tid < 64) {
    mn = (lane < 16) ? smn[lane] : 3.0e38f;
    mx = (lane < 16) ? smx[lane] : -3.0e38f;
#pragma unroll
    for (int off = 8; off; off >>= 1) {
      mn = fminf(mn, __shfl_xor(mn, off, 64));
      mx = fmaxf(mx, __shfl_xor(mx, off, 64));
    }
    if (lane == 0) { smn[0] = mn; smx[0] = mx; }
  }
  __syncthreads();
  float MN = smn[0], inv = 1.0f / (smx[0] - MN + 1e-6f);
  aw[b * 2048 + tid] = (p0 - MN) * inv;
  aw[b * 2048 + 1024 + tid] = (p1 - MN) * inv;
}

// ---------------------------------------------------------------------------
// Workspace layout (round-5, verified; peak ~104.9 MB)
// ---------------------------------------------------------------------------
extern "C" void kernel_launch(void* const* d_in, const int* in_sizes, int n_in,
                              void* d_out, int out_size, void* d_ws, size_t ws_size,
                              hipStream_t stream) {
  const float* x      = (const float*)d_in[0];
  const float* W_qkv  = (const float*)d_in[1];
  const float* b_qkv  = (const float*)d_in[2];
  const float* W_proj = (const float*)d_in[3];
  const float* b_proj = (const float*)d_in[4];
  float* out = (float*)d_out;

  char* wsb = (char*)d_ws;
  unsigned short* xh  = (unsigned short*)wsb;                // [0,16M)
  unsigned short* xl  = xh + 4194304;
  unsigned short* A2h = (unsigned short*)wsb;                // reuse after gemm_qkv
  unsigned short* A2l = A2h + 4194304;
  float* qkv_f = (float*)(wsb + 16777216);                   // [16M,64M)
  unsigned short* Wqh = (unsigned short*)(wsb + 67108864);   // [64M,76.6M)
  unsigned short* Wql = Wqh + 3145728;
  unsigned short* Qh  = (unsigned short*)(wsb + 67108864);   // images overlay Wq
  unsigned short* Ql  = Qh + 4194304;
  unsigned short* Ktg = Ql + 4194304;
  unsigned short* Vtg = Ktg + 4194304;                       // ends 96M
  unsigned short* Wph = (unsigned short*)(wsb + 100663296);  // [96M,100M)
  unsigned short* Wpl = Wph + 1048576;
  float* kmp = (float*)(wsb + 104857600);                    // [100M,...)
  float* pos = kmp + 16384;
  float* aw  = pos + 4096;

  // 1) operand prep
  conv_split<<<2048, 256, 0, stream>>>(x, xh, xl);
  conv_split_T<<<dim3(96, 32), 256, 0, stream>>>(W_qkv, Wqh, Wql, 1024, 3072);
  conv_split_T<<<dim3(32, 32), 256, 0, stream>>>(W_proj, Wph, Wpl, 1024, 1024);
  // 2) qkv = x @ W_qkv + b (split-bf16 MFMA)
  gemm_mfma_split<<<dim3(24, 32), 256, 0, stream>>>(xh, xl, Wqh, Wql, b_qkv,
                                                    qkv_f, 4096, 3072, 1024);
  // 3) attention operand images (overwrites Wq region)
  convert_kernel<<<dim3(32, 32), 256, 0, stream>>>(qkv_f, Qh, Ql, Ktg, Vtg);
  // 4) k_mean partials / pos / aw
  kmean_part<<<dim3(32, 8), 256, 0, stream>>>(Ktg, kmp);
  pos_kernel<<<1024, 256, 0, stream>>>(Qh, Ql, kmp, pos);
  aw_kernel<<<2, 1024, 0, stream>>>(pos, aw);
  // 5) MFMA flash attention (swapped QK^T), fused aw-scale + split epilogue
  attn_mfma<<<dim3(32, 32), 256, 0, stream>>>(Qh, Ql, Ktg, Vtg, aw, A2h, A2l);
  // 6) out = A2 @ W_proj + b (split-bf16 MFMA)
  gemm_mfma_split<<<dim3(8, 32), 256, 0, stream>>>(A2h, A2l, Wph, Wpl, b_proj,
                                                   out, 4096, 1024, 1024);
}

// Round 7
// 294.659 us; speedup vs baseline: 6.9394x; 1.1201x over previous
//
#include <hip/hip_runtime.h>
#include <hip/hip_bf16.h>

// Problem constants: B=2, T=2048, W=1024, H=16, C=64
// scale^2 = 1/8 folded into Q along with log2(e) (exp2-domain softmax).

#define LOG2E 1.4426950408889634f

typedef float f32x4 __attribute__((ext_vector_type(4)));
typedef short bf16x8 __attribute__((ext_vector_type(8)));

__device__ __forceinline__ unsigned short f2bf(float f) {
  union { float f; unsigned int u; } v; v.f = f;
  unsigned int r = v.u + 0x7fffu + ((v.u >> 16) & 1u);
  return (unsigned short)(r >> 16);
}
__device__ __forceinline__ float bf2f(unsigned short h) {
  union { unsigned int u; float f; } v; v.u = ((unsigned int)h) << 16;
  return v.f;
}
// packed f32x2 -> bf16x2; a in low short
__device__ __forceinline__ unsigned int pk_bf16(float a, float b) {
  union { __hip_bfloat162 h; unsigned int u; } v;
  v.h = __float22bfloat162_rn(make_float2(a, b));
  return v.u;
}

// ---------------------------------------------------------------------------
// conv_split: fp32 -> bf16 hi/lo (a ~= hi + lo, err ~2^-17).
// ---------------------------------------------------------------------------
__global__ __launch_bounds__(256) void conv_split(
    const float* __restrict__ in, unsigned short* __restrict__ hi,
    unsigned short* __restrict__ lo) {
  size_t base = ((size_t)blockIdx.x * 256 + threadIdx.x) * 8;
  float4 v0 = *(const float4*)&in[base];
  float4 v1 = *(const float4*)&in[base + 4];
  float f[8] = {v0.x, v0.y, v0.z, v0.w, v1.x, v1.y, v1.z, v1.w};
  unsigned int hw[4], lw[4];
#pragma unroll
  for (int p = 0; p < 4; ++p) {
    float a = f[2 * p], b = f[2 * p + 1];
    unsigned short ha = f2bf(a), hb = f2bf(b);
    unsigned short la = f2bf(a - bf2f(ha)), lb = f2bf(b - bf2f(hb));
    hw[p] = (unsigned int)ha | ((unsigned int)hb << 16);
    lw[p] = (unsigned int)la | ((unsigned int)lb << 16);
  }
  uint4 H = {hw[0], hw[1], hw[2], hw[3]};
  uint4 L = {lw[0], lw[1], lw[2], lw[3]};
  *(uint4*)&hi[base] = H;
  *(uint4*)&lo[base] = L;
}

// ---------------------------------------------------------------------------
// conv_split_T: in [K][N] fp32 -> out [N][K] bf16 hi/lo (LDS 32x32 transpose).
// ---------------------------------------------------------------------------
__global__ __launch_bounds__(256) void conv_split_T(
    const float* __restrict__ in, unsigned short* __restrict__ hi,
    unsigned short* __restrict__ lo, int K, int N) {
  __shared__ float t[32][33];
  const int n0 = blockIdx.x * 32, k0 = blockIdx.y * 32;
  const int r = threadIdx.x >> 3, c4 = (threadIdx.x & 7) * 4;
  float4 v = *(const float4*)&in[(size_t)(k0 + r) * N + n0 + c4];
  t[r][c4 + 0] = v.x; t[r][c4 + 1] = v.y; t[r][c4 + 2] = v.z; t[r][c4 + 3] = v.w;
  __syncthreads();
  unsigned int hw[2], lw[2];
#pragma unroll
  for (int p = 0; p < 2; ++p) {
    float a = t[c4 + 2 * p][r], b = t[c4 + 2 * p + 1][r];
    unsigned short ha = f2bf(a), hb = f2bf(b);
    unsigned short la = f2bf(a - bf2f(ha)), lb = f2bf(b - bf2f(hb));
    hw[p] = (unsigned int)ha | ((unsigned int)hb << 16);
    lw[p] = (unsigned int)la | ((unsigned int)lb << 16);
  }
  size_t o = (size_t)(n0 + r) * K + k0 + c4;
  *(uint2*)&hi[o] = make_uint2(hw[0], hw[1]);
  *(uint2*)&lo[o] = make_uint2(lw[0], lw[1]);
}

// ---------------------------------------------------------------------------
// Split-bf16 MFMA GEMM (round-3, verified): C = (Ah+Al)@(Bh+Bl)^T + bias.
// Used for the proj GEMM only now.
// ---------------------------------------------------------------------------
__global__ __launch_bounds__(256, 2) void gemm_mfma_split(
    const unsigned short* __restrict__ Ah, const unsigned short* __restrict__ Al,
    const unsigned short* __restrict__ Bh, const unsigned short* __restrict__ Bl,
    const float* __restrict__ bias, float* __restrict__ C,
    int M, int N, int K) {
  __shared__ __align__(16) unsigned short lds[2][16384];

  const int tid = threadIdx.x;
  const int w = tid >> 6, l = tid & 63;
  const int lc = l & 15, lr = l >> 4;
  const int wr = w >> 1, wc = w & 1;
  const int m0 = blockIdx.y * 128, n0 = blockIdx.x * 128;

  f32x4 acc[4][4];
#pragma unroll
  for (int mi = 0; mi < 4; ++mi)
#pragma unroll
    for (int ni = 0; ni < 4; ++ni) acc[mi][ni] = (f32x4){0.f, 0.f, 0.f, 0.f};

  const unsigned short* src = (w == 0) ? Ah : (w == 1) ? Al : (w == 2) ? Bh : Bl;
  const int rowbase = (w < 2) ? m0 : n0;
  const int lrow = l >> 2, lkk = (l & 3) * 8;

  const int NT = K / 32;
  int buf = 0;

#define STAGE(B_, KT_)                                                         \
  {                                                                            \
    unsigned short* dst = lds[B_] + w * 4096;                                  \
    _Pragma("unroll") for (int c = 0; c < 8; ++c) {                            \
      const unsigned short* g =                                                \
          src + (size_t)(rowbase + c * 16 + lrow) * K + (KT_) + lkk;           \
      __builtin_amdgcn_global_load_lds(                                        \
          (const __attribute__((address_space(1))) unsigned int*)g,            \
          (__attribute__((address_space(3))) unsigned int*)(dst + c * 512),    \
          16, 0, 0);                                                           \
    }                                                                          \
  }

  STAGE(0, 0);
  asm volatile("s_waitcnt vmcnt(0)");
  __syncthreads();

  for (int t = 0; t < NT; ++t) {
    if (t + 1 < NT) STAGE(buf ^ 1, (t + 1) * 32);

    const unsigned short* bp = lds[buf];
    bf16x8 ah[4], al[4], bh[4], bl[4];
#pragma unroll
    for (int mi = 0; mi < 4; ++mi) {
      int ro = (wr * 64 + mi * 16 + lc) * 32 + lr * 8;
      ah[mi] = *(const bf16x8*)&bp[ro];
      al[mi] = *(const bf16x8*)&bp[4096 + ro];
    }
#pragma unroll
    for (int ni = 0; ni < 4; ++ni) {
      int co = (wc * 64 + ni * 16 + lc) * 32 + lr * 8;
      bh[ni] = *(const bf16x8*)&bp[8192 + co];
      bl[ni] = *(const bf16x8*)&bp[12288 + co];
    }

    __builtin_amdgcn_s_setprio(1);
#pragma unroll
    for (int mi = 0; mi < 4; ++mi)
#pragma unroll
      for (int ni = 0; ni < 4; ++ni) {
        acc[mi][ni] = __builtin_amdgcn_mfma_f32_16x16x32_bf16(ah[mi], bh[ni], acc[mi][ni], 0, 0, 0);
        acc[mi][ni] = __builtin_amdgcn_mfma_f32_16x16x32_bf16(ah[mi], bl[ni], acc[mi][ni], 0, 0, 0);
        acc[mi][ni] = __builtin_amdgcn_mfma_f32_16x16x32_bf16(al[mi], bh[ni], acc[mi][ni], 0, 0, 0);
      }
    __builtin_amdgcn_s_setprio(0);

    __syncthreads();
    buf ^= 1;
  }
#undef STAGE

#pragma unroll
  for (int mi = 0; mi < 4; ++mi)
#pragma unroll
    for (int r = 0; r < 4; ++r) {
      int row = m0 + wr * 64 + mi * 16 + lr * 4 + r;
#pragma unroll
      for (int ni = 0; ni < 4; ++ni) {
        int col = n0 + wc * 64 + ni * 16 + lc;
        C[(size_t)row * N + col] = acc[mi][ni][r] + bias[col];
      }
    }
}

// ---------------------------------------------------------------------------
// qkv GEMM with FUSED image epilogue: instead of fp32 qkv, directly emits
//  Qh/Ql (scaled hi/lo split, row-major), Ktg / Vtg (swizzled tile images).
// Role blocks (Q/K/V) are 64-aligned and the 16-lane col span is 16-aligned
// -> role/h are uniform across the span (no divergence).
// M=4096, N=3072, K=1024.
// ---------------------------------------------------------------------------
__global__ __launch_bounds__(256, 2) void gemm_qkv_fused(
    const unsigned short* __restrict__ Ah, const unsigned short* __restrict__ Al,
    const unsigned short* __restrict__ Bh, const unsigned short* __restrict__ Bl,
    const float* __restrict__ bias,
    unsigned short* __restrict__ Qh, unsigned short* __restrict__ Ql,
    unsigned short* __restrict__ Ktg, unsigned short* __restrict__ Vtg) {
  const int M = 4096, N = 3072, K = 1024;
  (void)M; (void)N;
  __shared__ __align__(16) unsigned short lds[2][16384];

  const int tid = threadIdx.x;
  const int w = tid >> 6, l = tid & 63;
  const int lc = l & 15, lr = l >> 4;
  const int wr = w >> 1, wc = w & 1;
  const int m0 = blockIdx.y * 128, n0 = blockIdx.x * 128;

  f32x4 acc[4][4];
#pragma unroll
  for (int mi = 0; mi < 4; ++mi)
#pragma unroll
    for (int ni = 0; ni < 4; ++ni) acc[mi][ni] = (f32x4){0.f, 0.f, 0.f, 0.f};

  const unsigned short* src = (w == 0) ? Ah : (w == 1) ? Al : (w == 2) ? Bh : Bl;
  const int rowbase = (w < 2) ? m0 : n0;
  const int lrow = l >> 2, lkk = (l & 3) * 8;

  const int NT = K / 32;
  int buf = 0;

#define STAGEQ(B_, KT_)                                                        \
  {                                                                            \
    unsigned short* dst = lds[B_] + w * 4096;                                  \
    _Pragma("unroll") for (int c = 0; c < 8; ++c) {                            \
      const unsigned short* g =                                                \
          src + (size_t)(rowbase + c * 16 + lrow) * K + (KT_) + lkk;           \
      __builtin_amdgcn_global_load_lds(                                        \
          (const __attribute__((address_space(1))) unsigned int*)g,            \
          (__attribute__((address_space(3))) unsigned int*)(dst + c * 512),    \
          16, 0, 0);                                                           \
    }                                                                          \
  }

  STAGEQ(0, 0);
  asm volatile("s_waitcnt vmcnt(0)");
  __syncthreads();

  for (int t = 0; t < NT; ++t) {
    if (t + 1 < NT) STAGEQ(buf ^ 1, (t + 1) * 32);

    const unsigned short* bp = lds[buf];
    bf16x8 ah[4], al[4], bh[4], bl[4];
#pragma unroll
    for (int mi = 0; mi < 4; ++mi) {
      int ro = (wr * 64 + mi * 16 + lc) * 32 + lr * 8;
      ah[mi] = *(const bf16x8*)&bp[ro];
      al[mi] = *(const bf16x8*)&bp[4096 + ro];
    }
#pragma unroll
    for (int ni = 0; ni < 4; ++ni) {
      int co = (wc * 64 + ni * 16 + lc) * 32 + lr * 8;
      bh[ni] = *(const bf16x8*)&bp[8192 + co];
      bl[ni] = *(const bf16x8*)&bp[12288 + co];
    }

    __builtin_amdgcn_s_setprio(1);
#pragma unroll
    for (int mi = 0; mi < 4; ++mi)
#pragma unroll
      for (int ni = 0; ni < 4; ++ni) {
        acc[mi][ni] = __builtin_amdgcn_mfma_f32_16x16x32_bf16(ah[mi], bh[ni], acc[mi][ni], 0, 0, 0);
        acc[mi][ni] = __builtin_amdgcn_mfma_f32_16x16x32_bf16(ah[mi], bl[ni], acc[mi][ni], 0, 0, 0);
        acc[mi][ni] = __builtin_amdgcn_mfma_f32_16x16x32_bf16(al[mi], bh[ni], acc[mi][ni], 0, 0, 0);
      }
    __builtin_amdgcn_s_setprio(0);

    __syncthreads();
    buf ^= 1;
  }
#undef STAGEQ

  // fused epilogue
  const float QS = 0.125f * LOG2E;
#pragma unroll
  for (int ni = 0; ni < 4; ++ni) {
    int col = n0 + wc * 64 + ni * 16 + lc;   // 0..3071
    int h = col / 192;
    int rr = col - h * 192;
    float bs = bias[col];
    if (rr < 64) {  // Q: scaled hi/lo split, row-major [bh][t][c]
      int c = rr;
#pragma unroll
      for (int mi = 0; mi < 4; ++mi)
#pragma unroll
        for (int r = 0; r < 4; ++r) {
          int row = m0 + wr * 64 + mi * 16 + lr * 4 + r;
          int bb = row >> 11, tl = row & 2047;
          float v = (acc[mi][ni][r] + bs) * QS;
          unsigned short hh = f2bf(v);
          size_t off = ((size_t)(bb * 16 + h) * 2048 + tl) * 64 + c;
          Qh[off] = hh;
          Ql[off] = f2bf(v - bf2f(hh));
        }
    } else if (rr < 128) {  // K: swizzled tile image [bh*32+st][s][c]
      int c2 = (rr - 64) * 2;
#pragma unroll
      for (int mi = 0; mi < 4; ++mi)
#pragma unroll
        for (int r = 0; r < 4; ++r) {
          int row = m0 + wr * 64 + mi * 16 + lr * 4 + r;
          int bb = row >> 11, tl = row & 2047;
          int s = tl & 63;
          size_t base = (size_t)((bb * 16 + h) * 32 + (tl >> 6)) * 4096;
          Ktg[base + (((s * 128 + c2) ^ ((s & 7) << 4)) >> 1)] =
              f2bf(acc[mi][ni][r] + bs);
        }
    } else {  // V: transposed swizzled image [bh*32+st][c][s]
      int cb = (rr - 128) * 128, csw = ((rr - 128) & 7) << 4;
#pragma unroll
      for (int mi = 0; mi < 4; ++mi)
#pragma unroll
        for (int r = 0; r < 4; ++r) {
          int row = m0 + wr * 64 + mi * 16 + lr * 4 + r;
          int bb = row >> 11, tl = row & 2047;
          int s = tl & 63;
          size_t base = (size_t)((bb * 16 + h) * 32 + (tl >> 6)) * 4096;
          Vtg[base + (((cb + s * 2) ^ csw) >> 1)] = f2bf(acc[mi][ni][r] + bs);
        }
    }
  }
}

// ---------------------------------------------------------------------------
// MFMA flash attention, round-7:
//  - b64 P-stores (4 ds_write_b64, conflict-free bank mapping)
//  - T13 defer-max (THR=8): rescale path ~never fires after tile 0
//  Rest as round-6 (swapped QK^T, dbuf staging, fused aw/split epilogue).
// ---------------------------------------------------------------------------
__global__ __launch_bounds__(256, 4) void attn_mfma(
    const unsigned short* __restrict__ Qh, const unsigned short* __restrict__ Ql,
    const unsigned short* __restrict__ Ktg, const unsigned short* __restrict__ Vtg,
    const float* __restrict__ aw,
    unsigned short* __restrict__ A2h, unsigned short* __restrict__ A2l) {
  const int qt = blockIdx.x, bh = blockIdx.y;
  const int b = bh >> 4, h = bh & 15;
  const int tid = threadIdx.x;
  const int w = tid >> 6, l = tid & 63;
  const int lc = l & 15, lr = l >> 4;

  __shared__ __align__(16) unsigned short ldsKV[2][8192];  // [K 4096 | V 4096]
  __shared__ __align__(16) unsigned short ldsP[4096];
  unsigned short* Pl = ldsP + w * 1024;        // [16 q][64 k], XOR-swizzled
  uint2* Pl2 = (uint2*)Pl;

  const int q0 = qt * 64 + w * 16;
  bf16x8 qh0, qh1, ql0, ql1;
  {
    size_t base = ((size_t)bh * 2048 + q0 + lc) * 64 + lr * 8;
    qh0 = *(const bf16x8*)&Qh[base];
    qh1 = *(const bf16x8*)&Qh[base + 32];
    ql0 = *(const bf16x8*)&Ql[base];
    ql1 = *(const bf16x8*)&Ql[base + 32];
  }

  // swizzled K/V fragment read indices (shorts); P reads reuse st=0 entries
  int kidx0[4], kidx1[4];
#pragma unroll
  for (int st = 0; st < 4; ++st) {
    int row = st * 16 + lc;
    int sw = (row & 7) << 4;
    kidx0[st] = ((row * 128 + lr * 16) ^ sw) >> 1;
    kidx1[st] = ((row * 128 + 64 + lr * 16) ^ sw) >> 1;
  }
  // P b64 write indices (uint2): byte = lc*128 + st*32 + lr*8 (8B-aligned;
  // XOR touches bits 4-6 only -> alignment preserved; bank-pair mapping
  // {lr0, lr1^lc0, st0^lc1, st1^lc2} -> minimum-cycle, conflict-free)
  int pwd[4];
  {
    int sw = (lc & 7) << 4;
#pragma unroll
    for (int st = 0; st < 4; ++st)
      pwd[st] = ((lc * 128 + st * 32 + lr * 8) ^ sw) >> 3;
  }

  f32x4 o[4];
  float m = -1e30f, lsum = 0.f;
#pragma unroll
  for (int ct = 0; ct < 4; ++ct) o[ct] = (f32x4){0.f, 0.f, 0.f, 0.f};

  // staging (round-5, verified): 16 chunks of 1KB; wave w handles 4.
  const unsigned short* gsrc =
      ((w < 2) ? Ktg : Vtg) + (size_t)bh * 32 * 4096 + (w & 1) * 2048 + l * 8;
  unsigned short* ldst0 = &ldsKV[0][(w >> 1) * 4096 + (w & 1) * 2048];
  unsigned short* ldst1 = &ldsKV[1][(w >> 1) * 4096 + (w & 1) * 2048];

#define STAGE_KV(DST_, T_)                                                     \
  {                                                                            \
    const unsigned short* g = gsrc + (size_t)(T_) * 4096;                      \
    _Pragma("unroll") for (int i = 0; i < 4; ++i) {                            \
      __builtin_amdgcn_global_load_lds(                                        \
          (const __attribute__((address_space(1))) unsigned int*)(g + i * 512),\
          (__attribute__((address_space(3))) unsigned int*)((DST_) + i * 512), \
          16, 0, 0);                                                           \
    }                                                                          \
  }

  STAGE_KV(ldst0, 0);
  asm volatile("s_waitcnt vmcnt(0)");
  __syncthreads();

  int buf = 0;
  for (int kvt = 0; kvt < 32; ++kvt) {
    if (kvt + 1 < 32) STAGE_KV(buf ? ldst0 : ldst1, kvt + 1);

    const unsigned short* KT = &ldsKV[buf][0];
    const unsigned short* VT = &ldsKV[buf][4096];

    // swapped QK^T: sacc[st] = S^T[k=st*16+lr*4+r][q=lc]
    f32x4 sacc[4];
    __builtin_amdgcn_s_setprio(1);
#pragma unroll
    for (int st = 0; st < 4; ++st) {
      bf16x8 k0 = *(const bf16x8*)&KT[kidx0[st]];
      bf16x8 k1 = *(const bf16x8*)&KT[kidx1[st]];
      f32x4 acc = (f32x4){0.f, 0.f, 0.f, 0.f};
      acc = __builtin_amdgcn_mfma_f32_16x16x32_bf16(k0, qh0, acc, 0, 0, 0);
      acc = __builtin_amdgcn_mfma_f32_16x16x32_bf16(k1, qh1, acc, 0, 0, 0);
      acc = __builtin_amdgcn_mfma_f32_16x16x32_bf16(k0, ql0, acc, 0, 0, 0);
      acc = __builtin_amdgcn_mfma_f32_16x16x32_bf16(k1, ql1, acc, 0, 0, 0);
      sacc[st] = acc;
    }
    __builtin_amdgcn_s_setprio(0);

    // T13 defer-max: keep reference m unless exceeded by >8 (exp2 domain;
    // P bounded by 2^8 = 256, harmless for bf16 P / fp32 lsum).
    float pmax = fmaxf(fmaxf(fmaxf(sacc[0][0], sacc[0][1]), fmaxf(sacc[0][2], sacc[0][3])),
                       fmaxf(fmaxf(sacc[1][0], sacc[1][1]), fmaxf(sacc[1][2], sacc[1][3])));
    pmax = fmaxf(pmax,
           fmaxf(fmaxf(fmaxf(sacc[2][0], sacc[2][1]), fmaxf(sacc[2][2], sacc[2][3])),
                 fmaxf(fmaxf(sacc[3][0], sacc[3][1]), fmaxf(sacc[3][2], sacc[3][3]))));
    if (__any(pmax > m + 8.0f)) {
      float pm = fmaxf(pmax, __shfl_xor(pmax, 16));
      pm = fmaxf(pm, __shfl_xor(pm, 32));
      float mn = fmaxf(m, pm);
      float corr = exp2f(m - mn);
      m = mn;
      lsum *= corr;
#pragma unroll
      for (int r = 0; r < 4; ++r) {
        float cq = __shfl(corr, lr * 4 + r);
        o[0][r] *= cq; o[1][r] *= cq; o[2][r] *= cq; o[3][r] *= cq;
      }
    }

    // exp2 + per-lane row partial sum
#pragma unroll
    for (int st = 0; st < 4; ++st)
#pragma unroll
      for (int r = 0; r < 4; ++r)
        sacc[st][r] = exp2f(sacc[st][r] - m);
#pragma unroll
    for (int st = 0; st < 4; ++st)
      lsum += (sacc[st][0] + sacc[st][1]) + (sacc[st][2] + sacc[st][3]);

    // pack 4 adjacent k into one b64 store (conflict-free)
#pragma unroll
    for (int st = 0; st < 4; ++st) {
      uint2 pv;
      pv.x = pk_bf16(sacc[st][0], sacc[st][1]);
      pv.y = pk_bf16(sacc[st][2], sacc[st][3]);
      Pl2[pwd[st]] = pv;
    }

    bf16x8 pa0 = *(const bf16x8*)&Pl[kidx0[0]];
    bf16x8 pa1 = *(const bf16x8*)&Pl[kidx1[0]];

    // PV: O += P @ V
    __builtin_amdgcn_s_setprio(1);
#pragma unroll
    for (int ct = 0; ct < 4; ++ct) {
      bf16x8 v0 = *(const bf16x8*)&VT[kidx0[ct]];
      bf16x8 v1 = *(const bf16x8*)&VT[kidx1[ct]];
      o[ct] = __builtin_amdgcn_mfma_f32_16x16x32_bf16(pa0, v0, o[ct], 0, 0, 0);
      o[ct] = __builtin_amdgcn_mfma_f32_16x16x32_bf16(pa1, v1, o[ct], 0, 0, 0);
    }
    __builtin_amdgcn_s_setprio(0);
    __syncthreads();
    buf ^= 1;
  }
#undef STAGE_KV

  // row sum for q=lc, then move to q=lr*4+r for the epilogue
  lsum += __shfl_xor(lsum, 16);
  lsum += __shfl_xor(lsum, 32);
  float inv = 1.0f / lsum;
#pragma unroll
  for (int r = 0; r < 4; ++r) {
    int t = q0 + lr * 4 + r;
    float sc = aw[b * 2048 + t] * __shfl(inv, lr * 4 + r);
    size_t off = (size_t)(b * 2048 + t) * 1024 + h * 64 + lc;
#pragma unroll
    for (int ct = 0; ct < 4; ++ct) {
      float v = o[ct][r] * sc;
      unsigned short hh = f2bf(v);
      A2h[off + ct * 16] = hh;
      A2l[off + ct * 16] = f2bf(v - bf2f(hh));
    }
  }
}

// ---------------------------------------------------------------------------
// k_mean partials / pos / aw (round-5, verified)
// ---------------------------------------------------------------------------
__global__ __launch_bounds__(256) void kmean_part(
    const unsigned short* __restrict__ Ktg, float* __restrict__ kmp) {
  const int bh = blockIdx.x, seg = blockIdx.y;
  const int c = threadIdx.x & 63, sub = threadIdx.x >> 6;
  const int tile = seg * 4 + sub;
  const unsigned short* kt = Ktg + (size_t)(bh * 32 + tile) * 4096;
  float sum = 0.f;
#pragma unroll 8
  for (int s = 0; s < 64; ++s) {
    int sidx = ((s * 128 + c * 2) ^ ((s & 7) << 4)) >> 1;
    sum += bf2f(kt[sidx]);
  }
  __shared__ float red[4][64];
  red[sub][c] = sum;
  __syncthreads();
  if (sub == 0)
    kmp[(size_t)(bh * 8 + seg) * 64 + c] =
        red[0][c] + red[1][c] + red[2][c] + red[3][c];
}

__global__ __launch_bounds__(256) void pos_kernel(
    const unsigned short* __restrict__ Qh, const unsigned short* __restrict__ Ql,
    const float* __restrict__ kmp, float* __restrict__ pos) {
  __shared__ float kms[1024];
  int blk = blockIdx.x;
  int b = (blk * 4) >> 11;
  for (int i = threadIdx.x; i < 1024; i += 256) {
    int h = i >> 6, cc = i & 63;
    float s = 0.f;
#pragma unroll
    for (int seg = 0; seg < 8; ++seg)
      s += kmp[(size_t)((b * 16 + h) * 8 + seg) * 64 + cc];
    kms[i] = s * (1.0f / 2048.0f) * (1.0f / LOG2E);
  }
  __syncthreads();
  int w = threadIdx.x >> 6, lane = threadIdx.x & 63;
  int row = blk * 4 + w;
  int t = row & 2047;
  float p = 0.f;
#pragma unroll
  for (int h = 0; h < 16; ++h) {
    size_t idx = ((size_t)(b * 16 + h) * 2048 + t) * 64 + lane;
    p = fmaf(bf2f(Qh[idx]) + bf2f(Ql[idx]), kms[h * 64 + lane], p);
  }
#pragma unroll
  for (int off = 32; off; off >>= 1) p += __shfl_xor(p, off, 64);
  if (lane == 0) pos[row] = p;
}

__global__ __launch_bounds__(1024) void aw_kernel(const float* __restrict__ pos,
                                                  float* __restrict__ aw) {
  int b = blockIdx.x, tid = threadIdx.x;
  float p0 = pos[b * 2048 + tid], p1 = pos[b * 2048 + 1024 + tid];
  float mn = fminf(p0, p1), mx = fmaxf(p0, p1);
#pragma unroll
  for (int off = 32; off; off >>= 1) {
    mn = fminf(mn, __shfl_xor(mn, off, 64));
    mx = fmaxf(mx, __shfl_xor(mx, off, 64));
  }
  __shared__ float smn[16], smx[16];
  int wave = tid >> 6, lane = tid & 63;
  if (lane == 0) { smn[wave] = mn; smx[wave] = mx; }
  __syncthreads();
  if (tid < 64) {
    mn = (lane < 16) ? smn[lane] : 3.0e38f;
    mx = (lane < 16) ? smx[lane] : -3.0e38f;
#pragma unroll
    for (int off = 8; off; off >>= 1) {
      mn = fminf(mn, __shfl_xor(mn, off, 64));
      mx = fmaxf(mx, __shfl_xor(mx, off, 64));
    }
    if (lane == 0) { smn[0] = mn; smx[0] = mx; }
  }
  __syncthreads();
  float MN = smn[0], inv = 1.0f / (smx[0] - MN + 1e-6f);
  aw[b * 2048 + tid] = (p0 - MN) * inv;
  aw[b * 2048 + 1024 + tid] = (p1 - MN) * inv;
}

// ---------------------------------------------------------------------------
// Workspace layout (peak ~71.4 MB; no fp32 qkv buffer anymore):
//  [0,16M)        xh/xl   live conv..gemm_qkv;  then A2h/A2l (attn..gemm_proj)
//  [16M,28.6M)    Wqh/Wql live conv..gemm_qkv
//  [32M,64M)      Qh|Ql|Ktg|Vtg  written by gemm_qkv_fused, live ..attn
//  [64M,68M)      Wph/Wpl
//  [68M,...)      kmp/pos/aw
// ---------------------------------------------------------------------------
extern "C" void kernel_launch(void* const* d_in, const int* in_sizes, int n_in,
                              void* d_out, int out_size, void* d_ws, size_t ws_size,
                              hipStream_t stream) {
  const float* x      = (const float*)d_in[0];
  const float* W_qkv  = (const float*)d_in[1];
  const float* b_qkv  = (const float*)d_in[2];
  const float* W_proj = (const float*)d_in[3];
  const float* b_proj = (const float*)d_in[4];
  float* out = (float*)d_out;

  char* wsb = (char*)d_ws;
  unsigned short* xh  = (unsigned short*)wsb;                // [0,16M)
  unsigned short* xl  = xh + 4194304;
  unsigned short* A2h = (unsigned short*)wsb;                // reuse after gemm_qkv
  unsigned short* A2l = A2h + 4194304;
  unsigned short* Wqh = (unsigned short*)(wsb + 16777216);   // [16M,28.6M)
  unsigned short* Wql = Wqh + 3145728;
  unsigned short* Qh  = (unsigned short*)(wsb + 33554432);   // [32M,64M)
  unsigned short* Ql  = Qh + 4194304;
  unsigned short* Ktg = Ql + 4194304;
  unsigned short* Vtg = Ktg + 4194304;
  unsigned short* Wph = (unsigned short*)(wsb + 67108864);   // [64M,68M)
  unsigned short* Wpl = Wph + 1048576;
  float* kmp = (float*)(wsb + 71303168);                     // [68M,...)
  float* pos = kmp + 16384;
  float* aw  = pos + 4096;

  // 1) operand prep
  conv_split<<<2048, 256, 0, stream>>>(x, xh, xl);
  conv_split_T<<<dim3(96, 32), 256, 0, stream>>>(W_qkv, Wqh, Wql, 1024, 3072);
  conv_split_T<<<dim3(32, 32), 256, 0, stream>>>(W_proj, Wph, Wpl, 1024, 1024);
  // 2) qkv GEMM with fused image epilogue (no fp32 qkv, no convert kernel)
  gemm_qkv_fused<<<dim3(24, 32), 256, 0, stream>>>(xh, xl, Wqh, Wql, b_qkv,
                                                   Qh, Ql, Ktg, Vtg);
  // 3) k_mean partials / pos / aw
  kmean_part<<<dim3(32, 8), 256, 0, stream>>>(Ktg, kmp);
  pos_kernel<<<1024, 256, 0, stream>>>(Qh, Ql, kmp, pos);
  aw_kernel<<<2, 1024, 0, stream>>>(pos, aw);
  // 4) MFMA flash attention (swapped QK^T), fused aw-scale + split epilogue
  attn_mfma<<<dim3(32, 32), 256, 0, stream>>>(Qh, Ql, Ktg, Vtg, aw, A2h, A2l);
  // 5) out = A2 @ W_proj + b (split-bf16 MFMA)
  gemm_mfma_split<<<dim3(8, 32), 256, 0, stream>>>(A2h, A2l, Wph, Wpl, b_proj,
                                                   out, 4096, 1024, 1024);
}

// Round 8
// 278.601 us; speedup vs baseline: 7.3394x; 1.0576x over previous
//
#include <hip/hip_runtime.h>
#include <hip/hip_bf16.h>

// Problem constants: B=2, T=2048, W=1024, H=16, C=64
// scale^2 = 1/8 folded into Q along with log2(e) (exp2-domain softmax).

#define LOG2E 1.4426950408889634f

typedef float f32x4 __attribute__((ext_vector_type(4)));
typedef short bf16x8 __attribute__((ext_vector_type(8)));

__device__ __forceinline__ unsigned short f2bf(float f) {
  union { float f; unsigned int u; } v; v.f = f;
  unsigned int r = v.u + 0x7fffu + ((v.u >> 16) & 1u);
  return (unsigned short)(r >> 16);
}
__device__ __forceinline__ float bf2f(unsigned short h) {
  union { unsigned int u; float f; } v; v.u = ((unsigned int)h) << 16;
  return v.f;
}
// HW packed f32x2 -> bf16x2 (RNE). a -> low short, b -> high short.
__device__ __forceinline__ unsigned int pk_bf16(float a, float b) {
  unsigned int r;
  asm("v_cvt_pk_bf16_f32 %0, %1, %2" : "=v"(r) : "v"(a), "v"(b));
  return r;
}

// ---------------------------------------------------------------------------
// Fused operand prep: one kernel, 3 block ranges.
//  [0,2048)    : x fp32 -> xh/xl split (8 floats/thread)
//  [2048,5120) : W_qkv [1024][3072] -> Wqh/Wql [3072][1024] transposed split
//  [5120,6144) : W_proj [1024][1024] -> Wph/Wpl transposed split
// ---------------------------------------------------------------------------
__device__ __forceinline__ void conv_T_tile(
    const float* __restrict__ in, unsigned short* __restrict__ hi,
    unsigned short* __restrict__ lo, int K, int N, int bx, int by,
    float (*t)[33], int tid) {
  const int n0 = bx * 32, k0 = by * 32;
  const int r = tid >> 3, c4 = (tid & 7) * 4;
  float4 v = *(const float4*)&in[(size_t)(k0 + r) * N + n0 + c4];
  t[r][c4 + 0] = v.x; t[r][c4 + 1] = v.y; t[r][c4 + 2] = v.z; t[r][c4 + 3] = v.w;
  __syncthreads();
  unsigned int hw[2], lw[2];
#pragma unroll
  for (int p = 0; p < 2; ++p) {
    float a = t[c4 + 2 * p][r], b = t[c4 + 2 * p + 1][r];
    unsigned int h2 = pk_bf16(a, b);
    float h0 = bf2f((unsigned short)h2), h1 = bf2f((unsigned short)(h2 >> 16));
    hw[p] = h2;
    lw[p] = pk_bf16(a - h0, b - h1);
  }
  size_t o = (size_t)(n0 + r) * K + k0 + c4;
  *(uint2*)&hi[o] = make_uint2(hw[0], hw[1]);
  *(uint2*)&lo[o] = make_uint2(lw[0], lw[1]);
}

__global__ __launch_bounds__(256) void conv_all(
    const float* __restrict__ x, unsigned short* __restrict__ xh,
    unsigned short* __restrict__ xl,
    const float* __restrict__ Wq, unsigned short* __restrict__ Wqh,
    unsigned short* __restrict__ Wql,
    const float* __restrict__ Wp, unsigned short* __restrict__ Wph,
    unsigned short* __restrict__ Wpl) {
  __shared__ float t[32][33];
  const int i = blockIdx.x, tid = threadIdx.x;
  if (i < 2048) {
    size_t base = ((size_t)i * 256 + tid) * 8;
    float4 v0 = *(const float4*)&x[base];
    float4 v1 = *(const float4*)&x[base + 4];
    float f[8] = {v0.x, v0.y, v0.z, v0.w, v1.x, v1.y, v1.z, v1.w};
    unsigned int hw[4], lw[4];
#pragma unroll
    for (int p = 0; p < 4; ++p) {
      float a = f[2 * p], b = f[2 * p + 1];
      unsigned int h2 = pk_bf16(a, b);
      float h0 = bf2f((unsigned short)h2), h1 = bf2f((unsigned short)(h2 >> 16));
      hw[p] = h2;
      lw[p] = pk_bf16(a - h0, b - h1);
    }
    uint4 H = {hw[0], hw[1], hw[2], hw[3]};
    uint4 L = {lw[0], lw[1], lw[2], lw[3]};
    *(uint4*)&xh[base] = H;
    *(uint4*)&xl[base] = L;
  } else if (i < 5120) {
    int j = i - 2048;
    conv_T_tile(Wq, Wqh, Wql, 1024, 3072, j % 96, j / 96, t, tid);
  } else {
    int j = i - 5120;
    conv_T_tile(Wp, Wph, Wpl, 1024, 1024, j % 32, j / 32, t, tid);
  }
}

// ---------------------------------------------------------------------------
// Split-bf16 MFMA GEMM (round-3, verified): C = (Ah+Al)@(Bh+Bl)^T + bias.
// Used for the proj GEMM.
// ---------------------------------------------------------------------------
__global__ __launch_bounds__(256, 2) void gemm_mfma_split(
    const unsigned short* __restrict__ Ah, const unsigned short* __restrict__ Al,
    const unsigned short* __restrict__ Bh, const unsigned short* __restrict__ Bl,
    const float* __restrict__ bias, float* __restrict__ C,
    int M, int N, int K) {
  __shared__ __align__(16) unsigned short lds[2][16384];

  const int tid = threadIdx.x;
  const int w = tid >> 6, l = tid & 63;
  const int lc = l & 15, lr = l >> 4;
  const int wr = w >> 1, wc = w & 1;
  const int m0 = blockIdx.y * 128, n0 = blockIdx.x * 128;

  f32x4 acc[4][4];
#pragma unroll
  for (int mi = 0; mi < 4; ++mi)
#pragma unroll
    for (int ni = 0; ni < 4; ++ni) acc[mi][ni] = (f32x4){0.f, 0.f, 0.f, 0.f};

  const unsigned short* src = (w == 0) ? Ah : (w == 1) ? Al : (w == 2) ? Bh : Bl;
  const int rowbase = (w < 2) ? m0 : n0;
  const int lrow = l >> 2, lkk = (l & 3) * 8;

  const int NT = K / 32;
  int buf = 0;

#define STAGE(B_, KT_)                                                         \
  {                                                                            \
    unsigned short* dst = lds[B_] + w * 4096;                                  \
    _Pragma("unroll") for (int c = 0; c < 8; ++c) {                            \
      const unsigned short* g =                                                \
          src + (size_t)(rowbase + c * 16 + lrow) * K + (KT_) + lkk;           \
      __builtin_amdgcn_global_load_lds(                                        \
          (const __attribute__((address_space(1))) unsigned int*)g,            \
          (__attribute__((address_space(3))) unsigned int*)(dst + c * 512),    \
          16, 0, 0);                                                           \
    }                                                                          \
  }

  STAGE(0, 0);
  asm volatile("s_waitcnt vmcnt(0)");
  __syncthreads();

  for (int t = 0; t < NT; ++t) {
    if (t + 1 < NT) STAGE(buf ^ 1, (t + 1) * 32);

    const unsigned short* bp = lds[buf];
    bf16x8 ah[4], al[4], bh[4], bl[4];
#pragma unroll
    for (int mi = 0; mi < 4; ++mi) {
      int ro = (wr * 64 + mi * 16 + lc) * 32 + lr * 8;
      ah[mi] = *(const bf16x8*)&bp[ro];
      al[mi] = *(const bf16x8*)&bp[4096 + ro];
    }
#pragma unroll
    for (int ni = 0; ni < 4; ++ni) {
      int co = (wc * 64 + ni * 16 + lc) * 32 + lr * 8;
      bh[ni] = *(const bf16x8*)&bp[8192 + co];
      bl[ni] = *(const bf16x8*)&bp[12288 + co];
    }

    __builtin_amdgcn_s_setprio(1);
#pragma unroll
    for (int mi = 0; mi < 4; ++mi)
#pragma unroll
      for (int ni = 0; ni < 4; ++ni) {
        acc[mi][ni] = __builtin_amdgcn_mfma_f32_16x16x32_bf16(ah[mi], bh[ni], acc[mi][ni], 0, 0, 0);
        acc[mi][ni] = __builtin_amdgcn_mfma_f32_16x16x32_bf16(ah[mi], bl[ni], acc[mi][ni], 0, 0, 0);
        acc[mi][ni] = __builtin_amdgcn_mfma_f32_16x16x32_bf16(al[mi], bh[ni], acc[mi][ni], 0, 0, 0);
      }
    __builtin_amdgcn_s_setprio(0);

    __syncthreads();
    buf ^= 1;
  }
#undef STAGE

#pragma unroll
  for (int mi = 0; mi < 4; ++mi)
#pragma unroll
    for (int r = 0; r < 4; ++r) {
      int row = m0 + wr * 64 + mi * 16 + lr * 4 + r;
#pragma unroll
      for (int ni = 0; ni < 4; ++ni) {
        int col = n0 + wc * 64 + ni * 16 + lc;
        C[(size_t)row * N + col] = acc[mi][ni][r] + bias[col];
      }
    }
}

// ---------------------------------------------------------------------------
// qkv GEMM with FUSED image epilogue (round-7, verified structure).
// Round-8: cvt_pk pair-conversions; V stores packed as u32.
// ---------------------------------------------------------------------------
__global__ __launch_bounds__(256, 2) void gemm_qkv_fused(
    const unsigned short* __restrict__ Ah, const unsigned short* __restrict__ Al,
    const unsigned short* __restrict__ Bh, const unsigned short* __restrict__ Bl,
    const float* __restrict__ bias,
    unsigned short* __restrict__ Qh, unsigned short* __restrict__ Ql,
    unsigned short* __restrict__ Ktg, unsigned short* __restrict__ Vtg) {
  const int K = 1024;
  __shared__ __align__(16) unsigned short lds[2][16384];

  const int tid = threadIdx.x;
  const int w = tid >> 6, l = tid & 63;
  const int lc = l & 15, lr = l >> 4;
  const int wr = w >> 1, wc = w & 1;
  const int m0 = blockIdx.y * 128, n0 = blockIdx.x * 128;

  f32x4 acc[4][4];
#pragma unroll
  for (int mi = 0; mi < 4; ++mi)
#pragma unroll
    for (int ni = 0; ni < 4; ++ni) acc[mi][ni] = (f32x4){0.f, 0.f, 0.f, 0.f};

  const unsigned short* src = (w == 0) ? Ah : (w == 1) ? Al : (w == 2) ? Bh : Bl;
  const int rowbase = (w < 2) ? m0 : n0;
  const int lrow = l >> 2, lkk = (l & 3) * 8;

  const int NT = K / 32;
  int buf = 0;

#define STAGEQ(B_, KT_)                                                        \
  {                                                                            \
    unsigned short* dst = lds[B_] + w * 4096;                                  \
    _Pragma("unroll") for (int c = 0; c < 8; ++c) {                            \
      const unsigned short* g =                                                \
          src + (size_t)(rowbase + c * 16 + lrow) * K + (KT_) + lkk;           \
      __builtin_amdgcn_global_load_lds(                                        \
          (const __attribute__((address_space(1))) unsigned int*)g,            \
          (__attribute__((address_space(3))) unsigned int*)(dst + c * 512),    \
          16, 0, 0);                                                           \
    }                                                                          \
  }

  STAGEQ(0, 0);
  asm volatile("s_waitcnt vmcnt(0)");
  __syncthreads();

  for (int t = 0; t < NT; ++t) {
    if (t + 1 < NT) STAGEQ(buf ^ 1, (t + 1) * 32);

    const unsigned short* bp = lds[buf];
    bf16x8 ah[4], al[4], bh[4], bl[4];
#pragma unroll
    for (int mi = 0; mi < 4; ++mi) {
      int ro = (wr * 64 + mi * 16 + lc) * 32 + lr * 8;
      ah[mi] = *(const bf16x8*)&bp[ro];
      al[mi] = *(const bf16x8*)&bp[4096 + ro];
    }
#pragma unroll
    for (int ni = 0; ni < 4; ++ni) {
      int co = (wc * 64 + ni * 16 + lc) * 32 + lr * 8;
      bh[ni] = *(const bf16x8*)&bp[8192 + co];
      bl[ni] = *(const bf16x8*)&bp[12288 + co];
    }

    __builtin_amdgcn_s_setprio(1);
#pragma unroll
    for (int mi = 0; mi < 4; ++mi)
#pragma unroll
      for (int ni = 0; ni < 4; ++ni) {
        acc[mi][ni] = __builtin_amdgcn_mfma_f32_16x16x32_bf16(ah[mi], bh[ni], acc[mi][ni], 0, 0, 0);
        acc[mi][ni] = __builtin_amdgcn_mfma_f32_16x16x32_bf16(ah[mi], bl[ni], acc[mi][ni], 0, 0, 0);
        acc[mi][ni] = __builtin_amdgcn_mfma_f32_16x16x32_bf16(al[mi], bh[ni], acc[mi][ni], 0, 0, 0);
      }
    __builtin_amdgcn_s_setprio(0);

    __syncthreads();
    buf ^= 1;
  }
#undef STAGEQ

  // fused epilogue (role uniform across the 16-lane col span)
  const float QS = 0.125f * LOG2E;
#pragma unroll
  for (int ni = 0; ni < 4; ++ni) {
    int col = n0 + wc * 64 + ni * 16 + lc;   // 0..3071
    int h = col / 192;
    int rr = col - h * 192;
    float bs = bias[col];
    if (rr < 64) {  // Q: scaled hi/lo split, row-major [bh][t][c]
      int c = rr;
#pragma unroll
      for (int mi = 0; mi < 4; ++mi)
#pragma unroll
        for (int rp = 0; rp < 2; ++rp) {
          int row = m0 + wr * 64 + mi * 16 + lr * 4 + rp * 2;
          int bb = row >> 11, tl = row & 2047;
          float v0 = (acc[mi][ni][rp * 2] + bs) * QS;
          float v1 = (acc[mi][ni][rp * 2 + 1] + bs) * QS;
          unsigned int hw = pk_bf16(v0, v1);
          float h0 = bf2f((unsigned short)hw), h1 = bf2f((unsigned short)(hw >> 16));
          unsigned int lw = pk_bf16(v0 - h0, v1 - h1);
          size_t off = ((size_t)(bb * 16 + h) * 2048 + tl) * 64 + c;
          Qh[off] = (unsigned short)hw;
          Qh[off + 64] = (unsigned short)(hw >> 16);
          Ql[off] = (unsigned short)lw;
          Ql[off + 64] = (unsigned short)(lw >> 16);
        }
    } else if (rr < 128) {  // K: swizzled tile image [bh*32+st][s][c]
      int c2 = (rr - 64) * 2;
#pragma unroll
      for (int mi = 0; mi < 4; ++mi)
#pragma unroll
        for (int rp = 0; rp < 2; ++rp) {
          int row = m0 + wr * 64 + mi * 16 + lr * 4 + rp * 2;
          int bb = row >> 11, tl = row & 2047;
          int s = tl & 63;  // even
          size_t base = (size_t)((bb * 16 + h) * 32 + (tl >> 6)) * 4096;
          unsigned int hw = pk_bf16(acc[mi][ni][rp * 2] + bs,
                                    acc[mi][ni][rp * 2 + 1] + bs);
          Ktg[base + (((s * 128 + c2) ^ ((s & 7) << 4)) >> 1)] =
              (unsigned short)hw;
          Ktg[base + ((((s + 1) * 128 + c2) ^ (((s + 1) & 7) << 4)) >> 1)] =
              (unsigned short)(hw >> 16);
        }
    } else {  // V: transposed swizzled image [bh*32+st][c][s], paired u32
      int cb = (rr - 128) * 128, csw = ((rr - 128) & 7) << 4;
#pragma unroll
      for (int mi = 0; mi < 4; ++mi)
#pragma unroll
        for (int rp = 0; rp < 2; ++rp) {
          int row = m0 + wr * 64 + mi * 16 + lr * 4 + rp * 2;
          int bb = row >> 11, tl = row & 2047;
          int s = tl & 63;  // even -> 4B-aligned store
          size_t base = (size_t)((bb * 16 + h) * 32 + (tl >> 6)) * 4096;
          unsigned int pv = pk_bf16(acc[mi][ni][rp * 2] + bs,
                                    acc[mi][ni][rp * 2 + 1] + bs);
          *(unsigned int*)&Vtg[base + (((cb + s * 2) ^ csw) >> 1)] = pv;
        }
    }
  }
}

// ---------------------------------------------------------------------------
// MFMA flash attention, round-8:
//  - kvt loop unrolled x2 -> compile-time LDS buffer bases (addr folding)
//  - inline-asm v_cvt_pk_bf16_f32 for P packing
//  Rest as round-7 (swapped QK^T, defer-max THR=8, b64 P stores, dbuf
//  staging, fused aw-scale + split epilogue).
// ---------------------------------------------------------------------------
__global__ __launch_bounds__(256, 4) void attn_mfma(
    const unsigned short* __restrict__ Qh, const unsigned short* __restrict__ Ql,
    const unsigned short* __restrict__ Ktg, const unsigned short* __restrict__ Vtg,
    const float* __restrict__ aw,
    unsigned short* __restrict__ A2h, unsigned short* __restrict__ A2l) {
  const int qt = blockIdx.x, bh = blockIdx.y;
  const int b = bh >> 4, h = bh & 15;
  const int tid = threadIdx.x;
  const int w = tid >> 6, l = tid & 63;
  const int lc = l & 15, lr = l >> 4;

  __shared__ __align__(16) unsigned short ldsKV[2][8192];  // [K 4096 | V 4096]
  __shared__ __align__(16) unsigned short ldsP[4096];
  unsigned short* Pl = ldsP + w * 1024;        // [16 q][64 k], XOR-swizzled
  uint2* Pl2 = (uint2*)Pl;

  const int q0 = qt * 64 + w * 16;
  bf16x8 qh0, qh1, ql0, ql1;
  {
    size_t base = ((size_t)bh * 2048 + q0 + lc) * 64 + lr * 8;
    qh0 = *(const bf16x8*)&Qh[base];
    qh1 = *(const bf16x8*)&Qh[base + 32];
    ql0 = *(const bf16x8*)&Ql[base];
    ql1 = *(const bf16x8*)&Ql[base + 32];
  }

  int kidx0[4], kidx1[4];
#pragma unroll
  for (int st = 0; st < 4; ++st) {
    int row = st * 16 + lc;
    int sw = (row & 7) << 4;
    kidx0[st] = ((row * 128 + lr * 16) ^ sw) >> 1;
    kidx1[st] = ((row * 128 + 64 + lr * 16) ^ sw) >> 1;
  }
  int pwd[4];
  {
    int sw = (lc & 7) << 4;
#pragma unroll
    for (int st = 0; st < 4; ++st)
      pwd[st] = ((lc * 128 + st * 32 + lr * 8) ^ sw) >> 3;
  }

  f32x4 o[4];
  float m = -1e30f, lsum = 0.f;
#pragma unroll
  for (int ct = 0; ct < 4; ++ct) o[ct] = (f32x4){0.f, 0.f, 0.f, 0.f};

  const unsigned short* gsrc =
      ((w < 2) ? Ktg : Vtg) + (size_t)bh * 32 * 4096 + (w & 1) * 2048 + l * 8;
  unsigned short* ldst0 = &ldsKV[0][(w >> 1) * 4096 + (w & 1) * 2048];
  unsigned short* ldst1 = &ldsKV[1][(w >> 1) * 4096 + (w & 1) * 2048];

#define STAGE_KV(DST_, T_)                                                     \
  {                                                                            \
    const unsigned short* g = gsrc + (size_t)(T_) * 4096;                      \
    _Pragma("unroll") for (int i = 0; i < 4; ++i) {                            \
      __builtin_amdgcn_global_load_lds(                                        \
          (const __attribute__((address_space(1))) unsigned int*)(g + i * 512),\
          (__attribute__((address_space(3))) unsigned int*)((DST_) + i * 512), \
          16, 0, 0);                                                           \
    }                                                                          \
  }

  STAGE_KV(ldst0, 0);
  asm volatile("s_waitcnt vmcnt(0)");
  __syncthreads();

  for (int kvt = 0; kvt < 32; kvt += 2) {
#pragma unroll
    for (int hf = 0; hf < 2; ++hf) {
      const int t2 = kvt + hf;
      if (t2 + 1 < 32) STAGE_KV(hf ? ldst0 : ldst1, t2 + 1);

      const unsigned short* KT = &ldsKV[hf][0];     // compile-time base
      const unsigned short* VT = &ldsKV[hf][4096];

      // swapped QK^T: sacc[st] = S^T[k=st*16+lr*4+r][q=lc]
      f32x4 sacc[4];
      __builtin_amdgcn_s_setprio(1);
#pragma unroll
      for (int st = 0; st < 4; ++st) {
        bf16x8 k0 = *(const bf16x8*)&KT[kidx0[st]];
        bf16x8 k1 = *(const bf16x8*)&KT[kidx1[st]];
        f32x4 acc = (f32x4){0.f, 0.f, 0.f, 0.f};
        acc = __builtin_amdgcn_mfma_f32_16x16x32_bf16(k0, qh0, acc, 0, 0, 0);
        acc = __builtin_amdgcn_mfma_f32_16x16x32_bf16(k1, qh1, acc, 0, 0, 0);
        acc = __builtin_amdgcn_mfma_f32_16x16x32_bf16(k0, ql0, acc, 0, 0, 0);
        acc = __builtin_amdgcn_mfma_f32_16x16x32_bf16(k1, ql1, acc, 0, 0, 0);
        sacc[st] = acc;
      }
      __builtin_amdgcn_s_setprio(0);

      // defer-max (THR=8): P bounded by 2^8, harmless for fp32 lsum/bf16 P
      float pmax = fmaxf(fmaxf(fmaxf(sacc[0][0], sacc[0][1]), fmaxf(sacc[0][2], sacc[0][3])),
                         fmaxf(fmaxf(sacc[1][0], sacc[1][1]), fmaxf(sacc[1][2], sacc[1][3])));
      pmax = fmaxf(pmax,
             fmaxf(fmaxf(fmaxf(sacc[2][0], sacc[2][1]), fmaxf(sacc[2][2], sacc[2][3])),
                   fmaxf(fmaxf(sacc[3][0], sacc[3][1]), fmaxf(sacc[3][2], sacc[3][3]))));
      if (__any(pmax > m + 8.0f)) {
        float pm = fmaxf(pmax, __shfl_xor(pmax, 16));
        pm = fmaxf(pm, __shfl_xor(pm, 32));
        float mn = fmaxf(m, pm);
        float corr = exp2f(m - mn);
        m = mn;
        lsum *= corr;
#pragma unroll
        for (int r = 0; r < 4; ++r) {
          float cq = __shfl(corr, lr * 4 + r);
          o[0][r] *= cq; o[1][r] *= cq; o[2][r] *= cq; o[3][r] *= cq;
        }
      }

      // exp2 + per-lane row partial sum
#pragma unroll
      for (int st = 0; st < 4; ++st)
#pragma unroll
        for (int r = 0; r < 4; ++r)
          sacc[st][r] = exp2f(sacc[st][r] - m);
#pragma unroll
      for (int st = 0; st < 4; ++st)
        lsum += (sacc[st][0] + sacc[st][1]) + (sacc[st][2] + sacc[st][3]);

      // HW cvt_pk + one b64 store per st
#pragma unroll
      for (int st = 0; st < 4; ++st) {
        uint2 pv;
        pv.x = pk_bf16(sacc[st][0], sacc[st][1]);
        pv.y = pk_bf16(sacc[st][2], sacc[st][3]);
        Pl2[pwd[st]] = pv;
      }

      bf16x8 pa0 = *(const bf16x8*)&Pl[kidx0[0]];
      bf16x8 pa1 = *(const bf16x8*)&Pl[kidx1[0]];

      // PV: O += P @ V
      __builtin_amdgcn_s_setprio(1);
#pragma unroll
      for (int ct = 0; ct < 4; ++ct) {
        bf16x8 v0 = *(const bf16x8*)&VT[kidx0[ct]];
        bf16x8 v1 = *(const bf16x8*)&VT[kidx1[ct]];
        o[ct] = __builtin_amdgcn_mfma_f32_16x16x32_bf16(pa0, v0, o[ct], 0, 0, 0);
        o[ct] = __builtin_amdgcn_mfma_f32_16x16x32_bf16(pa1, v1, o[ct], 0, 0, 0);
      }
      __builtin_amdgcn_s_setprio(0);
      __syncthreads();
    }
  }
#undef STAGE_KV

  // row sum for q=lc, then move to q=lr*4+r for the epilogue
  lsum += __shfl_xor(lsum, 16);
  lsum += __shfl_xor(lsum, 32);
  float inv = 1.0f / lsum;
#pragma unroll
  for (int r = 0; r < 4; ++r) {
    int t = q0 + lr * 4 + r;
    float sc = aw[b * 2048 + t] * __shfl(inv, lr * 4 + r);
    size_t off = (size_t)(b * 2048 + t) * 1024 + h * 64 + lc;
#pragma unroll
    for (int ct = 0; ct < 4; ++ct) {
      float v = o[ct][r] * sc;
      unsigned short hh = f2bf(v);
      A2h[off + ct * 16] = hh;
      A2l[off + ct * 16] = f2bf(v - bf2f(hh));
    }
  }
}

// ---------------------------------------------------------------------------
// k_mean partials / pos / aw (round-5, verified)
// ---------------------------------------------------------------------------
__global__ __launch_bounds__(256) void kmean_part(
    const unsigned short* __restrict__ Ktg, float* __restrict__ kmp) {
  const int bh = blockIdx.x, seg = blockIdx.y;
  const int c = threadIdx.x & 63, sub = threadIdx.x >> 6;
  const int tile = seg * 4 + sub;
  const unsigned short* kt = Ktg + (size_t)(bh * 32 + tile) * 4096;
  float sum = 0.f;
#pragma unroll 8
  for (int s = 0; s < 64; ++s) {
    int sidx = ((s * 128 + c * 2) ^ ((s & 7) << 4)) >> 1;
    sum += bf2f(kt[sidx]);
  }
  __shared__ float red[4][64];
  red[sub][c] = sum;
  __syncthreads();
  if (sub == 0)
    kmp[(size_t)(bh * 8 + seg) * 64 + c] =
        red[0][c] + red[1][c] + red[2][c] + red[3][c];
}

__global__ __launch_bounds__(256) void pos_kernel(
    const unsigned short* __restrict__ Qh, const unsigned short* __restrict__ Ql,
    const float* __restrict__ kmp, float* __restrict__ pos) {
  __shared__ float kms[1024];
  int blk = blockIdx.x;
  int b = (blk * 4) >> 11;
  for (int i = threadIdx.x; i < 1024; i += 256) {
    int h = i >> 6, cc = i & 63;
    float s = 0.f;
#pragma unroll
    for (int seg = 0; seg < 8; ++seg)
      s += kmp[(size_t)((b * 16 + h) * 8 + seg) * 64 + cc];
    kms[i] = s * (1.0f / 2048.0f) * (1.0f / LOG2E);
  }
  __syncthreads();
  int w = threadIdx.x >> 6, lane = threadIdx.x & 63;
  int row = blk * 4 + w;
  int t = row & 2047;
  float p = 0.f;
#pragma unroll
  for (int h = 0; h < 16; ++h) {
    size_t idx = ((size_t)(b * 16 + h) * 2048 + t) * 64 + lane;
    p = fmaf(bf2f(Qh[idx]) + bf2f(Ql[idx]), kms[h * 64 + lane], p);
  }
#pragma unroll
  for (int off = 32; off; off >>= 1) p += __shfl_xor(p, off, 64);
  if (lane == 0) pos[row] = p;
}

__global__ __launch_bounds__(1024) void aw_kernel(const float* __restrict__ pos,
                                                  float* __restrict__ aw) {
  int b = blockIdx.x, tid = threadIdx.x;
  float p0 = pos[b * 2048 + tid], p1 = pos[b * 2048 + 1024 + tid];
  float mn = fminf(p0, p1), mx = fmaxf(p0, p1);
#pragma unroll
  for (int off = 32; off; off >>= 1) {
    mn = fminf(mn, __shfl_xor(mn, off, 64));
    mx = fmaxf(mx, __shfl_xor(mx, off, 64));
  }
  __shared__ float smn[16], smx[16];
  int wave = tid >> 6, lane = tid & 63;
  if (lane == 0) { smn[wave] = mn; smx[wave] = mx; }
  __syncthreads();
  if (tid < 64) {
    mn = (lane < 16) ? smn[lane] : 3.0e38f;
    mx = (lane < 16) ? smx[lane] : -3.0e38f;
#pragma unroll
    for (int off = 8; off; off >>= 1) {
      mn = fminf(mn, __shfl_xor(mn, off, 64));
      mx = fmaxf(mx, __shfl_xor(mx, off, 64));
    }
    if (lane == 0) { smn[0] = mn; smx[0] = mx; }
  }
  __syncthreads();
  float MN = smn[0], inv = 1.0f / (smx[0] - MN + 1e-6f);
  aw[b * 2048 + tid] = (p0 - MN) * inv;
  aw[b * 2048 + 1024 + tid] = (p1 - MN) * inv;
}

// ---------------------------------------------------------------------------
// Workspace layout (round-7, verified; peak ~71.4 MB):
//  [0,16M)        xh/xl   live conv..gemm_qkv;  then A2h/A2l (attn..gemm_proj)
//  [16M,28.6M)    Wqh/Wql live conv..gemm_qkv
//  [32M,64M)      Qh|Ql|Ktg|Vtg  written by gemm_qkv_fused, live ..attn
//  [64M,68M)      Wph/Wpl
//  [68M,...)      kmp/pos/aw
// ---------------------------------------------------------------------------
extern "C" void kernel_launch(void* const* d_in, const int* in_sizes, int n_in,
                              void* d_out, int out_size, void* d_ws, size_t ws_size,
                              hipStream_t stream) {
  const float* x      = (const float*)d_in[0];
  const float* W_qkv  = (const float*)d_in[1];
  const float* b_qkv  = (const float*)d_in[2];
  const float* W_proj = (const float*)d_in[3];
  const float* b_proj = (const float*)d_in[4];
  float* out = (float*)d_out;

  char* wsb = (char*)d_ws;
  unsigned short* xh  = (unsigned short*)wsb;                // [0,16M)
  unsigned short* xl  = xh + 4194304;
  unsigned short* A2h = (unsigned short*)wsb;                // reuse after gemm_qkv
  unsigned short* A2l = A2h + 4194304;
  unsigned short* Wqh = (unsigned short*)(wsb + 16777216);   // [16M,28.6M)
  unsigned short* Wql = Wqh + 3145728;
  unsigned short* Qh  = (unsigned short*)(wsb + 33554432);   // [32M,64M)
  unsigned short* Ql  = Qh + 4194304;
  unsigned short* Ktg = Ql + 4194304;
  unsigned short* Vtg = Ktg + 4194304;
  unsigned short* Wph = (unsigned short*)(wsb + 67108864);   // [64M,68M)
  unsigned short* Wpl = Wph + 1048576;
  float* kmp = (float*)(wsb + 71303168);                     // [68M,...)
  float* pos = kmp + 16384;
  float* aw  = pos + 4096;

  // 1) fused operand prep (x split + both weight transposes)
  conv_all<<<6144, 256, 0, stream>>>(x, xh, xl, W_qkv, Wqh, Wql,
                                     W_proj, Wph, Wpl);
  // 2) qkv GEMM with fused image epilogue
  gemm_qkv_fused<<<dim3(24, 32), 256, 0, stream>>>(xh, xl, Wqh, Wql, b_qkv,
                                                   Qh, Ql, Ktg, Vtg);
  // 3) k_mean partials / pos / aw
  kmean_part<<<dim3(32, 8), 256, 0, stream>>>(Ktg, kmp);
  pos_kernel<<<1024, 256, 0, stream>>>(Qh, Ql, kmp, pos);
  aw_kernel<<<2, 1024, 0, stream>>>(pos, aw);
  // 4) MFMA flash attention (swapped QK^T), fused aw-scale + split epilogue
  attn_mfma<<<dim3(32, 32), 256, 0, stream>>>(Qh, Ql, Ktg, Vtg, aw, A2h, A2l);
  // 5) out = A2 @ W_proj + b (split-bf16 MFMA)
  gemm_mfma_split<<<dim3(8, 32), 256, 0, stream>>>(A2h, A2l, Wph, Wpl, b_proj,
                                                   out, 4096, 1024, 1024);
}

// Round 10
// 266.752 us; speedup vs baseline: 7.6654x; 1.0444x over previous
//
#include <hip/hip_runtime.h>
#include <hip/hip_bf16.h>

// Problem constants: B=2, T=2048, W=1024, H=16, C=64
// scale^2 = 1/8 folded into Q along with log2(e) (exp2-domain softmax).

#define LOG2E 1.4426950408889634f

typedef float f32x4 __attribute__((ext_vector_type(4)));
typedef short bf16x8 __attribute__((ext_vector_type(8)));

__device__ __forceinline__ unsigned short f2bf(float f) {
  union { float f; unsigned int u; } v; v.f = f;
  unsigned int r = v.u + 0x7fffu + ((v.u >> 16) & 1u);
  return (unsigned short)(r >> 16);
}
__device__ __forceinline__ float bf2f(unsigned short h) {
  union { unsigned int u; float f; } v; v.u = ((unsigned int)h) << 16;
  return v.f;
}
// HW packed f32x2 -> bf16x2 (RNE). a -> low short, b -> high short.
__device__ __forceinline__ unsigned int pk_bf16(float a, float b) {
  unsigned int r;
  asm("v_cvt_pk_bf16_f32 %0, %1, %2" : "=v"(r) : "v"(a), "v"(b));
  return r;
}

// ---------------------------------------------------------------------------
// Fused operand prep: one kernel, 3 block ranges.
//  [0,2048)    : x fp32 -> xh/xl split (8 floats/thread)
//  [2048,5120) : W_qkv [1024][3072] -> Wqh/Wql [3072][1024] transposed split
//  [5120,6144) : W_proj [1024][1024] -> Wph transposed (single bf16)
// ---------------------------------------------------------------------------
__device__ __forceinline__ void conv_T_tile(
    const float* __restrict__ in, unsigned short* __restrict__ hi,
    unsigned short* __restrict__ lo, int K, int N, int bx, int by,
    float (*t)[33], int tid) {
  const int n0 = bx * 32, k0 = by * 32;
  const int r = tid >> 3, c4 = (tid & 7) * 4;
  float4 v = *(const float4*)&in[(size_t)(k0 + r) * N + n0 + c4];
  t[r][c4 + 0] = v.x; t[r][c4 + 1] = v.y; t[r][c4 + 2] = v.z; t[r][c4 + 3] = v.w;
  __syncthreads();
  unsigned int hw[2], lw[2];
#pragma unroll
  for (int p = 0; p < 2; ++p) {
    float a = t[c4 + 2 * p][r], b = t[c4 + 2 * p + 1][r];
    unsigned int h2 = pk_bf16(a, b);
    float h0 = bf2f((unsigned short)h2), h1 = bf2f((unsigned short)(h2 >> 16));
    hw[p] = h2;
    lw[p] = pk_bf16(a - h0, b - h1);
  }
  size_t o = (size_t)(n0 + r) * K + k0 + c4;
  *(uint2*)&hi[o] = make_uint2(hw[0], hw[1]);
  *(uint2*)&lo[o] = make_uint2(lw[0], lw[1]);
}

__device__ __forceinline__ void conv_T_tile_hi(
    const float* __restrict__ in, unsigned short* __restrict__ hi,
    int K, int N, int bx, int by, float (*t)[33], int tid) {
  const int n0 = bx * 32, k0 = by * 32;
  const int r = tid >> 3, c4 = (tid & 7) * 4;
  float4 v = *(const float4*)&in[(size_t)(k0 + r) * N + n0 + c4];
  t[r][c4 + 0] = v.x; t[r][c4 + 1] = v.y; t[r][c4 + 2] = v.z; t[r][c4 + 3] = v.w;
  __syncthreads();
  unsigned int hw[2];
#pragma unroll
  for (int p = 0; p < 2; ++p)
    hw[p] = pk_bf16(t[c4 + 2 * p][r], t[c4 + 2 * p + 1][r]);
  size_t o = (size_t)(n0 + r) * K + k0 + c4;
  *(uint2*)&hi[o] = make_uint2(hw[0], hw[1]);
}

__global__ __launch_bounds__(256) void conv_all(
    const float* __restrict__ x, unsigned short* __restrict__ xh,
    unsigned short* __restrict__ xl,
    const float* __restrict__ Wq, unsigned short* __restrict__ Wqh,
    unsigned short* __restrict__ Wql,
    const float* __restrict__ Wp, unsigned short* __restrict__ Wph) {
  __shared__ float t[32][33];
  const int i = blockIdx.x, tid = threadIdx.x;
  if (i < 2048) {
    size_t base = ((size_t)i * 256 + tid) * 8;
    float4 v0 = *(const float4*)&x[base];
    float4 v1 = *(const float4*)&x[base + 4];
    float f[8] = {v0.x, v0.y, v0.z, v0.w, v1.x, v1.y, v1.z, v1.w};
    unsigned int hw[4], lw[4];
#pragma unroll
    for (int p = 0; p < 4; ++p) {
      float a = f[2 * p], b = f[2 * p + 1];
      unsigned int h2 = pk_bf16(a, b);
      float h0 = bf2f((unsigned short)h2), h1 = bf2f((unsigned short)(h2 >> 16));
      hw[p] = h2;
      lw[p] = pk_bf16(a - h0, b - h1);
    }
    uint4 H = {hw[0], hw[1], hw[2], hw[3]};
    uint4 L = {lw[0], lw[1], lw[2], lw[3]};
    *(uint4*)&xh[base] = H;
    *(uint4*)&xl[base] = L;
  } else if (i < 5120) {
    int j = i - 2048;
    conv_T_tile(Wq, Wqh, Wql, 1024, 3072, j % 96, j / 96, t, tid);
  } else {
    int j = i - 5120;
    conv_T_tile_hi(Wp, Wph, 1024, 1024, j % 32, j / 32, t, tid);
  }
}

// ---------------------------------------------------------------------------
// Single-bf16 MFMA GEMM for the proj: C = A @ B^T + bias.
// Tile 128x128, BK=32, 4 waves 2x2, double-buffered 32KB LDS.
// (A2/W_proj magnitudes make the lo-product negligible: ~3e-5 abs.)
// ---------------------------------------------------------------------------
__global__ __launch_bounds__(256, 2) void gemm_mfma_single(
    const unsigned short* __restrict__ Ah, const unsigned short* __restrict__ Bh,
    const float* __restrict__ bias, float* __restrict__ C,
    int M, int N, int K) {
  __shared__ __align__(16) unsigned short lds[2][8192];  // A 4096 | B 4096

  const int tid = threadIdx.x;
  const int w = tid >> 6, l = tid & 63;
  const int lc = l & 15, lr = l >> 4;
  const int wr = w >> 1, wc = w & 1;
  const int m0 = blockIdx.y * 128, n0 = blockIdx.x * 128;

  f32x4 acc[4][4];
#pragma unroll
  for (int mi = 0; mi < 4; ++mi)
#pragma unroll
    for (int ni = 0; ni < 4; ++ni) acc[mi][ni] = (f32x4){0.f, 0.f, 0.f, 0.f};

  // wave w: array w>>1 (0=A,1=B), half w&1 (rows 0-63 / 64-127); 4 chunks of 1KB
  const unsigned short* src = (w < 2) ? Ah : Bh;
  const int rowbase = ((w < 2) ? m0 : n0) + (w & 1) * 64;
  const int lrow = l >> 2, lkk = (l & 3) * 8;

  const int NT = K / 32;
  int buf = 0;

#define STAGE1(B_, KT_)                                                        \
  {                                                                            \
    unsigned short* dst = lds[B_] + (w >> 1) * 4096 + (w & 1) * 2048;          \
    _Pragma("unroll") for (int c = 0; c < 4; ++c) {                            \
      const unsigned short* g =                                                \
          src + (size_t)(rowbase + c * 16 + lrow) * K + (KT_) + lkk;           \
      __builtin_amdgcn_global_load_lds(                                        \
          (const __attribute__((address_space(1))) unsigned int*)g,            \
          (__attribute__((address_space(3))) unsigned int*)(dst + c * 512),    \
          16, 0, 0);                                                           \
    }                                                                          \
  }

  STAGE1(0, 0);
  asm volatile("s_waitcnt vmcnt(0)");
  __syncthreads();

  for (int t = 0; t < NT; ++t) {
    if (t + 1 < NT) STAGE1(buf ^ 1, (t + 1) * 32);

    const unsigned short* bp = lds[buf];
    bf16x8 ah[4], bh[4];
#pragma unroll
    for (int mi = 0; mi < 4; ++mi)
      ah[mi] = *(const bf16x8*)&bp[(wr * 64 + mi * 16 + lc) * 32 + lr * 8];
#pragma unroll
    for (int ni = 0; ni < 4; ++ni)
      bh[ni] = *(const bf16x8*)&bp[4096 + (wc * 64 + ni * 16 + lc) * 32 + lr * 8];

    __builtin_amdgcn_s_setprio(1);
#pragma unroll
    for (int mi = 0; mi < 4; ++mi)
#pragma unroll
      for (int ni = 0; ni < 4; ++ni)
        acc[mi][ni] = __builtin_amdgcn_mfma_f32_16x16x32_bf16(ah[mi], bh[ni], acc[mi][ni], 0, 0, 0);
    __builtin_amdgcn_s_setprio(0);

    __syncthreads();
    buf ^= 1;
  }
#undef STAGE1

#pragma unroll
  for (int mi = 0; mi < 4; ++mi)
#pragma unroll
    for (int r = 0; r < 4; ++r) {
      int row = m0 + wr * 64 + mi * 16 + lr * 4 + r;
#pragma unroll
      for (int ni = 0; ni < 4; ++ni) {
        int col = n0 + wc * 64 + ni * 16 + lc;
        C[(size_t)row * N + col] = acc[mi][ni][r] + bias[col];
      }
    }
}

// ---------------------------------------------------------------------------
// qkv GEMM with FUSED image epilogue. Epilogue is the round-7 form verbatim
// (round-8's paired-store variant regressed: +7MB writes, +8.5µs).
// ---------------------------------------------------------------------------
__global__ __launch_bounds__(256, 2) void gemm_qkv_fused(
    const unsigned short* __restrict__ Ah, const unsigned short* __restrict__ Al,
    const unsigned short* __restrict__ Bh, const unsigned short* __restrict__ Bl,
    const float* __restrict__ bias,
    unsigned short* __restrict__ Qh, unsigned short* __restrict__ Ql,
    unsigned short* __restrict__ Ktg, unsigned short* __restrict__ Vtg) {
  const int K = 1024;
  __shared__ __align__(16) unsigned short lds[2][16384];

  const int tid = threadIdx.x;
  const int w = tid >> 6, l = tid & 63;
  const int lc = l & 15, lr = l >> 4;
  const int wr = w >> 1, wc = w & 1;
  const int m0 = blockIdx.y * 128, n0 = blockIdx.x * 128;

  f32x4 acc[4][4];
#pragma unroll
  for (int mi = 0; mi < 4; ++mi)
#pragma unroll
    for (int ni = 0; ni < 4; ++ni) acc[mi][ni] = (f32x4){0.f, 0.f, 0.f, 0.f};

  const unsigned short* src = (w == 0) ? Ah : (w == 1) ? Al : (w == 2) ? Bh : Bl;
  const int rowbase = (w < 2) ? m0 : n0;
  const int lrow = l >> 2, lkk = (l & 3) * 8;

  const int NT = K / 32;
  int buf = 0;

#define STAGEQ(B_, KT_)                                                        \
  {                                                                            \
    unsigned short* dst = lds[B_] + w * 4096;                                  \
    _Pragma("unroll") for (int c = 0; c < 8; ++c) {                            \
      const unsigned short* g =                                                \
          src + (size_t)(rowbase + c * 16 + lrow) * K + (KT_) + lkk;           \
      __builtin_amdgcn_global_load_lds(                                        \
          (const __attribute__((address_space(1))) unsigned int*)g,            \
          (__attribute__((address_space(3))) unsigned int*)(dst + c * 512),    \
          16, 0, 0);                                                           \
    }                                                                          \
  }

  STAGEQ(0, 0);
  asm volatile("s_waitcnt vmcnt(0)");
  __syncthreads();

  for (int t = 0; t < NT; ++t) {
    if (t + 1 < NT) STAGEQ(buf ^ 1, (t + 1) * 32);

    const unsigned short* bp = lds[buf];
    bf16x8 ah[4], al[4], bh[4], bl[4];
#pragma unroll
    for (int mi = 0; mi < 4; ++mi) {
      int ro = (wr * 64 + mi * 16 + lc) * 32 + lr * 8;
      ah[mi] = *(const bf16x8*)&bp[ro];
      al[mi] = *(const bf16x8*)&bp[4096 + ro];
    }
#pragma unroll
    for (int ni = 0; ni < 4; ++ni) {
      int co = (wc * 64 + ni * 16 + lc) * 32 + lr * 8;
      bh[ni] = *(const bf16x8*)&bp[8192 + co];
      bl[ni] = *(const bf16x8*)&bp[12288 + co];
    }

    __builtin_amdgcn_s_setprio(1);
#pragma unroll
    for (int mi = 0; mi < 4; ++mi)
#pragma unroll
      for (int ni = 0; ni < 4; ++ni) {
        acc[mi][ni] = __builtin_amdgcn_mfma_f32_16x16x32_bf16(ah[mi], bh[ni], acc[mi][ni], 0, 0, 0);
        acc[mi][ni] = __builtin_amdgcn_mfma_f32_16x16x32_bf16(ah[mi], bl[ni], acc[mi][ni], 0, 0, 0);
        acc[mi][ni] = __builtin_amdgcn_mfma_f32_16x16x32_bf16(al[mi], bh[ni], acc[mi][ni], 0, 0, 0);
      }
    __builtin_amdgcn_s_setprio(0);

    __syncthreads();
    buf ^= 1;
  }
#undef STAGEQ

  // fused epilogue (round-7 verbatim; role uniform across the 16-lane span)
  const float QS = 0.125f * LOG2E;
#pragma unroll
  for (int ni = 0; ni < 4; ++ni) {
    int col = n0 + wc * 64 + ni * 16 + lc;   // 0..3071
    int h = col / 192;
    int rr = col - h * 192;
    float bs = bias[col];
    if (rr < 64) {  // Q: scaled hi/lo split, row-major [bh][t][c]
      int c = rr;
#pragma unroll
      for (int mi = 0; mi < 4; ++mi)
#pragma unroll
        for (int r = 0; r < 4; ++r) {
          int row = m0 + wr * 64 + mi * 16 + lr * 4 + r;
          int bb = row >> 11, tl = row & 2047;
          float v = (acc[mi][ni][r] + bs) * QS;
          unsigned short hh = f2bf(v);
          size_t off = ((size_t)(bb * 16 + h) * 2048 + tl) * 64 + c;
          Qh[off] = hh;
          Ql[off] = f2bf(v - bf2f(hh));
        }
    } else if (rr < 128) {  // K: swizzled tile image [bh*32+st][s][c]
      int c2 = (rr - 64) * 2;
#pragma unroll
      for (int mi = 0; mi < 4; ++mi)
#pragma unroll
        for (int r = 0; r < 4; ++r) {
          int row = m0 + wr * 64 + mi * 16 + lr * 4 + r;
          int bb = row >> 11, tl = row & 2047;
          int s = tl & 63;
          size_t base = (size_t)((bb * 16 + h) * 32 + (tl >> 6)) * 4096;
          Ktg[base + (((s * 128 + c2) ^ ((s & 7) << 4)) >> 1)] =
              f2bf(acc[mi][ni][r] + bs);
        }
    } else {  // V: transposed swizzled image [bh*32+st][c][s]
      int cb = (rr - 128) * 128, csw = ((rr - 128) & 7) << 4;
#pragma unroll
      for (int mi = 0; mi < 4; ++mi)
#pragma unroll
        for (int r = 0; r < 4; ++r) {
          int row = m0 + wr * 64 + mi * 16 + lr * 4 + r;
          int bb = row >> 11, tl = row & 2047;
          int s = tl & 63;
          size_t base = (size_t)((bb * 16 + h) * 32 + (tl >> 6)) * 4096;
          Vtg[base + (((cb + s * 2) ^ csw) >> 1)] = f2bf(acc[mi][ni][r] + bs);
        }
    }
  }
}

// ---------------------------------------------------------------------------
// MFMA flash attention (round-8 core, verified): swapped QK^T, defer-max
// THR=8, b64 P stores, x2-unrolled kvt with static LDS bases, dbuf staging.
// Round-9: epilogue writes SINGLE-bf16 A2 (cvt_pk packed).
// ---------------------------------------------------------------------------
__global__ __launch_bounds__(256, 4) void attn_mfma(
    const unsigned short* __restrict__ Qh, const unsigned short* __restrict__ Ql,
    const unsigned short* __restrict__ Ktg, const unsigned short* __restrict__ Vtg,
    const float* __restrict__ aw, unsigned short* __restrict__ A2h) {
  const int qt = blockIdx.x, bh = blockIdx.y;
  const int b = bh >> 4, h = bh & 15;
  const int tid = threadIdx.x;
  const int w = tid >> 6, l = tid & 63;
  const int lc = l & 15, lr = l >> 4;

  __shared__ __align__(16) unsigned short ldsKV[2][8192];  // [K 4096 | V 4096]
  __shared__ __align__(16) unsigned short ldsP[4096];
  unsigned short* Pl = ldsP + w * 1024;        // [16 q][64 k], XOR-swizzled
  uint2* Pl2 = (uint2*)Pl;

  const int q0 = qt * 64 + w * 16;
  bf16x8 qh0, qh1, ql0, ql1;
  {
    size_t base = ((size_t)bh * 2048 + q0 + lc) * 64 + lr * 8;
    qh0 = *(const bf16x8*)&Qh[base];
    qh1 = *(const bf16x8*)&Qh[base + 32];
    ql0 = *(const bf16x8*)&Ql[base];
    ql1 = *(const bf16x8*)&Ql[base + 32];
  }

  int kidx0[4], kidx1[4];
#pragma unroll
  for (int st = 0; st < 4; ++st) {
    int row = st * 16 + lc;
    int sw = (row & 7) << 4;
    kidx0[st] = ((row * 128 + lr * 16) ^ sw) >> 1;
    kidx1[st] = ((row * 128 + 64 + lr * 16) ^ sw) >> 1;
  }
  int pwd[4];
  {
    int sw = (lc & 7) << 4;
#pragma unroll
    for (int st = 0; st < 4; ++st)
      pwd[st] = ((lc * 128 + st * 32 + lr * 8) ^ sw) >> 3;
  }

  f32x4 o[4];
  float m = -1e30f, lsum = 0.f;
#pragma unroll
  for (int ct = 0; ct < 4; ++ct) o[ct] = (f32x4){0.f, 0.f, 0.f, 0.f};

  const unsigned short* gsrc =
      ((w < 2) ? Ktg : Vtg) + (size_t)bh * 32 * 4096 + (w & 1) * 2048 + l * 8;
  unsigned short* ldst0 = &ldsKV[0][(w >> 1) * 4096 + (w & 1) * 2048];
  unsigned short* ldst1 = &ldsKV[1][(w >> 1) * 4096 + (w & 1) * 2048];

#define STAGE_KV(DST_, T_)                                                     \
  {                                                                            \
    const unsigned short* g = gsrc + (size_t)(T_) * 4096;                      \
    _Pragma("unroll") for (int i = 0; i < 4; ++i) {                            \
      __builtin_amdgcn_global_load_lds(                                        \
          (const __attribute__((address_space(1))) unsigned int*)(g + i * 512),\
          (__attribute__((address_space(3))) unsigned int*)((DST_) + i * 512), \
          16, 0, 0);                                                           \
    }                                                                          \
  }

  STAGE_KV(ldst0, 0);
  asm volatile("s_waitcnt vmcnt(0)");
  __syncthreads();

  for (int kvt = 0; kvt < 32; kvt += 2) {
#pragma unroll
    for (int hf = 0; hf < 2; ++hf) {
      const int t2 = kvt + hf;
      if (t2 + 1 < 32) STAGE_KV(hf ? ldst0 : ldst1, t2 + 1);

      const unsigned short* KT = &ldsKV[hf][0];     // compile-time base
      const unsigned short* VT = &ldsKV[hf][4096];

      // swapped QK^T: sacc[st] = S^T[k=st*16+lr*4+r][q=lc]
      f32x4 sacc[4];
      __builtin_amdgcn_s_setprio(1);
#pragma unroll
      for (int st = 0; st < 4; ++st) {
        bf16x8 k0 = *(const bf16x8*)&KT[kidx0[st]];
        bf16x8 k1 = *(const bf16x8*)&KT[kidx1[st]];
        f32x4 acc = (f32x4){0.f, 0.f, 0.f, 0.f};
        acc = __builtin_amdgcn_mfma_f32_16x16x32_bf16(k0, qh0, acc, 0, 0, 0);
        acc = __builtin_amdgcn_mfma_f32_16x16x32_bf16(k1, qh1, acc, 0, 0, 0);
        acc = __builtin_amdgcn_mfma_f32_16x16x32_bf16(k0, ql0, acc, 0, 0, 0);
        acc = __builtin_amdgcn_mfma_f32_16x16x32_bf16(k1, ql1, acc, 0, 0, 0);
        sacc[st] = acc;
      }
      __builtin_amdgcn_s_setprio(0);

      // defer-max (THR=8): P bounded by 2^8, harmless for fp32 lsum/bf16 P
      float pmax = fmaxf(fmaxf(fmaxf(sacc[0][0], sacc[0][1]), fmaxf(sacc[0][2], sacc[0][3])),
                         fmaxf(fmaxf(sacc[1][0], sacc[1][1]), fmaxf(sacc[1][2], sacc[1][3])));
      pmax = fmaxf(pmax,
             fmaxf(fmaxf(fmaxf(sacc[2][0], sacc[2][1]), fmaxf(sacc[2][2], sacc[2][3])),
                   fmaxf(fmaxf(sacc[3][0], sacc[3][1]), fmaxf(sacc[3][2], sacc[3][3]))));
      if (__any(pmax > m + 8.0f)) {
        float pm = fmaxf(pmax, __shfl_xor(pmax, 16));
        pm = fmaxf(pm, __shfl_xor(pm, 32));
        float mn = fmaxf(m, pm);
        float corr = exp2f(m - mn);
        m = mn;
        lsum *= corr;
#pragma unroll
        for (int r = 0; r < 4; ++r) {
          float cq = __shfl(corr, lr * 4 + r);
          o[0][r] *= cq; o[1][r] *= cq; o[2][r] *= cq; o[3][r] *= cq;
        }
      }

      // exp2 + per-lane row partial sum
#pragma unroll
      for (int st = 0; st < 4; ++st)
#pragma unroll
        for (int r = 0; r < 4; ++r)
          sacc[st][r] = exp2f(sacc[st][r] - m);
#pragma unroll
      for (int st = 0; st < 4; ++st)
        lsum += (sacc[st][0] + sacc[st][1]) + (sacc[st][2] + sacc[st][3]);

      // HW cvt_pk + one b64 store per st
#pragma unroll
      for (int st = 0; st < 4; ++st) {
        uint2 pv;
        pv.x = pk_bf16(sacc[st][0], sacc[st][1]);
        pv.y = pk_bf16(sacc[st][2], sacc[st][3]);
        Pl2[pwd[st]] = pv;
      }

      bf16x8 pa0 = *(const bf16x8*)&Pl[kidx0[0]];
      bf16x8 pa1 = *(const bf16x8*)&Pl[kidx1[0]];

      // PV: O += P @ V
      __builtin_amdgcn_s_setprio(1);
#pragma unroll
      for (int ct = 0; ct < 4; ++ct) {
        bf16x8 v0 = *(const bf16x8*)&VT[kidx0[ct]];
        bf16x8 v1 = *(const bf16x8*)&VT[kidx1[ct]];
        o[ct] = __builtin_amdgcn_mfma_f32_16x16x32_bf16(pa0, v0, o[ct], 0, 0, 0);
        o[ct] = __builtin_amdgcn_mfma_f32_16x16x32_bf16(pa1, v1, o[ct], 0, 0, 0);
      }
      __builtin_amdgcn_s_setprio(0);
      __syncthreads();
    }
  }
#undef STAGE_KV

  // row sum for q=lc, move to q=lr*4+r; write SINGLE-bf16 A2 = aw*O/l
  lsum += __shfl_xor(lsum, 16);
  lsum += __shfl_xor(lsum, 32);
  float inv = 1.0f / lsum;
#pragma unroll
  for (int r = 0; r < 4; ++r) {
    int t = q0 + lr * 4 + r;
    float sc = aw[b * 2048 + t] * __shfl(inv, lr * 4 + r);
    size_t off = (size_t)(b * 2048 + t) * 1024 + h * 64 + lc;
    unsigned int u01 = pk_bf16(o[0][r] * sc, o[1][r] * sc);
    unsigned int u23 = pk_bf16(o[2][r] * sc, o[3][r] * sc);
    A2h[off]      = (unsigned short)u01;
    A2h[off + 16] = (unsigned short)(u01 >> 16);
    A2h[off + 32] = (unsigned short)u23;
    A2h[off + 48] = (unsigned short)(u23 >> 16);
  }
}

// ---------------------------------------------------------------------------
// k_mean partials / pos / aw (round-5, verified)
// ---------------------------------------------------------------------------
__global__ __launch_bounds__(256) void kmean_part(
    const unsigned short* __restrict__ Ktg, float* __restrict__ kmp) {
  const int bh = blockIdx.x, seg = blockIdx.y;
  const int c = threadIdx.x & 63, sub = threadIdx.x >> 6;
  const int tile = seg * 4 + sub;
  const unsigned short* kt = Ktg + (size_t)(bh * 32 + tile) * 4096;
  float sum = 0.f;
#pragma unroll 8
  for (int s = 0; s < 64; ++s) {
    int sidx = ((s * 128 + c * 2) ^ ((s & 7) << 4)) >> 1;
    sum += bf2f(kt[sidx]);
  }
  __shared__ float red[4][64];
  red[sub][c] = sum;
  __syncthreads();
  if (sub == 0)
    kmp[(size_t)(bh * 8 + seg) * 64 + c] =
        red[0][c] + red[1][c] + red[2][c] + red[3][c];
}

__global__ __launch_bounds__(256) void pos_kernel(
    const unsigned short* __restrict__ Qh, const unsigned short* __restrict__ Ql,
    const float* __restrict__ kmp, float* __restrict__ pos) {
  __shared__ float kms[1024];
  int blk = blockIdx.x;
  int b = (blk * 4) >> 11;
  for (int i = threadIdx.x; i < 1024; i += 256) {
    int h = i >> 6, cc = i & 63;
    float s = 0.f;
#pragma unroll
    for (int seg = 0; seg < 8; ++seg)
      s += kmp[(size_t)((b * 16 + h) * 8 + seg) * 64 + cc];
    kms[i] = s * (1.0f / 2048.0f) * (1.0f / LOG2E);
  }
  __syncthreads();
  int w = threadIdx.x >> 6, lane = threadIdx.x & 63;
  int row = blk * 4 + w;
  int t = row & 2047;
  float p = 0.f;
#pragma unroll
  for (int h = 0; h < 16; ++h) {
    size_t idx = ((size_t)(b * 16 + h) * 2048 + t) * 64 + lane;
    p = fmaf(bf2f(Qh[idx]) + bf2f(Ql[idx]), kms[h * 64 + lane], p);
  }
#pragma unroll
  for (int off = 32; off; off >>= 1) p += __shfl_xor(p, off, 64);
  if (lane == 0) pos[row] = p;
}

__global__ __launch_bounds__(1024) void aw_kernel(const float* __restrict__ pos,
                                                  float* __restrict__ aw) {
  int b = blockIdx.x, tid = threadIdx.x;
  float p0 = pos[b * 2048 + tid], p1 = pos[b * 2048 + 1024 + tid];
  float mn = fminf(p0, p1), mx = fmaxf(p0, p1);
#pragma unroll
  for (int off = 32; off; off >>= 1) {
    mn = fminf(mn, __shfl_xor(mn, off, 64));
    mx = fmaxf(mx, __shfl_xor(mx, off, 64));
  }
  __shared__ float smn[16], smx[16];
  int wave = tid >> 6, lane = tid & 63;
  if (lane == 0) { smn[wave] = mn; smx[wave] = mx; }
  __syncthreads();
  if (tid < 64) {
    mn = (lane < 16) ? smn[lane] : 3.0e38f;
    mx = (lane < 16) ? smx[lane] : -3.0e38f;
#pragma unroll
    for (int off = 8; off; off >>= 1) {
      mn = fminf(mn, __shfl_xor(mn, off, 64));
      mx = fmaxf(mx, __shfl_xor(mx, off, 64));
    }
    if (lane == 0) { smn[0] = mn; smx[0] = mx; }
  }
  __syncthreads();
  float MN = smn[0], inv = 1.0f / (smx[0] - MN + 1e-6f);
  aw[b * 2048 + tid] = (p0 - MN) * inv;
  aw[b * 2048 + 1024 + tid] = (p1 - MN) * inv;
}

// ---------------------------------------------------------------------------
// Workspace layout (peak ~71.4 MB):
//  [0,16M)      xh/xl   live conv..gemm_qkv;  then A2h [0,8M) (attn..proj)
//  [16M,28.6M)  Wqh/Wql live conv..gemm_qkv
//  [32M,64M)    Qh|Ql|Ktg|Vtg  written by gemm_qkv_fused, live ..attn
//  [64M,66M)    Wph (single)
//  [68M,...)    kmp/pos/aw
// ---------------------------------------------------------------------------
extern "C" void kernel_launch(void* const* d_in, const int* in_sizes, int n_in,
                              void* d_out, int out_size, void* d_ws, size_t ws_size,
                              hipStream_t stream) {
  const float* x      = (const float*)d_in[0];
  const float* W_qkv  = (const float*)d_in[1];
  const float* b_qkv  = (const float*)d_in[2];
  const float* W_proj = (const float*)d_in[3];
  const float* b_proj = (const float*)d_in[4];
  float* out = (float*)d_out;

  char* wsb = (char*)d_ws;
  unsigned short* xh  = (unsigned short*)wsb;                // [0,16M)
  unsigned short* xl  = xh + 4194304;
  unsigned short* A2h = (unsigned short*)wsb;                // reuse after gemm_qkv
  unsigned short* Wqh = (unsigned short*)(wsb + 16777216);   // [16M,28.6M)
  unsigned short* Wql = Wqh + 3145728;
  unsigned short* Qh  = (unsigned short*)(wsb + 33554432);   // [32M,64M)
  unsigned short* Ql  = Qh + 4194304;
  unsigned short* Ktg = Ql + 4194304;
  unsigned short* Vtg = Ktg + 4194304;
  unsigned short* Wph = (unsigned short*)(wsb + 67108864);   // [64M,66M)
  float* kmp = (float*)(wsb + 71303168);                     // [68M,...)
  float* pos = kmp + 16384;
  float* aw  = pos + 4096;

  // 1) fused operand prep (x split + Wq split-T + Wp single-T)
  conv_all<<<6144, 256, 0, stream>>>(x, xh, xl, W_qkv, Wqh, Wql, W_proj, Wph);
  // 2) qkv GEMM with fused image epilogue
  gemm_qkv_fused<<<dim3(24, 32), 256, 0, stream>>>(xh, xl, Wqh, Wql, b_qkv,
                                                   Qh, Ql, Ktg, Vtg);
  // 3) k_mean partials / pos / aw
  kmean_part<<<dim3(32, 8), 256, 0, stream>>>(Ktg, kmp);
  pos_kernel<<<1024, 256, 0, stream>>>(Qh, Ql, kmp, pos);
  aw_kernel<<<2, 1024, 0, stream>>>(pos, aw);
  // 4) MFMA flash attention, fused aw-scale + single-bf16 A2 epilogue
  attn_mfma<<<dim3(32, 32), 256, 0, stream>>>(Qh, Ql, Ktg, Vtg, aw, A2h);
  // 5) out = A2 @ W_proj + b (single-bf16 MFMA)
  gemm_mfma_single<<<dim3(8, 32), 256, 0, stream>>>(A2h, Wph, b_proj,
                                                    out, 4096, 1024, 1024);
}